// Round 18
// baseline (334.199 us; speedup 1.0000x reference)
//
#include <hip/hip_runtime.h>
#include <stdint.h>

// Problem constants (B=4, S=1024, H=2048, NH=16, HD=128)
#define HDIM 2048
#define SEQLEN 1024
#define NHEADS 16
#define HEADD 128

typedef unsigned short u16;
typedef unsigned int u32;
typedef __attribute__((ext_vector_type(8))) short bf16x8;   // MFMA A/B frag
typedef __attribute__((ext_vector_type(8))) u16 u16x8;
typedef __attribute__((ext_vector_type(4))) u16 u16x4;
typedef __attribute__((ext_vector_type(4))) float f32x4;

__device__ __forceinline__ float bf2f(u16 u) {
    union { u32 i; float f; } v; v.i = ((u32)u) << 16; return v.f;
}
__device__ __forceinline__ u16 f2bf(float f) {
    union { float f; u32 i; } v; v.f = f;
    return (u16)((v.i + 0x7fffu + ((v.i >> 16) & 1u)) >> 16);  // RNE
}
__device__ __forceinline__ u16 f2bf_t(float f) {               // truncation (1 op)
    union { float f; u32 i; } v; v.f = f; return (u16)(v.i >> 16);
}
// Fast silu: x * rcp(1+exp(-x)).
__device__ __forceinline__ float silu_f(float x) {
    return x * __builtin_amdgcn_rcpf(1.f + __expf(-x));
}
// Async global->LDS, 16B per lane. LDS dest = wave-uniform base + lane*16.
__device__ __forceinline__ void glds16(const void* g, void* l) {
    __builtin_amdgcn_global_load_lds(
        (const __attribute__((address_space(1))) u32*)g,
        (__attribute__((address_space(3))) u32*)l, 16, 0, 0);
}

// ---------------------------------------------------------------------------
// f32 -> bf16 bulk convert (8 elems/thread/iter), n8 = n/8.
__global__ __launch_bounds__(256) void f32_to_bf16(const float* __restrict__ in,
                                                   u16* __restrict__ out, int n8) {
    int i = blockIdx.x * 256 + threadIdx.x;
    const int stride = gridDim.x * 256;
    for (; i < n8; i += stride) {
        f32x4 a = *(const f32x4*)&in[(size_t)i * 8];
        f32x4 b = *(const f32x4*)&in[(size_t)i * 8 + 4];
        u16x8 o;
#pragma unroll
        for (int j = 0; j < 4; ++j) { o[j] = f2bf(a[j]); o[4 + j] = f2bf(b[j]); }
        *(u16x8*)&out[(size_t)i * 8] = o;
    }
}

// ---------------------------------------------------------------------------
// Transpose + downconvert W[k][n] (2048x2048 f32) -> WT[n][k] bf16.
__global__ __launch_bounds__(256) void transpose_w(const float* __restrict__ W,
                                                   u16* __restrict__ WT) {
    __shared__ u16 T[64][76];   // 152B rows: 8B aligned, 4-way max on reads
    const int r0 = blockIdx.y * 64;   // k
    const int c0 = blockIdx.x * 64;   // n
    const int t = threadIdx.x;
#pragma unroll
    for (int c = t; c < 1024; c += 256) {
        const int r = c >> 4, cc = (c & 15) << 2;
        f32x4 v = *(const f32x4*)&W[(size_t)(r0 + r) * HDIM + c0 + cc];
        u16x4 o;
#pragma unroll
        for (int j = 0; j < 4; ++j) o[j] = f2bf(v[j]);
        *(u16x4*)&T[r][cc] = o;
    }
    __syncthreads();
#pragma unroll
    for (int c = t; c < 512; c += 256) {
        const int n = c >> 3, kc = (c & 7) << 3;   // lanes 0-7: same n, kc 0..56
        u16x8 v;
#pragma unroll
        for (int j = 0; j < 8; ++j) v[j] = T[kc + j][n];
        *(u16x8*)&WT[(size_t)(c0 + n) * HDIM + r0 + kc] = v;
    }
}

// ---------------------------------------------------------------------------
// Transpose V: Vbuf[b*1024+s][h*128+d] bf16 -> VTg[(bh*128+d)*1024+s] bf16.
__global__ __launch_bounds__(256) void transpose_v(const u16* __restrict__ V,
                                                   u16* __restrict__ VT) {
    __shared__ u16 T[64][76];
    const int bh = blockIdx.y;
    const int st = (blockIdx.x & 15) * 64;
    const int dt = (blockIdx.x >> 4) * 64;
    const int b = bh >> 4, h = bh & 15;
    const int t = threadIdx.x;
#pragma unroll
    for (int c = t; c < 1024; c += 256) {        // u16x4 loads (8B, aligned)
        const int s = c >> 4, d4 = (c & 15) << 2;
        *(u16x4*)&T[s][d4] =
            *(const u16x4*)&V[(size_t)(b * SEQLEN + st + s) * HDIM + h * HEADD + dt + d4];
    }
    __syncthreads();
#pragma unroll
    for (int c = t; c < 512; c += 256) {
        const int d = c >> 3, s8 = (c & 7) << 3;  // lanes 0-7: same d, s8 0..56
        u16x8 v;
#pragma unroll
        for (int j = 0; j < 8; ++j) v[j] = T[s8 + j][d];
        *(u16x8*)&VT[((size_t)bh * HEADD + dt + d) * SEQLEN + st + s8] = v;
    }
}

// ---------------------------------------------------------------------------
// 8-phase 256x256 GEMM, QU-fused (round-17, unchanged).
__global__ __launch_bounds__(512, 2) void gemm256_8p(
    const u16* __restrict__ X,
    const u16* __restrict__ WTq, const u16* __restrict__ WTu,
    const float* __restrict__ bq, const float* __restrict__ bu,
    u16* __restrict__ Qo, u16* __restrict__ Uo)
{
    extern __shared__ u16 lds[];   // 2 bufs x 32768 u16 (A @0, B @16384)
    const int t = threadIdx.x;
    const int lane = t & 63, wid = t >> 6;        // 8 waves
    const int l15 = lane & 15, l4 = lane >> 4;
    const int wr = wid >> 2, wn = wid & 3;        // 2M x 4N

    const int bid = blockIdx.x;                   // 256 blocks
    const int u = (bid & 7) * 32 + (bid >> 3);    // XCD-bijective
    const int tm = u & 15, tn = u >> 4;
    const int m0 = tm * 256;
    const int n0 = tn * 256;                      // 0..4095
    const u16* WT = (n0 < 2048) ? WTq : WTu;
    const float* bias = (n0 < 2048) ? bq : bu;
    u16* outp = (n0 < 2048) ? Qo : Uo;
    const int nc0 = n0 & 2047;

    const int r64 = t >> 3;                       // 0..63
    const int cse = (((t & 7) ^ (r64 & 7)) << 3);
    const u16* gA = X + (size_t)(m0 + r64) * HDIM + cse;
    const int rB0 = (r64 >> 5) * 64 + (r64 & 31);
    const u16* gB = WT + (size_t)(nc0 + rB0) * HDIM + cse;

    const int wbase = wid * 512;
    const int dstBw = (wid >> 2) * 4096 + (wid & 3) * 512;

    int offA[8][2], offB[4][2];
#pragma unroll
    for (int mf = 0; mf < 8; ++mf) {
        const int row = wr * 128 + mf * 16 + l15;
#pragma unroll
        for (int kk = 0; kk < 2; ++kk) {
            const int c = kk * 4 + l4;
            offA[mf][kk] = row * 64 + (((c) ^ (row & 7)) << 3);
        }
    }
#pragma unroll
    for (int nf = 0; nf < 4; ++nf) {
        const int row = wn * 64 + nf * 16 + l15;
#pragma unroll
        for (int kk = 0; kk < 2; ++kk) {
            const int c = kk * 4 + l4;
            offB[nf][kk] = 16384 + row * 64 + (((c) ^ (row & 7)) << 3);
        }
    }

#define SA(buf, rb, kt) glds16(gA + (size_t)(rb) * HDIM + (kt) * 64, \
                               lds + (buf) * 32768 + (rb) * 64 + wbase)
#define SB(buf, c, half, kt) glds16(gB + (size_t)((c) * 128 + (half) * 32) * HDIM + (kt) * 64, \
                               lds + (buf) * 32768 + 16384 + dstBw + (c) * 8192 + (half) * 2048)

    SA(0, 0, 0);    SA(0, 128, 0);
    SB(0, 0, 0, 0); SB(0, 1, 0, 0);
    SB(0, 0, 1, 0); SB(0, 1, 1, 0);
    SA(0, 64, 0);   SA(0, 192, 0);
    asm volatile("s_waitcnt vmcnt(4)" ::: "memory");
    __builtin_amdgcn_s_barrier();

    f32x4 acc[8][4] = {};
    int cur = 0;

#pragma unroll 1
    for (int kt = 0; kt < 32; ++kt) {
        const u16* pc = lds + cur * 32768;
        const int nb = cur ^ 1;
        const bool pf = (kt + 1 < 32);
        bf16x8 a[4][2], b0[2][2], b1[2][2];

        // ---- P1 ----
#pragma unroll
        for (int mf = 0; mf < 4; ++mf)
#pragma unroll
            for (int kk = 0; kk < 2; ++kk)
                a[mf][kk] = *(const bf16x8*)(pc + offA[mf][kk]);
#pragma unroll
        for (int nf = 0; nf < 2; ++nf)
#pragma unroll
            for (int kk = 0; kk < 2; ++kk)
                b0[nf][kk] = *(const bf16x8*)(pc + offB[nf][kk]);
        if (pf) { SA(nb, 0, kt + 1); SA(nb, 128, kt + 1); }
        __builtin_amdgcn_s_barrier();
        asm volatile("s_waitcnt lgkmcnt(0)");
        __builtin_amdgcn_sched_barrier(0);
        __builtin_amdgcn_s_setprio(1);
#pragma unroll
        for (int mf = 0; mf < 4; ++mf)
#pragma unroll
            for (int nf = 0; nf < 2; ++nf)
#pragma unroll
                for (int kk = 0; kk < 2; ++kk)
                    acc[mf][nf] = __builtin_amdgcn_mfma_f32_16x16x32_bf16(
                        a[mf][kk], b0[nf][kk], acc[mf][nf], 0, 0, 0);
        __builtin_amdgcn_s_setprio(0);
        if (pf) { asm volatile("s_waitcnt vmcnt(4)" ::: "memory"); }
        else    { asm volatile("s_waitcnt vmcnt(2)" ::: "memory"); }
        __builtin_amdgcn_s_barrier();

        // ---- P2 ----
#pragma unroll
        for (int nf = 0; nf < 2; ++nf)
#pragma unroll
            for (int kk = 0; kk < 2; ++kk)
                b1[nf][kk] = *(const bf16x8*)(pc + offB[2 + nf][kk]);
        if (pf) { SB(nb, 0, 0, kt + 1); SB(nb, 1, 0, kt + 1); }
        __builtin_amdgcn_s_barrier();
        asm volatile("s_waitcnt lgkmcnt(0)");
        __builtin_amdgcn_sched_barrier(0);
        __builtin_amdgcn_s_setprio(1);
#pragma unroll
        for (int mf = 0; mf < 4; ++mf)
#pragma unroll
            for (int nf = 0; nf < 2; ++nf)
#pragma unroll
                for (int kk = 0; kk < 2; ++kk)
                    acc[mf][2 + nf] = __builtin_amdgcn_mfma_f32_16x16x32_bf16(
                        a[mf][kk], b1[nf][kk], acc[mf][2 + nf], 0, 0, 0);
        __builtin_amdgcn_s_setprio(0);
        if (pf) { asm volatile("s_waitcnt vmcnt(4)" ::: "memory"); }
        else    { asm volatile("s_waitcnt vmcnt(0)" ::: "memory"); }
        __builtin_amdgcn_s_barrier();

        // ---- P3 ----
#pragma unroll
        for (int mf = 0; mf < 4; ++mf)
#pragma unroll
            for (int kk = 0; kk < 2; ++kk)
                a[mf][kk] = *(const bf16x8*)(pc + offA[4 + mf][kk]);
        if (pf) { SB(nb, 0, 1, kt + 1); SB(nb, 1, 1, kt + 1); }
        __builtin_amdgcn_s_barrier();
        asm volatile("s_waitcnt lgkmcnt(0)");
        __builtin_amdgcn_sched_barrier(0);
        __builtin_amdgcn_s_setprio(1);
#pragma unroll
        for (int mf = 0; mf < 4; ++mf)
#pragma unroll
            for (int nf = 0; nf < 2; ++nf)
#pragma unroll
                for (int kk = 0; kk < 2; ++kk)
                    acc[4 + mf][nf] = __builtin_amdgcn_mfma_f32_16x16x32_bf16(
                        a[mf][kk], b0[nf][kk], acc[4 + mf][nf], 0, 0, 0);
        __builtin_amdgcn_s_setprio(0);
        __builtin_amdgcn_s_barrier();

        // ---- P4 ----
        if (pf) { SA(nb, 64, kt + 1); SA(nb, 192, kt + 1); }
        __builtin_amdgcn_s_barrier();
        __builtin_amdgcn_s_setprio(1);
#pragma unroll
        for (int mf = 0; mf < 4; ++mf)
#pragma unroll
            for (int nf = 0; nf < 2; ++nf)
#pragma unroll
                for (int kk = 0; kk < 2; ++kk)
                    acc[4 + mf][2 + nf] = __builtin_amdgcn_mfma_f32_16x16x32_bf16(
                        a[mf][kk], b1[nf][kk], acc[4 + mf][2 + nf], 0, 0, 0);
        __builtin_amdgcn_s_setprio(0);
        if (pf) { asm volatile("s_waitcnt vmcnt(4)" ::: "memory"); }
        __builtin_amdgcn_s_barrier();
        cur ^= 1;
    }
#undef SA
#undef SB

    // Coalesced epilogue
    float bvv[4];
#pragma unroll
    for (int nf = 0; nf < 4; ++nf) bvv[nf] = bias[nc0 + wn * 64 + nf * 16 + l15];
#pragma unroll
    for (int mf = 0; mf < 8; ++mf) {
        const int mbase = m0 + wr * 128 + mf * 16 + (l4 << 2);
#pragma unroll
        for (int r = 0; r < 4; ++r) {
            u16* rowp = outp + (size_t)(mbase + r) * HDIM + nc0 + wn * 64 + l15;
#pragma unroll
            for (int nf = 0; nf < 4; ++nf)
                rowp[nf * 16] = f2bf(silu_f(acc[mf][nf][r] + bvv[nf]));
        }
    }
}

// ---------------------------------------------------------------------------
// Pipelined GEMM 128x128 (round-17, unchanged).
__global__ __launch_bounds__(256) void gemm128(
    const u16* __restrict__ X, const u16* __restrict__ WT,
    const float* __restrict__ bias, void* __restrict__ outp, const int mode)
{
    extern __shared__ u16 lds[];   // 2 bufs x (A 8192 + B 8192) u16 = 64 KiB
    const int t = threadIdx.x;
    const int lane = t & 63, wid = t >> 6;       // 4 waves
    const int l15 = lane & 15, l4 = lane >> 4;
    const int wr = wid >> 1, wn = wid & 1;

    const int bid = blockIdx.x;                  // 512 blocks
    const int u = (bid & 7) * 64 + (bid >> 3);   // XCD-bijective
    const int tm = u & 31, tn = u >> 5;
    const int m0 = tm * 128, n0 = tn * 128;

    const int ric = t >> 3;
    const int cse = (((t & 7) ^ (ric & 7)) << 3);
    const u16* gA = X  + (size_t)(m0 + ric) * HDIM + cse;
    const u16* gB = WT + (size_t)(n0 + ric) * HDIM + cse;

    u16* buf0 = lds;
    u16* buf1 = lds + 16384;
    const int wbase = wid * 512;

    int offA[4][2], offB[4][2];
#pragma unroll
    for (int i = 0; i < 4; ++i) {
        const int row = wr * 64 + i * 16 + l15;
#pragma unroll
        for (int kk = 0; kk < 2; ++kk)
            offA[i][kk] = ((row * 128 + kk * 64 + l4 * 16) ^ ((row & 7) << 4)) >> 1;
    }
#pragma unroll
    for (int j = 0; j < 4; ++j) {
        const int row = wn * 64 + j * 16 + l15;
#pragma unroll
        for (int kk = 0; kk < 2; ++kk)
            offB[j][kk] = 8192 + ((((row * 128 + kk * 64 + l4 * 16) ^ ((row & 7) << 4))) >> 1);
    }

#define STAGE_A(buf, c, kt) glds16(gA + (size_t)(c) * 32 * HDIM + (kt) * 64, (buf) + (c) * 2048 + wbase)
#define STAGE_B(buf, c, kt) glds16(gB + (size_t)(c) * 32 * HDIM + (kt) * 64, (buf) + 8192 + (c) * 2048 + wbase)

    STAGE_B(buf0, 0, 0); STAGE_B(buf0, 1, 0); STAGE_B(buf0, 2, 0); STAGE_B(buf0, 3, 0);
    STAGE_A(buf0, 0, 0); STAGE_A(buf0, 1, 0); STAGE_A(buf0, 2, 0); STAGE_A(buf0, 3, 0);
    STAGE_B(buf1, 0, 1); STAGE_B(buf1, 1, 1); STAGE_B(buf1, 2, 1); STAGE_B(buf1, 3, 1);
    STAGE_A(buf1, 0, 1); STAGE_A(buf1, 2, 1);
    asm volatile("s_waitcnt vmcnt(6)" ::: "memory");
    __builtin_amdgcn_s_barrier();

    f32x4 acc[4][4] = {};
    u16* pc = buf0;
    u16* pn = buf1;

#pragma unroll 1
    for (int tt = 0; tt < 32; ++tt) {
        bf16x8 bfr[4][2], afr[2][2];
#pragma unroll
        for (int j = 0; j < 4; ++j)
#pragma unroll
            for (int kk = 0; kk < 2; ++kk)
                bfr[j][kk] = *(const bf16x8*)(pc + offB[j][kk]);
#pragma unroll
        for (int i = 0; i < 2; ++i)
#pragma unroll
            for (int kk = 0; kk < 2; ++kk)
                afr[i][kk] = *(const bf16x8*)(pc + offA[i][kk]);
        if (tt + 1 < 32) { STAGE_A(pn, 1, tt + 1); STAGE_A(pn, 3, tt + 1); }
        __builtin_amdgcn_s_barrier();
        asm volatile("s_waitcnt lgkmcnt(0)");
        __builtin_amdgcn_sched_barrier(0);
        __builtin_amdgcn_s_setprio(1);
#pragma unroll
        for (int i = 0; i < 2; ++i)
#pragma unroll
            for (int j = 0; j < 4; ++j)
#pragma unroll
                for (int kk = 0; kk < 2; ++kk)
                    acc[i][j] = __builtin_amdgcn_mfma_f32_16x16x32_bf16(
                        afr[i][kk], bfr[j][kk], acc[i][j], 0, 0, 0);
        __builtin_amdgcn_s_setprio(0);
        __builtin_amdgcn_s_barrier();

#pragma unroll
        for (int i = 0; i < 2; ++i)
#pragma unroll
            for (int kk = 0; kk < 2; ++kk)
                afr[i][kk] = *(const bf16x8*)(pc + offA[2 + i][kk]);
        if (tt + 2 < 32) {
            STAGE_B(pc, 0, tt + 2); STAGE_B(pc, 1, tt + 2);
            STAGE_B(pc, 2, tt + 2); STAGE_B(pc, 3, tt + 2);
            STAGE_A(pc, 0, tt + 2); STAGE_A(pc, 2, tt + 2);
        }
        __builtin_amdgcn_s_barrier();
        asm volatile("s_waitcnt lgkmcnt(0)");
        __builtin_amdgcn_sched_barrier(0);
        __builtin_amdgcn_s_setprio(1);
#pragma unroll
        for (int i = 0; i < 2; ++i)
#pragma unroll
            for (int j = 0; j < 4; ++j)
#pragma unroll
                for (int kk = 0; kk < 2; ++kk)
                    acc[2 + i][j] = __builtin_amdgcn_mfma_f32_16x16x32_bf16(
                        afr[i][kk], bfr[j][kk], acc[2 + i][j], 0, 0, 0);
        __builtin_amdgcn_s_setprio(0);
        if (tt + 2 < 32)      { asm volatile("s_waitcnt vmcnt(6)" ::: "memory"); }
        else if (tt + 1 < 32) { asm volatile("s_waitcnt vmcnt(0)" ::: "memory"); }
        __builtin_amdgcn_s_barrier();
        u16* tmp = pc; pc = pn; pn = tmp;
    }
#undef STAGE_A
#undef STAGE_B

    float bvv[4];
#pragma unroll
    for (int j = 0; j < 4; ++j) bvv[j] = bias[n0 + wn * 64 + j * 16 + l15];
#pragma unroll
    for (int i = 0; i < 4; ++i) {
        const int mbase = m0 + wr * 64 + i * 16 + (l4 << 2);
#pragma unroll
        for (int r = 0; r < 4; ++r) {
            const size_t rowoff = (size_t)(mbase + r) * HDIM + n0 + wn * 64 + l15;
#pragma unroll
            for (int j = 0; j < 4; ++j) {
                const float v = acc[i][j][r] + bvv[j];
                if (mode == 0)
                    ((u16*)outp)[rowoff + j * 16] = f2bf(silu_f(v));
                else
                    ((float*)outp)[rowoff + j * 16] = v;
            }
        }
    }
}

// ---------------------------------------------------------------------------
// Fused SiLU-attention + gating.  Round-17 structure + T14 K-prefetch:
// K(kt+1) loaded into REGISTERS at iteration top (full-iter latency cover),
// ds_written into kb after the mid-iteration barrier.  V stays glds-staged
// (already full-iter covered).  End-of-iter wait covers V glds + K ds_writes.
__global__ __launch_bounds__(256) void attn_fused(
    const u16* __restrict__ Qb, const u16* __restrict__ Kb,
    const u16* __restrict__ VTg, const u16* __restrict__ Ub,
    const float* __restrict__ rel, u16* __restrict__ G)
{
    extern __shared__ u16 alds[];
    u16* Ps = alds + 24576;
    float* relh = (float*)(alds + 33792);

    const int idx = blockIdx.x;
    const int bh8 = idx & 7;
    const int j = (idx >> 3) & 7;
    const int bhhi = idx >> 6;            // 0..7
    const int bh = bhhi * 8 + bh8;
    const int b = bh >> 4, h = bh & 15;
    const int qS0 = j * 64;               // short subtile
    const int qL0 = (15 - j) * 64;        // long subtile
    const int nkt = 16 - j;
    const int t = threadIdx.x, lane = t & 63, w = t >> 6;
    const int l15 = lane & 15, l4 = lane >> 4;
    const size_t rowbase = (size_t)b * SEQLEN;
    const int col0 = h * HEADD;
    const float scale = 0.088388347648318447f;   // 1/sqrt(128)

    for (int i = t; i < 1024; i += 256) relh[i] = rel[(size_t)(1023 + i) * NHEADS + h];

    const int rK = t >> 4;
    const int cK = (t & 15) ^ (rK & 7);
    const u16* gK = Kb + (rowbase + rK) * HDIM + col0 + cK * 8;
    const int rV = t >> 3;
    const int cV = (t & 7) ^ (rV & 7);
    const u16* gV = VTg + ((size_t)bh * HEADD + rV) * SEQLEN + cV * 8;
    const int sdst = w * 512;
    u16* kwdst = alds + sdst + (size_t)lane * 8;   // per-lane K ds_write dest

    bf16x8 aqL[4], aqS[4];
    {
        const int qrowL = qL0 + w * 16 + l15;
        const int qrowS = qS0 + w * 16 + l15;
#pragma unroll
        for (int dc = 0; dc < 4; ++dc) {
            aqL[dc] = *(const bf16x8*)&Qb[(rowbase + qrowL) * HDIM + col0 + dc * 32 + (l4 << 3)];
            aqS[dc] = *(const bf16x8*)&Qb[(rowbase + qrowS) * HDIM + col0 + dc * 32 + (l4 << 3)];
        }
    }

    f32x4 oaccL[8] = {}, oaccS[8] = {};

#define STAGE_K0(kt) do {                                                       \
    const size_t ko_ = (size_t)(kt) * 64;                                       \
    _Pragma("unroll") for (int c = 0; c < 4; ++c)                               \
        glds16(gK + (ko_ + c * 16) * HDIM, alds + c * 2048 + sdst);             \
} while (0)
#define STAGE_V(kt, bsel) do {                                                  \
    u16* vb_ = alds + 8192 + ((bsel) ? 8192 : 0);                               \
    const size_t ko_ = (size_t)(kt) * 64;                                       \
    _Pragma("unroll") for (int c = 0; c < 4; ++c)                               \
        glds16(gV + (size_t)c * 32 * SEQLEN + ko_, vb_ + c * 2048 + sdst);      \
} while (0)

    STAGE_K0(0); STAGE_V(0, 0);
    asm volatile("s_waitcnt vmcnt(0)" ::: "memory");
    __builtin_amdgcn_s_barrier();

    int cur = 0;
#pragma unroll 1
    for (int kt = 0; kt < nkt; ++kt) {
        const int k0 = kt * 64;
        const bool doS = (kt <= j);               // block-uniform
        const bool pfk = (kt + 1 < nkt);
        // Prefetch next tile: V via glds, K into registers (T14 split).
        if (pfk) STAGE_V(kt + 1, cur ^ 1);
        u16x8 kreg[4];
        if (pfk) {
            const size_t ko_ = (size_t)(kt + 1) * 64;
#pragma unroll
            for (int c = 0; c < 4; ++c)
                kreg[c] = *(const u16x8*)(gK + (ko_ + c * 16) * HDIM);
        }
        const u16* kb = alds;
        const u16* vb = alds + 8192 + (cur ? 8192 : 0);

        // QK^T + rel + causal mask + silu -> Ps
#pragma unroll
        for (int kf = 0; kf < 4; ++kf) {
            const int krow = kf * 16 + l15;
            f32x4 sL = {}, sS = {};
            __builtin_amdgcn_s_setprio(1);
#pragma unroll
            for (int dc = 0; dc < 4; ++dc) {
                bf16x8 bk = *(const bf16x8*)&kb[krow * 128 + (((dc * 4 + l4) ^ (krow & 7)) << 3)];
                sL = __builtin_amdgcn_mfma_f32_16x16x32_bf16(aqL[dc], bk, sL, 0, 0, 0);
                if (doS) sS = __builtin_amdgcn_mfma_f32_16x16x32_bf16(aqS[dc], bk, sS, 0, 0, 0);
            }
            __builtin_amdgcn_s_setprio(0);
            const int kabs = k0 + krow;
            const int prow = w * 16 + (l4 << 2);
#pragma unroll
            for (int r = 0; r < 4; ++r) {
                const int qabsL = qL0 + prow + r;
                float vL = 0.f;
                if (kabs <= qabsL) vL = silu_f(fmaf(sL[r], scale, relh[qabsL - kabs]));
                Ps[(prow + r) * 72 + kf * 16 + l15] = f2bf_t(vL);
            }
            if (doS) {
#pragma unroll
                for (int r = 0; r < 4; ++r) {
                    const int qabsS = qS0 + prow + r;
                    float vS = 0.f;
                    if (kabs <= qabsS) vS = silu_f(fmaf(sS[r], scale, relh[qabsS - kabs]));
                    Ps[(64 + prow + r) * 72 + kf * 16 + l15] = f2bf_t(vS);
                }
            }
        }
        asm volatile("s_waitcnt lgkmcnt(0)" ::: "memory");
        __builtin_amdgcn_s_barrier();                 // Kbuf free (QK^T reads done)
        if (pfk) {                                    // write next K from regs
#pragma unroll
            for (int c = 0; c < 4; ++c)
                *(u16x8*)&kwdst[c * 2048] = kreg[c];
        }

        // PV (Ps rows wave-private; V^T swizzled reads)
        bf16x8 apL[2], apS[2];
#pragma unroll
        for (int kc = 0; kc < 2; ++kc) {
            apL[kc] = *(const bf16x8*)&Ps[(w * 16 + l15) * 72 + kc * 32 + (l4 << 3)];
            if (doS) apS[kc] = *(const bf16x8*)&Ps[(64 + w * 16 + l15) * 72 + kc * 32 + (l4 << 3)];
        }
        __builtin_amdgcn_s_setprio(1);
#pragma unroll
        for (int df = 0; df < 8; ++df) {
            const int vrow = df * 16 + l15;
#pragma unroll
            for (int kc = 0; kc < 2; ++kc) {
                bf16x8 bv = *(const bf16x8*)&vb[vrow * 64 + (((kc * 4 + l4) ^ (vrow & 7)) << 3)];
                oaccL[df] = __builtin_amdgcn_mfma_f32_16x16x32_bf16(apL[kc], bv, oaccL[df], 0, 0, 0);
                if (doS) oaccS[df] = __builtin_amdgcn_mfma_f32_16x16x32_bf16(apS[kc], bv, oaccS[df], 0, 0, 0);
            }
        }
        __builtin_amdgcn_s_setprio(0);
        asm volatile("s_waitcnt vmcnt(0) lgkmcnt(0)" ::: "memory");  // V glds + K ds_writes done
        __builtin_amdgcn_s_barrier();
        cur ^= 1;
    }
#undef STAGE_K0
#undef STAGE_V

    // G = O * U, row-sweep order for coalescing
#pragma unroll
    for (int r = 0; r < 4; ++r) {
        const int qr = w * 16 + (l4 << 2) + r;
        const size_t rowL = (rowbase + qL0 + qr) * HDIM + col0 + l15;
        const size_t rowS = (rowbase + qS0 + qr) * HDIM + col0 + l15;
#pragma unroll
        for (int df = 0; df < 8; ++df)
            G[rowL + df * 16] = f2bf(oaccL[df][r] * bf2f(Ub[rowL + df * 16]));
#pragma unroll
        for (int df = 0; df < 8; ++df)
            G[rowS + df * 16] = f2bf(oaccS[df][r] * bf2f(Ub[rowS + df * 16]));
    }
}

// ---------------------------------------------------------------------------
extern "C" void kernel_launch(void* const* d_in, const int* in_sizes, int n_in,
                              void* d_out, int out_size, void* d_ws, size_t ws_size,
                              hipStream_t stream) {
    const float* query = (const float*)d_in[0];
    const float* key_  = (const float*)d_in[1];
    const float* value = (const float*)d_in[2];
    // d_in[3] attn_mask: causal by construction, handled analytically.
    const float* Wq  = (const float*)d_in[4];  const float* bq  = (const float*)d_in[5];
    const float* Wk  = (const float*)d_in[6];  const float* bk  = (const float*)d_in[7];
    const float* Wv  = (const float*)d_in[8];  const float* bv  = (const float*)d_in[9];
    const float* Wu  = (const float*)d_in[10]; const float* bu  = (const float*)d_in[11];
    const float* Wf2 = (const float*)d_in[12]; const float* bf2 = (const float*)d_in[13];
    const float* rel = (const float*)d_in[14];

    // Workspace (88 MiB): WTa 8 | Xbf 16 | Q(=G) 16 | K 16 | V 16 | U 16
    char* ws = (char*)d_ws;
    const size_t WBYTES = (size_t)HDIM * HDIM * 2;   // 8 MiB
    const size_t ABYTES = (size_t)4096 * HDIM * 2;   // 16 MiB
    u16* WTa  = (u16*)ws;
    u16* Xbf  = (u16*)(ws + WBYTES);
    u16* Qbuf = (u16*)(ws + WBYTES + 1 * ABYTES);
    u16* Kbuf = (u16*)(ws + WBYTES + 2 * ABYTES);
    u16* Vbuf = (u16*)(ws + WBYTES + 3 * ABYTES);
    u16* Ubuf = (u16*)(ws + WBYTES + 4 * ABYTES);
    u16* WTb  = Vbuf;          // borrowed: freed before V GEMM writes Vbuf
    u16* Gbuf = Qbuf;          // attn reads its own Q rows, then writes them as G
    u16* VTg  = Xbf;           // free after V GEMM; reused for transposed V

    dim3 tpb(256);
    dim3 tgrid(32, 32);        // W transpose tiles
    dim3 vgrid(32, 64);        // V transpose
    const int n8 = 4096 * HDIM / 8;
    const size_t GLDS  = 65536;  // 64 KiB for gemm128
    const size_t G8LDS = 131072; // 128 KiB for gemm256_8p
    const size_t ALDS  = 71680;  // 70 KiB for attn_fused

    f32_to_bf16<<<2048, tpb, 0, stream>>>(query, Xbf, n8);
    transpose_w<<<tgrid, tpb, 0, stream>>>(Wq, WTa);
    transpose_w<<<tgrid, tpb, 0, stream>>>(Wu, WTb);
    gemm256_8p<<<256, 512, G8LDS, stream>>>(Xbf, WTa, WTb, bq, bu, Qbuf, Ubuf);
    transpose_w<<<tgrid, tpb, 0, stream>>>(Wk, WTa);
    f32_to_bf16<<<2048, tpb, 0, stream>>>(key_, Xbf, n8);
    gemm128<<<512, tpb, GLDS, stream>>>(Xbf, WTa, bk, Kbuf, 0);
    transpose_w<<<tgrid, tpb, 0, stream>>>(Wv, WTa);
    f32_to_bf16<<<2048, tpb, 0, stream>>>(value, Xbf, n8);
    gemm128<<<512, tpb, GLDS, stream>>>(Xbf, WTa, bv, Vbuf, 0);
    transpose_v<<<vgrid, tpb, 0, stream>>>(Vbuf, VTg);
    attn_fused<<<512, tpb, ALDS, stream>>>(Qbuf, Kbuf, VTg, Ubuf, rel, Gbuf);
    transpose_w<<<tgrid, tpb, 0, stream>>>(Wf2, WTa);
    gemm128<<<512, tpb, GLDS, stream>>>(Gbuf, WTa, bf2, d_out, 1);
}

// Round 19
// 320.035 us; speedup vs baseline: 1.0443x; 1.0443x over previous
//
#include <hip/hip_runtime.h>
#include <stdint.h>

// Problem constants (B=4, S=1024, H=2048, NH=16, HD=128)
#define HDIM 2048
#define SEQLEN 1024
#define NHEADS 16
#define HEADD 128

typedef unsigned short u16;
typedef unsigned int u32;
typedef __attribute__((ext_vector_type(8))) short bf16x8;   // MFMA A/B frag
typedef __attribute__((ext_vector_type(8))) u16 u16x8;
typedef __attribute__((ext_vector_type(4))) u16 u16x4;
typedef __attribute__((ext_vector_type(4))) float f32x4;

__device__ __forceinline__ float bf2f(u16 u) {
    union { u32 i; float f; } v; v.i = ((u32)u) << 16; return v.f;
}
__device__ __forceinline__ u16 f2bf(float f) {
    union { float f; u32 i; } v; v.f = f;
    return (u16)((v.i + 0x7fffu + ((v.i >> 16) & 1u)) >> 16);  // RNE
}
__device__ __forceinline__ u16 f2bf_t(float f) {               // truncation (1 op)
    union { float f; u32 i; } v; v.f = f; return (u16)(v.i >> 16);
}
// Fast silu: x * rcp(1+exp(-x)).
__device__ __forceinline__ float silu_f(float x) {
    return x * __builtin_amdgcn_rcpf(1.f + __expf(-x));
}
// Async global->LDS, 16B per lane. LDS dest = wave-uniform base + lane*16.
__device__ __forceinline__ void glds16(const void* g, void* l) {
    __builtin_amdgcn_global_load_lds(
        (const __attribute__((address_space(1))) u32*)g,
        (__attribute__((address_space(3))) u32*)l, 16, 0, 0);
}

// ---------------------------------------------------------------------------
// f32 -> bf16 bulk convert (8 elems/thread/iter), n8 = n/8.
__global__ __launch_bounds__(256) void f32_to_bf16(const float* __restrict__ in,
                                                   u16* __restrict__ out, int n8) {
    int i = blockIdx.x * 256 + threadIdx.x;
    const int stride = gridDim.x * 256;
    for (; i < n8; i += stride) {
        f32x4 a = *(const f32x4*)&in[(size_t)i * 8];
        f32x4 b = *(const f32x4*)&in[(size_t)i * 8 + 4];
        u16x8 o;
#pragma unroll
        for (int j = 0; j < 4; ++j) { o[j] = f2bf(a[j]); o[4 + j] = f2bf(b[j]); }
        *(u16x8*)&out[(size_t)i * 8] = o;
    }
}

// ---------------------------------------------------------------------------
// Transpose + downconvert W[k][n] (2048x2048 f32) -> WT[n][k] bf16.
__global__ __launch_bounds__(256) void transpose_w(const float* __restrict__ W,
                                                   u16* __restrict__ WT) {
    __shared__ u16 T[64][76];   // 152B rows: 8B aligned, 4-way max on reads
    const int r0 = blockIdx.y * 64;   // k
    const int c0 = blockIdx.x * 64;   // n
    const int t = threadIdx.x;
#pragma unroll
    for (int c = t; c < 1024; c += 256) {
        const int r = c >> 4, cc = (c & 15) << 2;
        f32x4 v = *(const f32x4*)&W[(size_t)(r0 + r) * HDIM + c0 + cc];
        u16x4 o;
#pragma unroll
        for (int j = 0; j < 4; ++j) o[j] = f2bf(v[j]);
        *(u16x4*)&T[r][cc] = o;
    }
    __syncthreads();
#pragma unroll
    for (int c = t; c < 512; c += 256) {
        const int n = c >> 3, kc = (c & 7) << 3;   // lanes 0-7: same n, kc 0..56
        u16x8 v;
#pragma unroll
        for (int j = 0; j < 8; ++j) v[j] = T[kc + j][n];
        *(u16x8*)&WT[(size_t)(c0 + n) * HDIM + r0 + kc] = v;
    }
}

// ---------------------------------------------------------------------------
// Transpose V: Vbuf[b*1024+s][h*128+d] bf16 -> VTg[(bh*128+d)*1024+s] bf16.
__global__ __launch_bounds__(256) void transpose_v(const u16* __restrict__ V,
                                                   u16* __restrict__ VT) {
    __shared__ u16 T[64][76];
    const int bh = blockIdx.y;
    const int st = (blockIdx.x & 15) * 64;
    const int dt = (blockIdx.x >> 4) * 64;
    const int b = bh >> 4, h = bh & 15;
    const int t = threadIdx.x;
#pragma unroll
    for (int c = t; c < 1024; c += 256) {        // u16x4 loads (8B, aligned)
        const int s = c >> 4, d4 = (c & 15) << 2;
        *(u16x4*)&T[s][d4] =
            *(const u16x4*)&V[(size_t)(b * SEQLEN + st + s) * HDIM + h * HEADD + dt + d4];
    }
    __syncthreads();
#pragma unroll
    for (int c = t; c < 512; c += 256) {
        const int d = c >> 3, s8 = (c & 7) << 3;  // lanes 0-7: same d, s8 0..56
        u16x8 v;
#pragma unroll
        for (int j = 0; j < 8; ++j) v[j] = T[s8 + j][d];
        *(u16x8*)&VT[((size_t)bh * HEADD + dt + d) * SEQLEN + st + s8] = v;
    }
}

// ---------------------------------------------------------------------------
// 8-phase 256x256 GEMM, QU-fused (round-17, unchanged).
__global__ __launch_bounds__(512, 2) void gemm256_8p(
    const u16* __restrict__ X,
    const u16* __restrict__ WTq, const u16* __restrict__ WTu,
    const float* __restrict__ bq, const float* __restrict__ bu,
    u16* __restrict__ Qo, u16* __restrict__ Uo)
{
    extern __shared__ u16 lds[];   // 2 bufs x 32768 u16 (A @0, B @16384)
    const int t = threadIdx.x;
    const int lane = t & 63, wid = t >> 6;        // 8 waves
    const int l15 = lane & 15, l4 = lane >> 4;
    const int wr = wid >> 2, wn = wid & 3;        // 2M x 4N

    const int bid = blockIdx.x;                   // 256 blocks
    const int u = (bid & 7) * 32 + (bid >> 3);    // XCD-bijective
    const int tm = u & 15, tn = u >> 4;
    const int m0 = tm * 256;
    const int n0 = tn * 256;                      // 0..4095
    const u16* WT = (n0 < 2048) ? WTq : WTu;
    const float* bias = (n0 < 2048) ? bq : bu;
    u16* outp = (n0 < 2048) ? Qo : Uo;
    const int nc0 = n0 & 2047;

    const int r64 = t >> 3;                       // 0..63
    const int cse = (((t & 7) ^ (r64 & 7)) << 3);
    const u16* gA = X + (size_t)(m0 + r64) * HDIM + cse;
    const int rB0 = (r64 >> 5) * 64 + (r64 & 31);
    const u16* gB = WT + (size_t)(nc0 + rB0) * HDIM + cse;

    const int wbase = wid * 512;
    const int dstBw = (wid >> 2) * 4096 + (wid & 3) * 512;

    int offA[8][2], offB[4][2];
#pragma unroll
    for (int mf = 0; mf < 8; ++mf) {
        const int row = wr * 128 + mf * 16 + l15;
#pragma unroll
        for (int kk = 0; kk < 2; ++kk) {
            const int c = kk * 4 + l4;
            offA[mf][kk] = row * 64 + (((c) ^ (row & 7)) << 3);
        }
    }
#pragma unroll
    for (int nf = 0; nf < 4; ++nf) {
        const int row = wn * 64 + nf * 16 + l15;
#pragma unroll
        for (int kk = 0; kk < 2; ++kk) {
            const int c = kk * 4 + l4;
            offB[nf][kk] = 16384 + row * 64 + (((c) ^ (row & 7)) << 3);
        }
    }

#define SA(buf, rb, kt) glds16(gA + (size_t)(rb) * HDIM + (kt) * 64, \
                               lds + (buf) * 32768 + (rb) * 64 + wbase)
#define SB(buf, c, half, kt) glds16(gB + (size_t)((c) * 128 + (half) * 32) * HDIM + (kt) * 64, \
                               lds + (buf) * 32768 + 16384 + dstBw + (c) * 8192 + (half) * 2048)

    SA(0, 0, 0);    SA(0, 128, 0);
    SB(0, 0, 0, 0); SB(0, 1, 0, 0);
    SB(0, 0, 1, 0); SB(0, 1, 1, 0);
    SA(0, 64, 0);   SA(0, 192, 0);
    asm volatile("s_waitcnt vmcnt(4)" ::: "memory");
    __builtin_amdgcn_s_barrier();

    f32x4 acc[8][4] = {};
    int cur = 0;

#pragma unroll 1
    for (int kt = 0; kt < 32; ++kt) {
        const u16* pc = lds + cur * 32768;
        const int nb = cur ^ 1;
        const bool pf = (kt + 1 < 32);
        bf16x8 a[4][2], b0[2][2], b1[2][2];

        // ---- P1 ----
#pragma unroll
        for (int mf = 0; mf < 4; ++mf)
#pragma unroll
            for (int kk = 0; kk < 2; ++kk)
                a[mf][kk] = *(const bf16x8*)(pc + offA[mf][kk]);
#pragma unroll
        for (int nf = 0; nf < 2; ++nf)
#pragma unroll
            for (int kk = 0; kk < 2; ++kk)
                b0[nf][kk] = *(const bf16x8*)(pc + offB[nf][kk]);
        if (pf) { SA(nb, 0, kt + 1); SA(nb, 128, kt + 1); }
        __builtin_amdgcn_s_barrier();
        asm volatile("s_waitcnt lgkmcnt(0)");
        __builtin_amdgcn_sched_barrier(0);
        __builtin_amdgcn_s_setprio(1);
#pragma unroll
        for (int mf = 0; mf < 4; ++mf)
#pragma unroll
            for (int nf = 0; nf < 2; ++nf)
#pragma unroll
                for (int kk = 0; kk < 2; ++kk)
                    acc[mf][nf] = __builtin_amdgcn_mfma_f32_16x16x32_bf16(
                        a[mf][kk], b0[nf][kk], acc[mf][nf], 0, 0, 0);
        __builtin_amdgcn_s_setprio(0);
        if (pf) { asm volatile("s_waitcnt vmcnt(4)" ::: "memory"); }
        else    { asm volatile("s_waitcnt vmcnt(2)" ::: "memory"); }
        __builtin_amdgcn_s_barrier();

        // ---- P2 ----
#pragma unroll
        for (int nf = 0; nf < 2; ++nf)
#pragma unroll
            for (int kk = 0; kk < 2; ++kk)
                b1[nf][kk] = *(const bf16x8*)(pc + offB[2 + nf][kk]);
        if (pf) { SB(nb, 0, 0, kt + 1); SB(nb, 1, 0, kt + 1); }
        __builtin_amdgcn_s_barrier();
        asm volatile("s_waitcnt lgkmcnt(0)");
        __builtin_amdgcn_sched_barrier(0);
        __builtin_amdgcn_s_setprio(1);
#pragma unroll
        for (int mf = 0; mf < 4; ++mf)
#pragma unroll
            for (int nf = 0; nf < 2; ++nf)
#pragma unroll
                for (int kk = 0; kk < 2; ++kk)
                    acc[mf][2 + nf] = __builtin_amdgcn_mfma_f32_16x16x32_bf16(
                        a[mf][kk], b1[nf][kk], acc[mf][2 + nf], 0, 0, 0);
        __builtin_amdgcn_s_setprio(0);
        if (pf) { asm volatile("s_waitcnt vmcnt(4)" ::: "memory"); }
        else    { asm volatile("s_waitcnt vmcnt(0)" ::: "memory"); }
        __builtin_amdgcn_s_barrier();

        // ---- P3 ----
#pragma unroll
        for (int mf = 0; mf < 4; ++mf)
#pragma unroll
            for (int kk = 0; kk < 2; ++kk)
                a[mf][kk] = *(const bf16x8*)(pc + offA[4 + mf][kk]);
        if (pf) { SB(nb, 0, 1, kt + 1); SB(nb, 1, 1, kt + 1); }
        __builtin_amdgcn_s_barrier();
        asm volatile("s_waitcnt lgkmcnt(0)");
        __builtin_amdgcn_sched_barrier(0);
        __builtin_amdgcn_s_setprio(1);
#pragma unroll
        for (int mf = 0; mf < 4; ++mf)
#pragma unroll
            for (int nf = 0; nf < 2; ++nf)
#pragma unroll
                for (int kk = 0; kk < 2; ++kk)
                    acc[4 + mf][nf] = __builtin_amdgcn_mfma_f32_16x16x32_bf16(
                        a[mf][kk], b0[nf][kk], acc[4 + mf][nf], 0, 0, 0);
        __builtin_amdgcn_s_setprio(0);
        __builtin_amdgcn_s_barrier();

        // ---- P4 ----
        if (pf) { SA(nb, 64, kt + 1); SA(nb, 192, kt + 1); }
        __builtin_amdgcn_s_barrier();
        __builtin_amdgcn_s_setprio(1);
#pragma unroll
        for (int mf = 0; mf < 4; ++mf)
#pragma unroll
            for (int nf = 0; nf < 2; ++nf)
#pragma unroll
                for (int kk = 0; kk < 2; ++kk)
                    acc[4 + mf][2 + nf] = __builtin_amdgcn_mfma_f32_16x16x32_bf16(
                        a[mf][kk], b1[nf][kk], acc[4 + mf][2 + nf], 0, 0, 0);
        __builtin_amdgcn_s_setprio(0);
        if (pf) { asm volatile("s_waitcnt vmcnt(4)" ::: "memory"); }
        __builtin_amdgcn_s_barrier();
        cur ^= 1;
    }
#undef SA
#undef SB

    // Coalesced epilogue
    float bvv[4];
#pragma unroll
    for (int nf = 0; nf < 4; ++nf) bvv[nf] = bias[nc0 + wn * 64 + nf * 16 + l15];
#pragma unroll
    for (int mf = 0; mf < 8; ++mf) {
        const int mbase = m0 + wr * 128 + mf * 16 + (l4 << 2);
#pragma unroll
        for (int r = 0; r < 4; ++r) {
            u16* rowp = outp + (size_t)(mbase + r) * HDIM + nc0 + wn * 64 + l15;
#pragma unroll
            for (int nf = 0; nf < 4; ++nf)
                rowp[nf * 16] = f2bf(silu_f(acc[mf][nf][r] + bvv[nf]));
        }
    }
}

// ---------------------------------------------------------------------------
// Pipelined GEMM 128x128 (round-17, unchanged).
__global__ __launch_bounds__(256) void gemm128(
    const u16* __restrict__ X, const u16* __restrict__ WT,
    const float* __restrict__ bias, void* __restrict__ outp, const int mode)
{
    extern __shared__ u16 lds[];   // 2 bufs x (A 8192 + B 8192) u16 = 64 KiB
    const int t = threadIdx.x;
    const int lane = t & 63, wid = t >> 6;       // 4 waves
    const int l15 = lane & 15, l4 = lane >> 4;
    const int wr = wid >> 1, wn = wid & 1;

    const int bid = blockIdx.x;                  // 512 blocks
    const int u = (bid & 7) * 64 + (bid >> 3);   // XCD-bijective
    const int tm = u & 31, tn = u >> 5;
    const int m0 = tm * 128, n0 = tn * 128;

    const int ric = t >> 3;
    const int cse = (((t & 7) ^ (ric & 7)) << 3);
    const u16* gA = X  + (size_t)(m0 + ric) * HDIM + cse;
    const u16* gB = WT + (size_t)(n0 + ric) * HDIM + cse;

    u16* buf0 = lds;
    u16* buf1 = lds + 16384;
    const int wbase = wid * 512;

    int offA[4][2], offB[4][2];
#pragma unroll
    for (int i = 0; i < 4; ++i) {
        const int row = wr * 64 + i * 16 + l15;
#pragma unroll
        for (int kk = 0; kk < 2; ++kk)
            offA[i][kk] = ((row * 128 + kk * 64 + l4 * 16) ^ ((row & 7) << 4)) >> 1;
    }
#pragma unroll
    for (int j = 0; j < 4; ++j) {
        const int row = wn * 64 + j * 16 + l15;
#pragma unroll
        for (int kk = 0; kk < 2; ++kk)
            offB[j][kk] = 8192 + ((((row * 128 + kk * 64 + l4 * 16) ^ ((row & 7) << 4))) >> 1);
    }

#define STAGE_A(buf, c, kt) glds16(gA + (size_t)(c) * 32 * HDIM + (kt) * 64, (buf) + (c) * 2048 + wbase)
#define STAGE_B(buf, c, kt) glds16(gB + (size_t)(c) * 32 * HDIM + (kt) * 64, (buf) + 8192 + (c) * 2048 + wbase)

    STAGE_B(buf0, 0, 0); STAGE_B(buf0, 1, 0); STAGE_B(buf0, 2, 0); STAGE_B(buf0, 3, 0);
    STAGE_A(buf0, 0, 0); STAGE_A(buf0, 1, 0); STAGE_A(buf0, 2, 0); STAGE_A(buf0, 3, 0);
    STAGE_B(buf1, 0, 1); STAGE_B(buf1, 1, 1); STAGE_B(buf1, 2, 1); STAGE_B(buf1, 3, 1);
    STAGE_A(buf1, 0, 1); STAGE_A(buf1, 2, 1);
    asm volatile("s_waitcnt vmcnt(6)" ::: "memory");
    __builtin_amdgcn_s_barrier();

    f32x4 acc[4][4] = {};
    u16* pc = buf0;
    u16* pn = buf1;

#pragma unroll 1
    for (int tt = 0; tt < 32; ++tt) {
        bf16x8 bfr[4][2], afr[2][2];
#pragma unroll
        for (int j = 0; j < 4; ++j)
#pragma unroll
            for (int kk = 0; kk < 2; ++kk)
                bfr[j][kk] = *(const bf16x8*)(pc + offB[j][kk]);
#pragma unroll
        for (int i = 0; i < 2; ++i)
#pragma unroll
            for (int kk = 0; kk < 2; ++kk)
                afr[i][kk] = *(const bf16x8*)(pc + offA[i][kk]);
        if (tt + 1 < 32) { STAGE_A(pn, 1, tt + 1); STAGE_A(pn, 3, tt + 1); }
        __builtin_amdgcn_s_barrier();
        asm volatile("s_waitcnt lgkmcnt(0)");
        __builtin_amdgcn_sched_barrier(0);
        __builtin_amdgcn_s_setprio(1);
#pragma unroll
        for (int i = 0; i < 2; ++i)
#pragma unroll
            for (int j = 0; j < 4; ++j)
#pragma unroll
                for (int kk = 0; kk < 2; ++kk)
                    acc[i][j] = __builtin_amdgcn_mfma_f32_16x16x32_bf16(
                        afr[i][kk], bfr[j][kk], acc[i][j], 0, 0, 0);
        __builtin_amdgcn_s_setprio(0);
        __builtin_amdgcn_s_barrier();

#pragma unroll
        for (int i = 0; i < 2; ++i)
#pragma unroll
            for (int kk = 0; kk < 2; ++kk)
                afr[i][kk] = *(const bf16x8*)(pc + offA[2 + i][kk]);
        if (tt + 2 < 32) {
            STAGE_B(pc, 0, tt + 2); STAGE_B(pc, 1, tt + 2);
            STAGE_B(pc, 2, tt + 2); STAGE_B(pc, 3, tt + 2);
            STAGE_A(pc, 0, tt + 2); STAGE_A(pc, 2, tt + 2);
        }
        __builtin_amdgcn_s_barrier();
        asm volatile("s_waitcnt lgkmcnt(0)");
        __builtin_amdgcn_sched_barrier(0);
        __builtin_amdgcn_s_setprio(1);
#pragma unroll
        for (int i = 0; i < 2; ++i)
#pragma unroll
            for (int j = 0; j < 4; ++j)
#pragma unroll
                for (int kk = 0; kk < 2; ++kk)
                    acc[2 + i][j] = __builtin_amdgcn_mfma_f32_16x16x32_bf16(
                        afr[i][kk], bfr[j][kk], acc[2 + i][j], 0, 0, 0);
        __builtin_amdgcn_s_setprio(0);
        if (tt + 2 < 32)      { asm volatile("s_waitcnt vmcnt(6)" ::: "memory"); }
        else if (tt + 1 < 32) { asm volatile("s_waitcnt vmcnt(0)" ::: "memory"); }
        __builtin_amdgcn_s_barrier();
        u16* tmp = pc; pc = pn; pn = tmp;
    }
#undef STAGE_A
#undef STAGE_B

    float bvv[4];
#pragma unroll
    for (int j = 0; j < 4; ++j) bvv[j] = bias[n0 + wn * 64 + j * 16 + l15];
#pragma unroll
    for (int i = 0; i < 4; ++i) {
        const int mbase = m0 + wr * 64 + i * 16 + (l4 << 2);
#pragma unroll
        for (int r = 0; r < 4; ++r) {
            const size_t rowoff = (size_t)(mbase + r) * HDIM + n0 + wn * 64 + l15;
#pragma unroll
            for (int j = 0; j < 4; ++j) {
                const float v = acc[i][j][r] + bvv[j];
                if (mode == 0)
                    ((u16*)outp)[rowoff + j * 16] = f2bf(silu_f(v));
                else
                    ((float*)outp)[rowoff + j * 16] = v;
            }
        }
    }
}

// ---------------------------------------------------------------------------
// Fused SiLU-attention + gating, 8-wave split: waves 0-3 own the LONG
// subtile's 64 q-rows, waves 4-7 the SHORT subtile's (active only kt<=j).
// Same staging/ledger/LDS image as round 17 (2 glds/wave for K and V).
// LDS (u16): K [8192] @0, V dbuf [2][8192] @8192, Ps [128][72] @24576
// (rows 0-63 L, 64-127 S), relh f32[1024] @33792.  71680 B -> 2 blocks/CU,
// 16 waves/CU.
__global__ __launch_bounds__(512) void attn_fused(
    const u16* __restrict__ Qb, const u16* __restrict__ Kb,
    const u16* __restrict__ VTg, const u16* __restrict__ Ub,
    const float* __restrict__ rel, u16* __restrict__ G)
{
    extern __shared__ u16 alds[];
    u16* Ps = alds + 24576;
    float* relh = (float*)(alds + 33792);

    const int idx = blockIdx.x;
    const int bh8 = idx & 7;
    const int j = (idx >> 3) & 7;
    const int bhhi = idx >> 6;            // 0..7
    const int bh = bhhi * 8 + bh8;
    const int b = bh >> 4, h = bh & 15;
    const int qS0 = j * 64;               // short subtile
    const int qL0 = (15 - j) * 64;        // long subtile
    const int nkt = 16 - j;
    const int t = threadIdx.x, lane = t & 63, w = t >> 6;    // 8 waves
    const int wq = w & 3;
    const bool isL = (w < 4);
    const int l15 = lane & 15, l4 = lane >> 4, l3 = lane >> 3;
    const size_t rowbase = (size_t)b * SEQLEN;
    const int col0 = h * HEADD;
    const float scale = 0.088388347648318447f;   // 1/sqrt(128)

    for (int i = t; i < 1024; i += 512) relh[i] = rel[(size_t)(1023 + i) * NHEADS + h];

    // K staging: slot s = w*128 + i*64 + lane; row = s>>4, chunk = (s&15)^(row&7).
    // i=0: row = w*8+l4, chunk = (lane&15)^l4; i=1: row += 4, chunk ^= 4.
    const u16* gK0 = Kb + (rowbase + w * 8 + l4) * HDIM + col0 + ((lane & 15) ^ l4) * 8;
    const u16* gK1 = Kb + (rowbase + w * 8 + 4 + l4) * HDIM + col0 + ((lane & 15) ^ (l4 + 4)) * 8;
    // V staging: slot s = w*128 + i*64 + lane; row = s>>3 = w*16+i*8+l3, chunk=(lane&7)^l3.
    const u16* gV0 = VTg + ((size_t)bh * HEADD + w * 16 + l3) * SEQLEN + ((lane & 7) ^ l3) * 8;
    const u16* gV1 = VTg + ((size_t)bh * HEADD + w * 16 + 8 + l3) * SEQLEN + ((lane & 7) ^ l3) * 8;

    // Q A-frags: each wave its own subtile's 16 rows
    const int q0 = (isL ? qL0 : qS0) + wq * 16;
    bf16x8 aq[4];
#pragma unroll
    for (int dc = 0; dc < 4; ++dc)
        aq[dc] = *(const bf16x8*)&Qb[(rowbase + q0 + l15) * HDIM + col0 + dc * 32 + (l4 << 3)];

    f32x4 oacc[8] = {};
    const int prB = (isL ? 0 : 64) + wq * 16;     // Ps row base for this wave

#define STAGE_K(kt) do {                                                        \
    const size_t ko_ = (size_t)(kt) * 64 * HDIM;                                \
    glds16(gK0 + ko_, alds + w * 1024);                                         \
    glds16(gK1 + ko_, alds + w * 1024 + 512);                                   \
} while (0)
#define STAGE_V(kt, bsel) do {                                                  \
    u16* vb_ = alds + 8192 + ((bsel) ? 8192 : 0);                               \
    const size_t ko_ = (size_t)(kt) * 64;                                       \
    glds16(gV0 + ko_, vb_ + w * 1024);                                          \
    glds16(gV1 + ko_, vb_ + w * 1024 + 512);                                    \
} while (0)

    STAGE_K(0); STAGE_V(0, 0);
    asm volatile("s_waitcnt vmcnt(0)" ::: "memory");
    __builtin_amdgcn_s_barrier();

    int cur = 0;
#pragma unroll 1
    for (int kt = 0; kt < nkt; ++kt) {
        const int k0 = kt * 64;
        const bool act = isL || (kt <= j);        // wave-uniform
        if (kt + 1 < nkt) STAGE_V(kt + 1, cur ^ 1);
        const u16* kb = alds;
        const u16* vb = alds + 8192 + (cur ? 8192 : 0);

        // QK^T + rel + causal mask + silu -> Ps (active waves only)
        if (act) {
#pragma unroll
            for (int kf = 0; kf < 4; ++kf) {
                const int krow = kf * 16 + l15;
                f32x4 s = {};
                __builtin_amdgcn_s_setprio(1);
#pragma unroll
                for (int dc = 0; dc < 4; ++dc) {
                    bf16x8 bk = *(const bf16x8*)&kb[krow * 128 + (((dc * 4 + l4) ^ (krow & 7)) << 3)];
                    s = __builtin_amdgcn_mfma_f32_16x16x32_bf16(aq[dc], bk, s, 0, 0, 0);
                }
                __builtin_amdgcn_s_setprio(0);
                const int kabs = k0 + krow;
                const int pr = prB + (l4 << 2);
#pragma unroll
                for (int r = 0; r < 4; ++r) {
                    const int qabs = q0 + (l4 << 2) + r;
                    float v = 0.f;
                    if (kabs <= qabs) v = silu_f(fmaf(s[r], scale, relh[qabs - kabs]));
                    Ps[(pr + r) * 72 + kf * 16 + l15] = f2bf_t(v);
                }
            }
        }
        asm volatile("s_waitcnt lgkmcnt(0)" ::: "memory");
        __builtin_amdgcn_s_barrier();                 // Kbuf free (QK^T reads done)
        if (kt + 1 < nkt) STAGE_K(kt + 1);

        // PV (active waves only)
        if (act) {
            bf16x8 ap[2];
#pragma unroll
            for (int kc = 0; kc < 2; ++kc)
                ap[kc] = *(const bf16x8*)&Ps[(prB + l15) * 72 + kc * 32 + (l4 << 3)];
            __builtin_amdgcn_s_setprio(1);
#pragma unroll
            for (int df = 0; df < 8; ++df) {
                const int vrow = df * 16 + l15;
#pragma unroll
                for (int kc = 0; kc < 2; ++kc) {
                    bf16x8 bv = *(const bf16x8*)&vb[vrow * 64 + (((kc * 4 + l4) ^ (vrow & 7)) << 3)];
                    oacc[df] = __builtin_amdgcn_mfma_f32_16x16x32_bf16(ap[kc], bv, oacc[df], 0, 0, 0);
                }
            }
            __builtin_amdgcn_s_setprio(0);
        }
        asm volatile("s_waitcnt vmcnt(0) lgkmcnt(0)" ::: "memory");  // next K,V landed
        __builtin_amdgcn_s_barrier();
        cur ^= 1;
    }
#undef STAGE_K
#undef STAGE_V

    // G = O * U (each wave its own 16 rows), row-sweep for coalescing
#pragma unroll
    for (int r = 0; r < 4; ++r) {
        const int qr = q0 + (l4 << 2) + r;
        const size_t row = (rowbase + qr) * HDIM + col0 + l15;
#pragma unroll
        for (int df = 0; df < 8; ++df)
            G[row + df * 16] = f2bf(oacc[df][r] * bf2f(Ub[row + df * 16]));
    }
}

// ---------------------------------------------------------------------------
extern "C" void kernel_launch(void* const* d_in, const int* in_sizes, int n_in,
                              void* d_out, int out_size, void* d_ws, size_t ws_size,
                              hipStream_t stream) {
    const float* query = (const float*)d_in[0];
    const float* key_  = (const float*)d_in[1];
    const float* value = (const float*)d_in[2];
    // d_in[3] attn_mask: causal by construction, handled analytically.
    const float* Wq  = (const float*)d_in[4];  const float* bq  = (const float*)d_in[5];
    const float* Wk  = (const float*)d_in[6];  const float* bk  = (const float*)d_in[7];
    const float* Wv  = (const float*)d_in[8];  const float* bv  = (const float*)d_in[9];
    const float* Wu  = (const float*)d_in[10]; const float* bu  = (const float*)d_in[11];
    const float* Wf2 = (const float*)d_in[12]; const float* bf2 = (const float*)d_in[13];
    const float* rel = (const float*)d_in[14];

    // Workspace (88 MiB): WTa 8 | Xbf 16 | Q(=G) 16 | K 16 | V 16 | U 16
    char* ws = (char*)d_ws;
    const size_t WBYTES = (size_t)HDIM * HDIM * 2;   // 8 MiB
    const size_t ABYTES = (size_t)4096 * HDIM * 2;   // 16 MiB
    u16* WTa  = (u16*)ws;
    u16* Xbf  = (u16*)(ws + WBYTES);
    u16* Qbuf = (u16*)(ws + WBYTES + 1 * ABYTES);
    u16* Kbuf = (u16*)(ws + WBYTES + 2 * ABYTES);
    u16* Vbuf = (u16*)(ws + WBYTES + 3 * ABYTES);
    u16* Ubuf = (u16*)(ws + WBYTES + 4 * ABYTES);
    u16* WTb  = Vbuf;          // borrowed: freed before V GEMM writes Vbuf
    u16* Gbuf = Qbuf;          // attn reads its own Q rows, then writes them as G
    u16* VTg  = Xbf;           // free after V GEMM; reused for transposed V

    dim3 tpb(256);
    dim3 tgrid(32, 32);        // W transpose tiles
    dim3 vgrid(32, 64);        // V transpose
    const int n8 = 4096 * HDIM / 8;
    const size_t GLDS  = 65536;  // 64 KiB for gemm128
    const size_t G8LDS = 131072; // 128 KiB for gemm256_8p
    const size_t ALDS  = 71680;  // 70 KiB for attn_fused

    f32_to_bf16<<<2048, tpb, 0, stream>>>(query, Xbf, n8);
    transpose_w<<<tgrid, tpb, 0, stream>>>(Wq, WTa);
    transpose_w<<<tgrid, tpb, 0, stream>>>(Wu, WTb);
    gemm256_8p<<<256, 512, G8LDS, stream>>>(Xbf, WTa, WTb, bq, bu, Qbuf, Ubuf);
    transpose_w<<<tgrid, tpb, 0, stream>>>(Wk, WTa);
    f32_to_bf16<<<2048, tpb, 0, stream>>>(key_, Xbf, n8);
    gemm128<<<512, tpb, GLDS, stream>>>(Xbf, WTa, bk, Kbuf, 0);
    transpose_w<<<tgrid, tpb, 0, stream>>>(Wv, WTa);
    f32_to_bf16<<<2048, tpb, 0, stream>>>(value, Xbf, n8);
    gemm128<<<512, tpb, GLDS, stream>>>(Xbf, WTa, bv, Vbuf, 0);
    transpose_v<<<vgrid, tpb, 0, stream>>>(Vbuf, VTg);
    attn_fused<<<512, 512, ALDS, stream>>>(Qbuf, Kbuf, VTg, Ubuf, rel, Gbuf);
    transpose_w<<<tgrid, tpb, 0, stream>>>(Wf2, WTa);
    gemm128<<<512, tpb, GLDS, stream>>>(Gbuf, WTa, bf2, d_out, 1);
}

// Round 20
// 310.903 us; speedup vs baseline: 1.0749x; 1.0294x over previous
//
#include <hip/hip_runtime.h>
#include <stdint.h>

// Problem constants (B=4, S=1024, H=2048, NH=16, HD=128)
#define HDIM 2048
#define SEQLEN 1024
#define NHEADS 16
#define HEADD 128

typedef unsigned short u16;
typedef unsigned int u32;
typedef __attribute__((ext_vector_type(8))) short bf16x8;   // MFMA A/B frag
typedef __attribute__((ext_vector_type(8))) u16 u16x8;
typedef __attribute__((ext_vector_type(4))) u16 u16x4;
typedef __attribute__((ext_vector_type(4))) float f32x4;

__device__ __forceinline__ float bf2f(u16 u) {
    union { u32 i; float f; } v; v.i = ((u32)u) << 16; return v.f;
}
__device__ __forceinline__ u16 f2bf(float f) {
    union { float f; u32 i; } v; v.f = f;
    return (u16)((v.i + 0x7fffu + ((v.i >> 16) & 1u)) >> 16);  // RNE
}
__device__ __forceinline__ u16 f2bf_t(float f) {               // truncation (1 op)
    union { float f; u32 i; } v; v.f = f; return (u16)(v.i >> 16);
}
// Fast silu: x * rcp(1+exp(-x)).
__device__ __forceinline__ float silu_f(float x) {
    return x * __builtin_amdgcn_rcpf(1.f + __expf(-x));
}
// Async global->LDS, 16B per lane. LDS dest = wave-uniform base + lane*16.
__device__ __forceinline__ void glds16(const void* g, void* l) {
    __builtin_amdgcn_global_load_lds(
        (const __attribute__((address_space(1))) u32*)g,
        (__attribute__((address_space(3))) u32*)l, 16, 0, 0);
}

// ---------------------------------------------------------------------------
// f32 -> bf16 bulk convert (8 elems/thread/iter), n8 = n/8.
__global__ __launch_bounds__(256) void f32_to_bf16(const float* __restrict__ in,
                                                   u16* __restrict__ out, int n8) {
    int i = blockIdx.x * 256 + threadIdx.x;
    const int stride = gridDim.x * 256;
    for (; i < n8; i += stride) {
        f32x4 a = *(const f32x4*)&in[(size_t)i * 8];
        f32x4 b = *(const f32x4*)&in[(size_t)i * 8 + 4];
        u16x8 o;
#pragma unroll
        for (int j = 0; j < 4; ++j) { o[j] = f2bf(a[j]); o[4 + j] = f2bf(b[j]); }
        *(u16x8*)&out[(size_t)i * 8] = o;
    }
}

// ---------------------------------------------------------------------------
// Transpose + downconvert W[k][n] (2048x2048 f32) -> WT[n][k] bf16.
__global__ __launch_bounds__(256) void transpose_w(const float* __restrict__ W,
                                                   u16* __restrict__ WT) {
    __shared__ u16 T[64][76];   // 152B rows: 8B aligned, 4-way max on reads
    const int r0 = blockIdx.y * 64;   // k
    const int c0 = blockIdx.x * 64;   // n
    const int t = threadIdx.x;
#pragma unroll
    for (int c = t; c < 1024; c += 256) {
        const int r = c >> 4, cc = (c & 15) << 2;
        f32x4 v = *(const f32x4*)&W[(size_t)(r0 + r) * HDIM + c0 + cc];
        u16x4 o;
#pragma unroll
        for (int j = 0; j < 4; ++j) o[j] = f2bf(v[j]);
        *(u16x4*)&T[r][cc] = o;
    }
    __syncthreads();
#pragma unroll
    for (int c = t; c < 512; c += 256) {
        const int n = c >> 3, kc = (c & 7) << 3;   // lanes 0-7: same n, kc 0..56
        u16x8 v;
#pragma unroll
        for (int j = 0; j < 8; ++j) v[j] = T[kc + j][n];
        *(u16x8*)&WT[(size_t)(c0 + n) * HDIM + r0 + kc] = v;
    }
}

// ---------------------------------------------------------------------------
// Transpose V: Vbuf[b*1024+s][h*128+d] bf16 -> VTg[(bh*128+d)*1024+s] bf16.
__global__ __launch_bounds__(256) void transpose_v(const u16* __restrict__ V,
                                                   u16* __restrict__ VT) {
    __shared__ u16 T[64][76];
    const int bh = blockIdx.y;
    const int st = (blockIdx.x & 15) * 64;
    const int dt = (blockIdx.x >> 4) * 64;
    const int b = bh >> 4, h = bh & 15;
    const int t = threadIdx.x;
#pragma unroll
    for (int c = t; c < 1024; c += 256) {        // u16x4 loads (8B, aligned)
        const int s = c >> 4, d4 = (c & 15) << 2;
        *(u16x4*)&T[s][d4] =
            *(const u16x4*)&V[(size_t)(b * SEQLEN + st + s) * HDIM + h * HEADD + dt + d4];
    }
    __syncthreads();
#pragma unroll
    for (int c = t; c < 512; c += 256) {
        const int d = c >> 3, s8 = (c & 7) << 3;  // lanes 0-7: same d, s8 0..56
        u16x8 v;
#pragma unroll
        for (int j = 0; j < 8; ++j) v[j] = T[s8 + j][d];
        *(u16x8*)&VT[((size_t)bh * HEADD + dt + d) * SEQLEN + st + s8] = v;
    }
}

// ---------------------------------------------------------------------------
// 8-phase 256x256 GEMM, QU-fused.  Round-19 pipeline with P3+P4 MERGED:
// 3 phases per K-tile (6 barriers, clusters 16/16/32 MFMA).  Ledger
// (induction-verified): steady-state wait vmcnt(4) at each phase end —
// P1-end drains prev B-P2, P2-end drains prev A-P3, P3-end drains this
// tile's A-P1+B-P1.  Tail: vmcnt(2)/(0)/skip.
__global__ __launch_bounds__(512, 2) void gemm256_8p(
    const u16* __restrict__ X,
    const u16* __restrict__ WTq, const u16* __restrict__ WTu,
    const float* __restrict__ bq, const float* __restrict__ bu,
    u16* __restrict__ Qo, u16* __restrict__ Uo)
{
    extern __shared__ u16 lds[];   // 2 bufs x 32768 u16 (A @0, B @16384)
    const int t = threadIdx.x;
    const int lane = t & 63, wid = t >> 6;        // 8 waves
    const int l15 = lane & 15, l4 = lane >> 4;
    const int wr = wid >> 2, wn = wid & 3;        // 2M x 4N

    const int bid = blockIdx.x;                   // 256 blocks
    const int u = (bid & 7) * 32 + (bid >> 3);    // XCD-bijective
    const int tm = u & 15, tn = u >> 4;
    const int m0 = tm * 256;
    const int n0 = tn * 256;                      // 0..4095
    const u16* WT = (n0 < 2048) ? WTq : WTu;
    const float* bias = (n0 < 2048) ? bq : bu;
    u16* outp = (n0 < 2048) ? Qo : Uo;
    const int nc0 = n0 & 2047;

    const int r64 = t >> 3;                       // 0..63
    const int cse = (((t & 7) ^ (r64 & 7)) << 3);
    const u16* gA = X + (size_t)(m0 + r64) * HDIM + cse;
    const int rB0 = (r64 >> 5) * 64 + (r64 & 31);
    const u16* gB = WT + (size_t)(nc0 + rB0) * HDIM + cse;

    const int wbase = wid * 512;
    const int dstBw = (wid >> 2) * 4096 + (wid & 3) * 512;

    int offA[8][2], offB[4][2];
#pragma unroll
    for (int mf = 0; mf < 8; ++mf) {
        const int row = wr * 128 + mf * 16 + l15;
#pragma unroll
        for (int kk = 0; kk < 2; ++kk) {
            const int c = kk * 4 + l4;
            offA[mf][kk] = row * 64 + (((c) ^ (row & 7)) << 3);
        }
    }
#pragma unroll
    for (int nf = 0; nf < 4; ++nf) {
        const int row = wn * 64 + nf * 16 + l15;
#pragma unroll
        for (int kk = 0; kk < 2; ++kk) {
            const int c = kk * 4 + l4;
            offB[nf][kk] = 16384 + row * 64 + (((c) ^ (row & 7)) << 3);
        }
    }

#define SA(buf, rb, kt) glds16(gA + (size_t)(rb) * HDIM + (kt) * 64, \
                               lds + (buf) * 32768 + (rb) * 64 + wbase)
#define SB(buf, c, half, kt) glds16(gB + (size_t)((c) * 128 + (half) * 32) * HDIM + (kt) * 64, \
                               lds + (buf) * 32768 + 16384 + dstBw + (c) * 8192 + (half) * 2048)

    // Prologue: tile 0 units in issue order A-P1, B-P1, B-P2, A-P3 (8 glds)
    SA(0, 0, 0);    SA(0, 128, 0);
    SB(0, 0, 0, 0); SB(0, 1, 0, 0);
    SB(0, 0, 1, 0); SB(0, 1, 1, 0);
    SA(0, 64, 0);   SA(0, 192, 0);
    asm volatile("s_waitcnt vmcnt(4)" ::: "memory");   // A-P1,B-P1 landed
    __builtin_amdgcn_s_barrier();

    f32x4 acc[8][4] = {};
    int cur = 0;

#pragma unroll 1
    for (int kt = 0; kt < 32; ++kt) {
        const u16* pc = lds + cur * 32768;
        const int nb = cur ^ 1;
        const bool pf = (kt + 1 < 32);
        bf16x8 a[4][2], b0[2][2], b1[2][2];

        // ---- P1: read A mf0-3 + B nf0-1; issue A-P1(t+1) ----
#pragma unroll
        for (int mf = 0; mf < 4; ++mf)
#pragma unroll
            for (int kk = 0; kk < 2; ++kk)
                a[mf][kk] = *(const bf16x8*)(pc + offA[mf][kk]);
#pragma unroll
        for (int nf = 0; nf < 2; ++nf)
#pragma unroll
            for (int kk = 0; kk < 2; ++kk)
                b0[nf][kk] = *(const bf16x8*)(pc + offB[nf][kk]);
        if (pf) { SA(nb, 0, kt + 1); SA(nb, 128, kt + 1); }
        __builtin_amdgcn_s_barrier();
        asm volatile("s_waitcnt lgkmcnt(0)");
        __builtin_amdgcn_sched_barrier(0);
        __builtin_amdgcn_s_setprio(1);
#pragma unroll
        for (int mf = 0; mf < 4; ++mf)
#pragma unroll
            for (int nf = 0; nf < 2; ++nf)
#pragma unroll
                for (int kk = 0; kk < 2; ++kk)
                    acc[mf][nf] = __builtin_amdgcn_mfma_f32_16x16x32_bf16(
                        a[mf][kk], b0[nf][kk], acc[mf][nf], 0, 0, 0);
        __builtin_amdgcn_s_setprio(0);
        if (pf) { asm volatile("s_waitcnt vmcnt(4)" ::: "memory"); }
        else    { asm volatile("s_waitcnt vmcnt(2)" ::: "memory"); }
        __builtin_amdgcn_s_barrier();

        // ---- P2: read B nf2-3; issue B-P1(t+1) ----
#pragma unroll
        for (int nf = 0; nf < 2; ++nf)
#pragma unroll
            for (int kk = 0; kk < 2; ++kk)
                b1[nf][kk] = *(const bf16x8*)(pc + offB[2 + nf][kk]);
        if (pf) { SB(nb, 0, 0, kt + 1); SB(nb, 1, 0, kt + 1); }
        __builtin_amdgcn_s_barrier();
        asm volatile("s_waitcnt lgkmcnt(0)");
        __builtin_amdgcn_sched_barrier(0);
        __builtin_amdgcn_s_setprio(1);
#pragma unroll
        for (int mf = 0; mf < 4; ++mf)
#pragma unroll
            for (int nf = 0; nf < 2; ++nf)
#pragma unroll
                for (int kk = 0; kk < 2; ++kk)
                    acc[mf][2 + nf] = __builtin_amdgcn_mfma_f32_16x16x32_bf16(
                        a[mf][kk], b1[nf][kk], acc[mf][2 + nf], 0, 0, 0);
        __builtin_amdgcn_s_setprio(0);
        if (pf) { asm volatile("s_waitcnt vmcnt(4)" ::: "memory"); }
        else    { asm volatile("s_waitcnt vmcnt(0)" ::: "memory"); }
        __builtin_amdgcn_s_barrier();

        // ---- P3 (merged P3+P4): read A mf4-7; issue B-P2(t+1) + A-P3(t+1);
        //      32-MFMA cluster (quadrants q2+q3) ----
#pragma unroll
        for (int mf = 0; mf < 4; ++mf)
#pragma unroll
            for (int kk = 0; kk < 2; ++kk)
                a[mf][kk] = *(const bf16x8*)(pc + offA[4 + mf][kk]);
        if (pf) {
            SB(nb, 0, 1, kt + 1); SB(nb, 1, 1, kt + 1);
            SA(nb, 64, kt + 1);   SA(nb, 192, kt + 1);
        }
        __builtin_amdgcn_s_barrier();
        asm volatile("s_waitcnt lgkmcnt(0)");
        __builtin_amdgcn_sched_barrier(0);
        __builtin_amdgcn_s_setprio(1);
#pragma unroll
        for (int mf = 0; mf < 4; ++mf)
#pragma unroll
            for (int nf = 0; nf < 2; ++nf)
#pragma unroll
                for (int kk = 0; kk < 2; ++kk)
                    acc[4 + mf][nf] = __builtin_amdgcn_mfma_f32_16x16x32_bf16(
                        a[mf][kk], b0[nf][kk], acc[4 + mf][nf], 0, 0, 0);
#pragma unroll
        for (int mf = 0; mf < 4; ++mf)
#pragma unroll
            for (int nf = 0; nf < 2; ++nf)
#pragma unroll
                for (int kk = 0; kk < 2; ++kk)
                    acc[4 + mf][2 + nf] = __builtin_amdgcn_mfma_f32_16x16x32_bf16(
                        a[mf][kk], b1[nf][kk], acc[4 + mf][2 + nf], 0, 0, 0);
        __builtin_amdgcn_s_setprio(0);
        if (pf) { asm volatile("s_waitcnt vmcnt(4)" ::: "memory"); }
        __builtin_amdgcn_s_barrier();
        cur ^= 1;
    }
#undef SA
#undef SB

    // Coalesced epilogue
    float bvv[4];
#pragma unroll
    for (int nf = 0; nf < 4; ++nf) bvv[nf] = bias[nc0 + wn * 64 + nf * 16 + l15];
#pragma unroll
    for (int mf = 0; mf < 8; ++mf) {
        const int mbase = m0 + wr * 128 + mf * 16 + (l4 << 2);
#pragma unroll
        for (int r = 0; r < 4; ++r) {
            u16* rowp = outp + (size_t)(mbase + r) * HDIM + nc0 + wn * 64 + l15;
#pragma unroll
            for (int nf = 0; nf < 4; ++nf)
                rowp[nf * 16] = f2bf(silu_f(acc[mf][nf][r] + bvv[nf]));
        }
    }
}

// ---------------------------------------------------------------------------
// Pipelined GEMM 128x128 (round-17, unchanged).
__global__ __launch_bounds__(256) void gemm128(
    const u16* __restrict__ X, const u16* __restrict__ WT,
    const float* __restrict__ bias, void* __restrict__ outp, const int mode)
{
    extern __shared__ u16 lds[];   // 2 bufs x (A 8192 + B 8192) u16 = 64 KiB
    const int t = threadIdx.x;
    const int lane = t & 63, wid = t >> 6;       // 4 waves
    const int l15 = lane & 15, l4 = lane >> 4;
    const int wr = wid >> 1, wn = wid & 1;

    const int bid = blockIdx.x;                  // 512 blocks
    const int u = (bid & 7) * 64 + (bid >> 3);   // XCD-bijective
    const int tm = u & 31, tn = u >> 5;
    const int m0 = tm * 128, n0 = tn * 128;

    const int ric = t >> 3;
    const int cse = (((t & 7) ^ (ric & 7)) << 3);
    const u16* gA = X  + (size_t)(m0 + ric) * HDIM + cse;
    const u16* gB = WT + (size_t)(n0 + ric) * HDIM + cse;

    u16* buf0 = lds;
    u16* buf1 = lds + 16384;
    const int wbase = wid * 512;

    int offA[4][2], offB[4][2];
#pragma unroll
    for (int i = 0; i < 4; ++i) {
        const int row = wr * 64 + i * 16 + l15;
#pragma unroll
        for (int kk = 0; kk < 2; ++kk)
            offA[i][kk] = ((row * 128 + kk * 64 + l4 * 16) ^ ((row & 7) << 4)) >> 1;
    }
#pragma unroll
    for (int j = 0; j < 4; ++j) {
        const int row = wn * 64 + j * 16 + l15;
#pragma unroll
        for (int kk = 0; kk < 2; ++kk)
            offB[j][kk] = 8192 + ((((row * 128 + kk * 64 + l4 * 16) ^ ((row & 7) << 4))) >> 1);
    }

#define STAGE_A(buf, c, kt) glds16(gA + (size_t)(c) * 32 * HDIM + (kt) * 64, (buf) + (c) * 2048 + wbase)
#define STAGE_B(buf, c, kt) glds16(gB + (size_t)(c) * 32 * HDIM + (kt) * 64, (buf) + 8192 + (c) * 2048 + wbase)

    STAGE_B(buf0, 0, 0); STAGE_B(buf0, 1, 0); STAGE_B(buf0, 2, 0); STAGE_B(buf0, 3, 0);
    STAGE_A(buf0, 0, 0); STAGE_A(buf0, 1, 0); STAGE_A(buf0, 2, 0); STAGE_A(buf0, 3, 0);
    STAGE_B(buf1, 0, 1); STAGE_B(buf1, 1, 1); STAGE_B(buf1, 2, 1); STAGE_B(buf1, 3, 1);
    STAGE_A(buf1, 0, 1); STAGE_A(buf1, 2, 1);
    asm volatile("s_waitcnt vmcnt(6)" ::: "memory");
    __builtin_amdgcn_s_barrier();

    f32x4 acc[4][4] = {};
    u16* pc = buf0;
    u16* pn = buf1;

#pragma unroll 1
    for (int tt = 0; tt < 32; ++tt) {
        bf16x8 bfr[4][2], afr[2][2];
#pragma unroll
        for (int j = 0; j < 4; ++j)
#pragma unroll
            for (int kk = 0; kk < 2; ++kk)
                bfr[j][kk] = *(const bf16x8*)(pc + offB[j][kk]);
#pragma unroll
        for (int i = 0; i < 2; ++i)
#pragma unroll
            for (int kk = 0; kk < 2; ++kk)
                afr[i][kk] = *(const bf16x8*)(pc + offA[i][kk]);
        if (tt + 1 < 32) { STAGE_A(pn, 1, tt + 1); STAGE_A(pn, 3, tt + 1); }
        __builtin_amdgcn_s_barrier();
        asm volatile("s_waitcnt lgkmcnt(0)");
        __builtin_amdgcn_sched_barrier(0);
        __builtin_amdgcn_s_setprio(1);
#pragma unroll
        for (int i = 0; i < 2; ++i)
#pragma unroll
            for (int j = 0; j < 4; ++j)
#pragma unroll
                for (int kk = 0; kk < 2; ++kk)
                    acc[i][j] = __builtin_amdgcn_mfma_f32_16x16x32_bf16(
                        afr[i][kk], bfr[j][kk], acc[i][j], 0, 0, 0);
        __builtin_amdgcn_s_setprio(0);
        __builtin_amdgcn_s_barrier();

#pragma unroll
        for (int i = 0; i < 2; ++i)
#pragma unroll
            for (int kk = 0; kk < 2; ++kk)
                afr[i][kk] = *(const bf16x8*)(pc + offA[2 + i][kk]);
        if (tt + 2 < 32) {
            STAGE_B(pc, 0, tt + 2); STAGE_B(pc, 1, tt + 2);
            STAGE_B(pc, 2, tt + 2); STAGE_B(pc, 3, tt + 2);
            STAGE_A(pc, 0, tt + 2); STAGE_A(pc, 2, tt + 2);
        }
        __builtin_amdgcn_s_barrier();
        asm volatile("s_waitcnt lgkmcnt(0)");
        __builtin_amdgcn_sched_barrier(0);
        __builtin_amdgcn_s_setprio(1);
#pragma unroll
        for (int i = 0; i < 2; ++i)
#pragma unroll
            for (int j = 0; j < 4; ++j)
#pragma unroll
                for (int kk = 0; kk < 2; ++kk)
                    acc[2 + i][j] = __builtin_amdgcn_mfma_f32_16x16x32_bf16(
                        afr[i][kk], bfr[j][kk], acc[2 + i][j], 0, 0, 0);
        __builtin_amdgcn_s_setprio(0);
        if (tt + 2 < 32)      { asm volatile("s_waitcnt vmcnt(6)" ::: "memory"); }
        else if (tt + 1 < 32) { asm volatile("s_waitcnt vmcnt(0)" ::: "memory"); }
        __builtin_amdgcn_s_barrier();
        u16* tmp = pc; pc = pn; pn = tmp;
    }
#undef STAGE_A
#undef STAGE_B

    float bvv[4];
#pragma unroll
    for (int j = 0; j < 4; ++j) bvv[j] = bias[n0 + wn * 64 + j * 16 + l15];
#pragma unroll
    for (int i = 0; i < 4; ++i) {
        const int mbase = m0 + wr * 64 + i * 16 + (l4 << 2);
#pragma unroll
        for (int r = 0; r < 4; ++r) {
            const size_t rowoff = (size_t)(mbase + r) * HDIM + n0 + wn * 64 + l15;
#pragma unroll
            for (int j = 0; j < 4; ++j) {
                const float v = acc[i][j][r] + bvv[j];
                if (mode == 0)
                    ((u16*)outp)[rowoff + j * 16] = f2bf(silu_f(v));
                else
                    ((float*)outp)[rowoff + j * 16] = v;
            }
        }
    }
}

// ---------------------------------------------------------------------------
// Fused SiLU-attention + gating, 8-wave split (round-19) + diagonal-branch:
// only the diagonal k-tile needs the causal compare; earlier active tiles
// are fully unmasked (kabs < qabs guaranteed).
__global__ __launch_bounds__(512) void attn_fused(
    const u16* __restrict__ Qb, const u16* __restrict__ Kb,
    const u16* __restrict__ VTg, const u16* __restrict__ Ub,
    const float* __restrict__ rel, u16* __restrict__ G)
{
    extern __shared__ u16 alds[];
    u16* Ps = alds + 24576;
    float* relh = (float*)(alds + 33792);

    const int idx = blockIdx.x;
    const int bh8 = idx & 7;
    const int j = (idx >> 3) & 7;
    const int bhhi = idx >> 6;            // 0..7
    const int bh = bhhi * 8 + bh8;
    const int b = bh >> 4, h = bh & 15;
    const int qS0 = j * 64;               // short subtile
    const int qL0 = (15 - j) * 64;        // long subtile
    const int nkt = 16 - j;
    const int t = threadIdx.x, lane = t & 63, w = t >> 6;    // 8 waves
    const int wq = w & 3;
    const bool isL = (w < 4);
    const int l15 = lane & 15, l4 = lane >> 4, l3 = lane >> 3;
    const size_t rowbase = (size_t)b * SEQLEN;
    const int col0 = h * HEADD;
    const float scale = 0.088388347648318447f;   // 1/sqrt(128)

    for (int i = t; i < 1024; i += 512) relh[i] = rel[(size_t)(1023 + i) * NHEADS + h];

    const u16* gK0 = Kb + (rowbase + w * 8 + l4) * HDIM + col0 + ((lane & 15) ^ l4) * 8;
    const u16* gK1 = Kb + (rowbase + w * 8 + 4 + l4) * HDIM + col0 + ((lane & 15) ^ (l4 + 4)) * 8;
    const u16* gV0 = VTg + ((size_t)bh * HEADD + w * 16 + l3) * SEQLEN + ((lane & 7) ^ l3) * 8;
    const u16* gV1 = VTg + ((size_t)bh * HEADD + w * 16 + 8 + l3) * SEQLEN + ((lane & 7) ^ l3) * 8;

    const int q0 = (isL ? qL0 : qS0) + wq * 16;
    bf16x8 aq[4];
#pragma unroll
    for (int dc = 0; dc < 4; ++dc)
        aq[dc] = *(const bf16x8*)&Qb[(rowbase + q0 + l15) * HDIM + col0 + dc * 32 + (l4 << 3)];

    f32x4 oacc[8] = {};
    const int prB = (isL ? 0 : 64) + wq * 16;     // Ps row base for this wave

#define STAGE_K(kt) do {                                                        \
    const size_t ko_ = (size_t)(kt) * 64 * HDIM;                                \
    glds16(gK0 + ko_, alds + w * 1024);                                         \
    glds16(gK1 + ko_, alds + w * 1024 + 512);                                   \
} while (0)
#define STAGE_V(kt, bsel) do {                                                  \
    u16* vb_ = alds + 8192 + ((bsel) ? 8192 : 0);                               \
    const size_t ko_ = (size_t)(kt) * 64;                                       \
    glds16(gV0 + ko_, vb_ + w * 1024);                                          \
    glds16(gV1 + ko_, vb_ + w * 1024 + 512);                                    \
} while (0)

    STAGE_K(0); STAGE_V(0, 0);
    asm volatile("s_waitcnt vmcnt(0)" ::: "memory");
    __builtin_amdgcn_s_barrier();

    int cur = 0;
#pragma unroll 1
    for (int kt = 0; kt < nkt; ++kt) {
        const int k0 = kt * 64;
        const bool act = isL || (kt <= j);        // wave-uniform
        const bool diag = isL ? (kt == nkt - 1) : (kt == j);
        if (kt + 1 < nkt) STAGE_V(kt + 1, cur ^ 1);
        const u16* kb = alds;
        const u16* vb = alds + 8192 + (cur ? 8192 : 0);

        // QK^T + rel (+ mask only on diag tile) + silu -> Ps
        if (act) {
#pragma unroll
            for (int kf = 0; kf < 4; ++kf) {
                const int krow = kf * 16 + l15;
                f32x4 s = {};
                __builtin_amdgcn_s_setprio(1);
#pragma unroll
                for (int dc = 0; dc < 4; ++dc) {
                    bf16x8 bk = *(const bf16x8*)&kb[krow * 128 + (((dc * 4 + l4) ^ (krow & 7)) << 3)];
                    s = __builtin_amdgcn_mfma_f32_16x16x32_bf16(aq[dc], bk, s, 0, 0, 0);
                }
                __builtin_amdgcn_s_setprio(0);
                const int kabs = k0 + krow;
                const int pr = prB + (l4 << 2);
                if (diag) {
#pragma unroll
                    for (int r = 0; r < 4; ++r) {
                        const int qabs = q0 + (l4 << 2) + r;
                        float v = 0.f;
                        if (kabs <= qabs) v = silu_f(fmaf(s[r], scale, relh[qabs - kabs]));
                        Ps[(pr + r) * 72 + kf * 16 + l15] = f2bf_t(v);
                    }
                } else {
#pragma unroll
                    for (int r = 0; r < 4; ++r) {
                        const int qabs = q0 + (l4 << 2) + r;
                        const float v = silu_f(fmaf(s[r], scale, relh[qabs - kabs]));
                        Ps[(pr + r) * 72 + kf * 16 + l15] = f2bf_t(v);
                    }
                }
            }
        }
        asm volatile("s_waitcnt lgkmcnt(0)" ::: "memory");
        __builtin_amdgcn_s_barrier();                 // Kbuf free (QK^T reads done)
        if (kt + 1 < nkt) STAGE_K(kt + 1);

        // PV (active waves only)
        if (act) {
            bf16x8 ap[2];
#pragma unroll
            for (int kc = 0; kc < 2; ++kc)
                ap[kc] = *(const bf16x8*)&Ps[(prB + l15) * 72 + kc * 32 + (l4 << 3)];
            __builtin_amdgcn_s_setprio(1);
#pragma unroll
            for (int df = 0; df < 8; ++df) {
                const int vrow = df * 16 + l15;
#pragma unroll
                for (int kc = 0; kc < 2; ++kc) {
                    bf16x8 bv = *(const bf16x8*)&vb[vrow * 64 + (((kc * 4 + l4) ^ (vrow & 7)) << 3)];
                    oacc[df] = __builtin_amdgcn_mfma_f32_16x16x32_bf16(ap[kc], bv, oacc[df], 0, 0, 0);
                }
            }
            __builtin_amdgcn_s_setprio(0);
        }
        asm volatile("s_waitcnt vmcnt(0) lgkmcnt(0)" ::: "memory");  // next K,V landed
        __builtin_amdgcn_s_barrier();
        cur ^= 1;
    }
#undef STAGE_K
#undef STAGE_V

    // G = O * U (each wave its own 16 rows), row-sweep for coalescing
#pragma unroll
    for (int r = 0; r < 4; ++r) {
        const int qr = q0 + (l4 << 2) + r;
        const size_t row = (rowbase + qr) * HDIM + col0 + l15;
#pragma unroll
        for (int df = 0; df < 8; ++df)
            G[row + df * 16] = f2bf(oacc[df][r] * bf2f(Ub[row + df * 16]));
    }
}

// ---------------------------------------------------------------------------
extern "C" void kernel_launch(void* const* d_in, const int* in_sizes, int n_in,
                              void* d_out, int out_size, void* d_ws, size_t ws_size,
                              hipStream_t stream) {
    const float* query = (const float*)d_in[0];
    const float* key_  = (const float*)d_in[1];
    const float* value = (const float*)d_in[2];
    // d_in[3] attn_mask: causal by construction, handled analytically.
    const float* Wq  = (const float*)d_in[4];  const float* bq  = (const float*)d_in[5];
    const float* Wk  = (const float*)d_in[6];  const float* bk  = (const float*)d_in[7];
    const float* Wv  = (const float*)d_in[8];  const float* bv  = (const float*)d_in[9];
    const float* Wu  = (const float*)d_in[10]; const float* bu  = (const float*)d_in[11];
    const float* Wf2 = (const float*)d_in[12]; const float* bf2 = (const float*)d_in[13];
    const float* rel = (const float*)d_in[14];

    // Workspace (88 MiB): WTa 8 | Xbf 16 | Q(=G) 16 | K 16 | V 16 | U 16
    char* ws = (char*)d_ws;
    const size_t WBYTES = (size_t)HDIM * HDIM * 2;   // 8 MiB
    const size_t ABYTES = (size_t)4096 * HDIM * 2;   // 16 MiB
    u16* WTa  = (u16*)ws;
    u16* Xbf  = (u16*)(ws + WBYTES);
    u16* Qbuf = (u16*)(ws + WBYTES + 1 * ABYTES);
    u16* Kbuf = (u16*)(ws + WBYTES + 2 * ABYTES);
    u16* Vbuf = (u16*)(ws + WBYTES + 3 * ABYTES);
    u16* Ubuf = (u16*)(ws + WBYTES + 4 * ABYTES);
    u16* WTb  = Vbuf;          // borrowed: freed before V GEMM writes Vbuf
    u16* Gbuf = Qbuf;          // attn reads its own Q rows, then writes them as G
    u16* VTg  = Xbf;           // free after V GEMM; reused for transposed V

    dim3 tpb(256);
    dim3 tgrid(32, 32);        // W transpose tiles
    dim3 vgrid(32, 64);        // V transpose
    const int n8 = 4096 * HDIM / 8;
    const size_t GLDS  = 65536;  // 64 KiB for gemm128
    const size_t G8LDS = 131072; // 128 KiB for gemm256_8p
    const size_t ALDS  = 71680;  // 70 KiB for attn_fused

    f32_to_bf16<<<2048, tpb, 0, stream>>>(query, Xbf, n8);
    transpose_w<<<tgrid, tpb, 0, stream>>>(Wq, WTa);
    transpose_w<<<tgrid, tpb, 0, stream>>>(Wu, WTb);
    gemm256_8p<<<256, 512, G8LDS, stream>>>(Xbf, WTa, WTb, bq, bu, Qbuf, Ubuf);
    transpose_w<<<tgrid, tpb, 0, stream>>>(Wk, WTa);
    f32_to_bf16<<<2048, tpb, 0, stream>>>(key_, Xbf, n8);
    gemm128<<<512, tpb, GLDS, stream>>>(Xbf, WTa, bk, Kbuf, 0);
    transpose_w<<<tgrid, tpb, 0, stream>>>(Wv, WTa);
    f32_to_bf16<<<2048, tpb, 0, stream>>>(value, Xbf, n8);
    gemm128<<<512, tpb, GLDS, stream>>>(Xbf, WTa, bv, Vbuf, 0);
    transpose_v<<<vgrid, tpb, 0, stream>>>(Vbuf, VTg);
    attn_fused<<<512, 512, ALDS, stream>>>(Qbuf, Kbuf, VTg, Ubuf, rel, Gbuf);
    transpose_w<<<tgrid, tpb, 0, stream>>>(Wf2, WTa);
    gemm128<<<512, tpb, GLDS, stream>>>(Gbuf, WTa, bf2, d_out, 1);
}

// Round 21
// 299.725 us; speedup vs baseline: 1.1150x; 1.0373x over previous
//
#include <hip/hip_runtime.h>
#include <stdint.h>

// Problem constants (B=4, S=1024, H=2048, NH=16, HD=128)
#define HDIM 2048
#define SEQLEN 1024
#define NHEADS 16
#define HEADD 128

typedef unsigned short u16;
typedef unsigned int u32;
typedef __attribute__((ext_vector_type(8))) short bf16x8;   // MFMA A/B frag
typedef __attribute__((ext_vector_type(8))) u16 u16x8;
typedef __attribute__((ext_vector_type(4))) u16 u16x4;
typedef __attribute__((ext_vector_type(4))) float f32x4;

__device__ __forceinline__ float bf2f(u16 u) {
    union { u32 i; float f; } v; v.i = ((u32)u) << 16; return v.f;
}
__device__ __forceinline__ u16 f2bf(float f) {
    union { float f; u32 i; } v; v.f = f;
    return (u16)((v.i + 0x7fffu + ((v.i >> 16) & 1u)) >> 16);  // RNE
}
__device__ __forceinline__ u16 f2bf_t(float f) {               // truncation (1 op)
    union { float f; u32 i; } v; v.f = f; return (u16)(v.i >> 16);
}
// Fast silu: x * rcp(1+exp(-x)).
__device__ __forceinline__ float silu_f(float x) {
    return x * __builtin_amdgcn_rcpf(1.f + __expf(-x));
}
// Async global->LDS, 16B per lane. LDS dest = wave-uniform base + lane*16.
__device__ __forceinline__ void glds16(const void* g, void* l) {
    __builtin_amdgcn_global_load_lds(
        (const __attribute__((address_space(1))) u32*)g,
        (__attribute__((address_space(3))) u32*)l, 16, 0, 0);
}

// ---------------------------------------------------------------------------
// f32 -> bf16 bulk convert (8 elems/thread/iter), n8 = n/8.
__global__ __launch_bounds__(256) void f32_to_bf16(const float* __restrict__ in,
                                                   u16* __restrict__ out, int n8) {
    int i = blockIdx.x * 256 + threadIdx.x;
    const int stride = gridDim.x * 256;
    for (; i < n8; i += stride) {
        f32x4 a = *(const f32x4*)&in[(size_t)i * 8];
        f32x4 b = *(const f32x4*)&in[(size_t)i * 8 + 4];
        u16x8 o;
#pragma unroll
        for (int j = 0; j < 4; ++j) { o[j] = f2bf(a[j]); o[4 + j] = f2bf(b[j]); }
        *(u16x8*)&out[(size_t)i * 8] = o;
    }
}

// ---------------------------------------------------------------------------
// Transpose + downconvert W[k][n] (2048x2048 f32) -> WT[n][k] bf16.
__global__ __launch_bounds__(256) void transpose_w(const float* __restrict__ W,
                                                   u16* __restrict__ WT) {
    __shared__ u16 T[64][76];   // 152B rows: 8B aligned, 4-way max on reads
    const int r0 = blockIdx.y * 64;   // k
    const int c0 = blockIdx.x * 64;   // n
    const int t = threadIdx.x;
#pragma unroll
    for (int c = t; c < 1024; c += 256) {
        const int r = c >> 4, cc = (c & 15) << 2;
        f32x4 v = *(const f32x4*)&W[(size_t)(r0 + r) * HDIM + c0 + cc];
        u16x4 o;
#pragma unroll
        for (int j = 0; j < 4; ++j) o[j] = f2bf(v[j]);
        *(u16x4*)&T[r][cc] = o;
    }
    __syncthreads();
#pragma unroll
    for (int c = t; c < 512; c += 256) {
        const int n = c >> 3, kc = (c & 7) << 3;   // lanes 0-7: same n, kc 0..56
        u16x8 v;
#pragma unroll
        for (int j = 0; j < 8; ++j) v[j] = T[kc + j][n];
        *(u16x8*)&WT[(size_t)(c0 + n) * HDIM + r0 + kc] = v;
    }
}

// ---------------------------------------------------------------------------
// 256x256 GEMM, QU-fused, 2-phase schedule: per K-tile {Φ1: A mf0-3 x B all
// (32 MFMA), Φ2: A mf4-7 x B-in-regs (32 MFMA)}, 4 barriers, 2 counted waits.
// Ledger (induction): tile-entry invariant = A-P3(t) outstanding (2 loads);
// Φ1-end vmcnt(4) drains A-P3(t); Φ2-end vmcnt(2) drains U1(t+1)+B-P2(t+1).
__global__ __launch_bounds__(512, 2) void gemm256_8p(
    const u16* __restrict__ X,
    const u16* __restrict__ WTq, const u16* __restrict__ WTu,
    const float* __restrict__ bq, const float* __restrict__ bu,
    u16* __restrict__ Qo, u16* __restrict__ Uo)
{
    extern __shared__ u16 lds[];   // 2 bufs x 32768 u16 (A @0, B @16384)
    const int t = threadIdx.x;
    const int lane = t & 63, wid = t >> 6;        // 8 waves
    const int l15 = lane & 15, l4 = lane >> 4;
    const int wr = wid >> 2, wn = wid & 3;        // 2M x 4N

    const int bid = blockIdx.x;                   // 256 blocks
    const int u = (bid & 7) * 32 + (bid >> 3);    // XCD-bijective
    const int tm = u & 15, tn = u >> 4;
    const int m0 = tm * 256;
    const int n0 = tn * 256;                      // 0..4095
    const u16* WT = (n0 < 2048) ? WTq : WTu;
    const float* bias = (n0 < 2048) ? bq : bu;
    u16* outp = (n0 < 2048) ? Qo : Uo;
    const int nc0 = n0 & 2047;

    const int r64 = t >> 3;                       // 0..63
    const int cse = (((t & 7) ^ (r64 & 7)) << 3);
    const u16* gA = X + (size_t)(m0 + r64) * HDIM + cse;
    const int rB0 = (r64 >> 5) * 64 + (r64 & 31);
    const u16* gB = WT + (size_t)(nc0 + rB0) * HDIM + cse;

    const int wbase = wid * 512;
    const int dstBw = (wid >> 2) * 4096 + (wid & 3) * 512;

    int offA[8][2], offB[4][2];
#pragma unroll
    for (int mf = 0; mf < 8; ++mf) {
        const int row = wr * 128 + mf * 16 + l15;
#pragma unroll
        for (int kk = 0; kk < 2; ++kk) {
            const int c = kk * 4 + l4;
            offA[mf][kk] = row * 64 + (((c) ^ (row & 7)) << 3);
        }
    }
#pragma unroll
    for (int nf = 0; nf < 4; ++nf) {
        const int row = wn * 64 + nf * 16 + l15;
#pragma unroll
        for (int kk = 0; kk < 2; ++kk) {
            const int c = kk * 4 + l4;
            offB[nf][kk] = 16384 + row * 64 + (((c) ^ (row & 7)) << 3);
        }
    }

#define SA(buf, rb, kt) glds16(gA + (size_t)(rb) * HDIM + (kt) * 64, \
                               lds + (buf) * 32768 + (rb) * 64 + wbase)
#define SB(buf, c, half, kt) glds16(gB + (size_t)((c) * 128 + (half) * 32) * HDIM + (kt) * 64, \
                               lds + (buf) * 32768 + 16384 + dstBw + (c) * 8192 + (half) * 2048)

    // Prologue: U1(0)={A-P1,B-P1}, U2(0)={B-P2,A-P3}; vmcnt(2) leaves A-P3(0).
    SA(0, 0, 0);    SA(0, 128, 0);
    SB(0, 0, 0, 0); SB(0, 1, 0, 0);
    SB(0, 0, 1, 0); SB(0, 1, 1, 0);
    SA(0, 64, 0);   SA(0, 192, 0);
    asm volatile("s_waitcnt vmcnt(2)" ::: "memory");
    __builtin_amdgcn_s_barrier();

    f32x4 acc[8][4] = {};
    int cur = 0;

#pragma unroll 1
    for (int kt = 0; kt < 32; ++kt) {
        const u16* pc = lds + cur * 32768;
        const int nb = cur ^ 1;
        const bool pf = (kt + 1 < 32);
        bf16x8 a[4][2], b[4][2];

        // ---- Φ1: read A mf0-3 + B all; issue U1(t+1); 32 MFMA ----
#pragma unroll
        for (int mf = 0; mf < 4; ++mf)
#pragma unroll
            for (int kk = 0; kk < 2; ++kk)
                a[mf][kk] = *(const bf16x8*)(pc + offA[mf][kk]);
#pragma unroll
        for (int nf = 0; nf < 4; ++nf)
#pragma unroll
            for (int kk = 0; kk < 2; ++kk)
                b[nf][kk] = *(const bf16x8*)(pc + offB[nf][kk]);
        if (pf) { SA(nb, 0, kt + 1); SA(nb, 128, kt + 1);
                  SB(nb, 0, 0, kt + 1); SB(nb, 1, 0, kt + 1); }
        __builtin_amdgcn_s_barrier();
        asm volatile("s_waitcnt lgkmcnt(0)");
        __builtin_amdgcn_sched_barrier(0);
        __builtin_amdgcn_s_setprio(1);
#pragma unroll
        for (int mf = 0; mf < 4; ++mf)
#pragma unroll
            for (int nf = 0; nf < 4; ++nf)
#pragma unroll
                for (int kk = 0; kk < 2; ++kk)
                    acc[mf][nf] = __builtin_amdgcn_mfma_f32_16x16x32_bf16(
                        a[mf][kk], b[nf][kk], acc[mf][nf], 0, 0, 0);
        __builtin_amdgcn_s_setprio(0);
        if (pf) { asm volatile("s_waitcnt vmcnt(4)" ::: "memory"); }
        else    { asm volatile("s_waitcnt vmcnt(0)" ::: "memory"); }
        __builtin_amdgcn_s_barrier();

        // ---- Φ2: read A mf4-7 (B held in regs); issue U2(t+1); 32 MFMA ----
#pragma unroll
        for (int mf = 0; mf < 4; ++mf)
#pragma unroll
            for (int kk = 0; kk < 2; ++kk)
                a[mf][kk] = *(const bf16x8*)(pc + offA[4 + mf][kk]);
        if (pf) { SB(nb, 0, 1, kt + 1); SB(nb, 1, 1, kt + 1);
                  SA(nb, 64, kt + 1);   SA(nb, 192, kt + 1); }
        __builtin_amdgcn_s_barrier();
        asm volatile("s_waitcnt lgkmcnt(0)");
        __builtin_amdgcn_sched_barrier(0);
        __builtin_amdgcn_s_setprio(1);
#pragma unroll
        for (int mf = 0; mf < 4; ++mf)
#pragma unroll
            for (int nf = 0; nf < 4; ++nf)
#pragma unroll
                for (int kk = 0; kk < 2; ++kk)
                    acc[4 + mf][nf] = __builtin_amdgcn_mfma_f32_16x16x32_bf16(
                        a[mf][kk], b[nf][kk], acc[4 + mf][nf], 0, 0, 0);
        __builtin_amdgcn_s_setprio(0);
        if (pf) { asm volatile("s_waitcnt vmcnt(2)" ::: "memory"); }
        __builtin_amdgcn_s_barrier();
        cur ^= 1;
    }
#undef SA
#undef SB

    // Coalesced epilogue
    float bvv[4];
#pragma unroll
    for (int nf = 0; nf < 4; ++nf) bvv[nf] = bias[nc0 + wn * 64 + nf * 16 + l15];
#pragma unroll
    for (int mf = 0; mf < 8; ++mf) {
        const int mbase = m0 + wr * 128 + mf * 16 + (l4 << 2);
#pragma unroll
        for (int r = 0; r < 4; ++r) {
            u16* rowp = outp + (size_t)(mbase + r) * HDIM + nc0 + wn * 64 + l15;
#pragma unroll
            for (int nf = 0; nf < 4; ++nf)
                rowp[nf * 16] = f2bf(silu_f(acc[mf][nf][r] + bvv[nf]));
        }
    }
}

// ---------------------------------------------------------------------------
// Pipelined GEMM 128x128.  mode 0: silu->bf16; mode 1: bias->f32;
// mode 2: silu->bf16 written TRANSPOSED into VTg[(bh*128+d)*1024 + s]
// (block tile = exactly one (b,h) with s-range 128, d full) via padded LDS.
__global__ __launch_bounds__(256) void gemm128(
    const u16* __restrict__ X, const u16* __restrict__ WT,
    const float* __restrict__ bias, void* __restrict__ outp, const int mode)
{
    extern __shared__ u16 lds[];   // 2 bufs x (A 8192 + B 8192) u16 = 64 KiB
    const int t = threadIdx.x;
    const int lane = t & 63, wid = t >> 6;       // 4 waves
    const int l15 = lane & 15, l4 = lane >> 4;
    const int wr = wid >> 1, wn = wid & 1;

    const int bid = blockIdx.x;                  // 512 blocks
    const int u = (bid & 7) * 64 + (bid >> 3);   // XCD-bijective
    const int tm = u & 31, tn = u >> 5;
    const int m0 = tm * 128, n0 = tn * 128;

    const int ric = t >> 3;
    const int cse = (((t & 7) ^ (ric & 7)) << 3);
    const u16* gA = X  + (size_t)(m0 + ric) * HDIM + cse;
    const u16* gB = WT + (size_t)(n0 + ric) * HDIM + cse;

    u16* buf0 = lds;
    u16* buf1 = lds + 16384;
    const int wbase = wid * 512;

    int offA[4][2], offB[4][2];
#pragma unroll
    for (int i = 0; i < 4; ++i) {
        const int row = wr * 64 + i * 16 + l15;
#pragma unroll
        for (int kk = 0; kk < 2; ++kk)
            offA[i][kk] = ((row * 128 + kk * 64 + l4 * 16) ^ ((row & 7) << 4)) >> 1;
    }
#pragma unroll
    for (int j = 0; j < 4; ++j) {
        const int row = wn * 64 + j * 16 + l15;
#pragma unroll
        for (int kk = 0; kk < 2; ++kk)
            offB[j][kk] = 8192 + ((((row * 128 + kk * 64 + l4 * 16) ^ ((row & 7) << 4))) >> 1);
    }

#define STAGE_A(buf, c, kt) glds16(gA + (size_t)(c) * 32 * HDIM + (kt) * 64, (buf) + (c) * 2048 + wbase)
#define STAGE_B(buf, c, kt) glds16(gB + (size_t)(c) * 32 * HDIM + (kt) * 64, (buf) + 8192 + (c) * 2048 + wbase)

    STAGE_B(buf0, 0, 0); STAGE_B(buf0, 1, 0); STAGE_B(buf0, 2, 0); STAGE_B(buf0, 3, 0);
    STAGE_A(buf0, 0, 0); STAGE_A(buf0, 1, 0); STAGE_A(buf0, 2, 0); STAGE_A(buf0, 3, 0);
    STAGE_B(buf1, 0, 1); STAGE_B(buf1, 1, 1); STAGE_B(buf1, 2, 1); STAGE_B(buf1, 3, 1);
    STAGE_A(buf1, 0, 1); STAGE_A(buf1, 2, 1);
    asm volatile("s_waitcnt vmcnt(6)" ::: "memory");
    __builtin_amdgcn_s_barrier();

    f32x4 acc[4][4] = {};
    u16* pc = buf0;
    u16* pn = buf1;

#pragma unroll 1
    for (int tt = 0; tt < 32; ++tt) {
        bf16x8 bfr[4][2], afr[2][2];
#pragma unroll
        for (int j = 0; j < 4; ++j)
#pragma unroll
            for (int kk = 0; kk < 2; ++kk)
                bfr[j][kk] = *(const bf16x8*)(pc + offB[j][kk]);
#pragma unroll
        for (int i = 0; i < 2; ++i)
#pragma unroll
            for (int kk = 0; kk < 2; ++kk)
                afr[i][kk] = *(const bf16x8*)(pc + offA[i][kk]);
        if (tt + 1 < 32) { STAGE_A(pn, 1, tt + 1); STAGE_A(pn, 3, tt + 1); }
        __builtin_amdgcn_s_barrier();
        asm volatile("s_waitcnt lgkmcnt(0)");
        __builtin_amdgcn_sched_barrier(0);
        __builtin_amdgcn_s_setprio(1);
#pragma unroll
        for (int i = 0; i < 2; ++i)
#pragma unroll
            for (int j = 0; j < 4; ++j)
#pragma unroll
                for (int kk = 0; kk < 2; ++kk)
                    acc[i][j] = __builtin_amdgcn_mfma_f32_16x16x32_bf16(
                        afr[i][kk], bfr[j][kk], acc[i][j], 0, 0, 0);
        __builtin_amdgcn_s_setprio(0);
        __builtin_amdgcn_s_barrier();

#pragma unroll
        for (int i = 0; i < 2; ++i)
#pragma unroll
            for (int kk = 0; kk < 2; ++kk)
                afr[i][kk] = *(const bf16x8*)(pc + offA[2 + i][kk]);
        if (tt + 2 < 32) {
            STAGE_B(pc, 0, tt + 2); STAGE_B(pc, 1, tt + 2);
            STAGE_B(pc, 2, tt + 2); STAGE_B(pc, 3, tt + 2);
            STAGE_A(pc, 0, tt + 2); STAGE_A(pc, 2, tt + 2);
        }
        __builtin_amdgcn_s_barrier();
        asm volatile("s_waitcnt lgkmcnt(0)");
        __builtin_amdgcn_sched_barrier(0);
        __builtin_amdgcn_s_setprio(1);
#pragma unroll
        for (int i = 0; i < 2; ++i)
#pragma unroll
            for (int j = 0; j < 4; ++j)
#pragma unroll
                for (int kk = 0; kk < 2; ++kk)
                    acc[2 + i][j] = __builtin_amdgcn_mfma_f32_16x16x32_bf16(
                        afr[i][kk], bfr[j][kk], acc[2 + i][j], 0, 0, 0);
        __builtin_amdgcn_s_setprio(0);
        if (tt + 2 < 32)      { asm volatile("s_waitcnt vmcnt(6)" ::: "memory"); }
        else if (tt + 1 < 32) { asm volatile("s_waitcnt vmcnt(0)" ::: "memory"); }
        __builtin_amdgcn_s_barrier();
        u16* tmp = pc; pc = pn; pn = tmp;
    }
#undef STAGE_A
#undef STAGE_B

    float bvv[4];
#pragma unroll
    for (int j = 0; j < 4; ++j) bvv[j] = bias[n0 + wn * 64 + j * 16 + l15];

    if (mode == 2) {
        // silu -> LDS transposed tile Tv[d][s], pad 136 (16B-aligned rows)
        u16* Tv = lds;
        __syncthreads();   // all waves done with staging buffers
#pragma unroll
        for (int i = 0; i < 4; ++i)
#pragma unroll
            for (int r = 0; r < 4; ++r) {
                const int s = wr * 64 + i * 16 + (l4 << 2) + r;
#pragma unroll
                for (int j = 0; j < 4; ++j) {
                    const int d = wn * 64 + j * 16 + l15;
                    Tv[d * 136 + s] = f2bf(silu_f(acc[i][j][r] + bvv[j]));
                }
            }
        __syncthreads();
        const int bh = (m0 >> 10) * 16 + tn;     // b*16 + h
        const int s0 = m0 & 1023;
        u16* vt = (u16*)outp;
#pragma unroll
        for (int r8 = 0; r8 < 8; ++r8) {
            const int d = (t >> 4) + r8 * 16;
            const int s = (t & 15) * 8;
            u16x8 v = *(const u16x8*)&Tv[d * 136 + s];
            *(u16x8*)&vt[((size_t)bh * HEADD + d) * SEQLEN + s0 + s] = v;
        }
        return;
    }

#pragma unroll
    for (int i = 0; i < 4; ++i) {
        const int mbase = m0 + wr * 64 + i * 16 + (l4 << 2);
#pragma unroll
        for (int r = 0; r < 4; ++r) {
            const size_t rowoff = (size_t)(mbase + r) * HDIM + n0 + wn * 64 + l15;
#pragma unroll
            for (int j = 0; j < 4; ++j) {
                const float v = acc[i][j][r] + bvv[j];
                if (mode == 0)
                    ((u16*)outp)[rowoff + j * 16] = f2bf(silu_f(v));
                else
                    ((float*)outp)[rowoff + j * 16] = v;
            }
        }
    }
}

// ---------------------------------------------------------------------------
// Fused SiLU-attention + gating, 8-wave split + diagonal-branch (round-20).
__global__ __launch_bounds__(512) void attn_fused(
    const u16* __restrict__ Qb, const u16* __restrict__ Kb,
    const u16* __restrict__ VTg, const u16* __restrict__ Ub,
    const float* __restrict__ rel, u16* __restrict__ G)
{
    extern __shared__ u16 alds[];
    u16* Ps = alds + 24576;
    float* relh = (float*)(alds + 33792);

    const int idx = blockIdx.x;
    const int bh8 = idx & 7;
    const int j = (idx >> 3) & 7;
    const int bhhi = idx >> 6;            // 0..7
    const int bh = bhhi * 8 + bh8;
    const int b = bh >> 4, h = bh & 15;
    const int qS0 = j * 64;               // short subtile
    const int qL0 = (15 - j) * 64;        // long subtile
    const int nkt = 16 - j;
    const int t = threadIdx.x, lane = t & 63, w = t >> 6;    // 8 waves
    const int wq = w & 3;
    const bool isL = (w < 4);
    const int l15 = lane & 15, l4 = lane >> 4, l3 = lane >> 3;
    const size_t rowbase = (size_t)b * SEQLEN;
    const int col0 = h * HEADD;
    const float scale = 0.088388347648318447f;   // 1/sqrt(128)

    for (int i = t; i < 1024; i += 512) relh[i] = rel[(size_t)(1023 + i) * NHEADS + h];

    const u16* gK0 = Kb + (rowbase + w * 8 + l4) * HDIM + col0 + ((lane & 15) ^ l4) * 8;
    const u16* gK1 = Kb + (rowbase + w * 8 + 4 + l4) * HDIM + col0 + ((lane & 15) ^ (l4 + 4)) * 8;
    const u16* gV0 = VTg + ((size_t)bh * HEADD + w * 16 + l3) * SEQLEN + ((lane & 7) ^ l3) * 8;
    const u16* gV1 = VTg + ((size_t)bh * HEADD + w * 16 + 8 + l3) * SEQLEN + ((lane & 7) ^ l3) * 8;

    const int q0 = (isL ? qL0 : qS0) + wq * 16;
    bf16x8 aq[4];
#pragma unroll
    for (int dc = 0; dc < 4; ++dc)
        aq[dc] = *(const bf16x8*)&Qb[(rowbase + q0 + l15) * HDIM + col0 + dc * 32 + (l4 << 3)];

    f32x4 oacc[8] = {};
    const int prB = (isL ? 0 : 64) + wq * 16;     // Ps row base for this wave

#define STAGE_K(kt) do {                                                        \
    const size_t ko_ = (size_t)(kt) * 64 * HDIM;                                \
    glds16(gK0 + ko_, alds + w * 1024);                                         \
    glds16(gK1 + ko_, alds + w * 1024 + 512);                                   \
} while (0)
#define STAGE_V(kt, bsel) do {                                                  \
    u16* vb_ = alds + 8192 + ((bsel) ? 8192 : 0);                               \
    const size_t ko_ = (size_t)(kt) * 64;                                       \
    glds16(gV0 + ko_, vb_ + w * 1024);                                          \
    glds16(gV1 + ko_, vb_ + w * 1024 + 512);                                    \
} while (0)

    STAGE_K(0); STAGE_V(0, 0);
    asm volatile("s_waitcnt vmcnt(0)" ::: "memory");
    __builtin_amdgcn_s_barrier();

    int cur = 0;
#pragma unroll 1
    for (int kt = 0; kt < nkt; ++kt) {
        const int k0 = kt * 64;
        const bool act = isL || (kt <= j);        // wave-uniform
        const bool diag = isL ? (kt == nkt - 1) : (kt == j);
        if (kt + 1 < nkt) STAGE_V(kt + 1, cur ^ 1);
        const u16* kb = alds;
        const u16* vb = alds + 8192 + (cur ? 8192 : 0);

        // QK^T + rel (+ mask only on diag tile) + silu -> Ps
        if (act) {
#pragma unroll
            for (int kf = 0; kf < 4; ++kf) {
                const int krow = kf * 16 + l15;
                f32x4 s = {};
                __builtin_amdgcn_s_setprio(1);
#pragma unroll
                for (int dc = 0; dc < 4; ++dc) {
                    bf16x8 bk = *(const bf16x8*)&kb[krow * 128 + (((dc * 4 + l4) ^ (krow & 7)) << 3)];
                    s = __builtin_amdgcn_mfma_f32_16x16x32_bf16(aq[dc], bk, s, 0, 0, 0);
                }
                __builtin_amdgcn_s_setprio(0);
                const int kabs = k0 + krow;
                const int pr = prB + (l4 << 2);
                if (diag) {
#pragma unroll
                    for (int r = 0; r < 4; ++r) {
                        const int qabs = q0 + (l4 << 2) + r;
                        float v = 0.f;
                        if (kabs <= qabs) v = silu_f(fmaf(s[r], scale, relh[qabs - kabs]));
                        Ps[(pr + r) * 72 + kf * 16 + l15] = f2bf_t(v);
                    }
                } else {
#pragma unroll
                    for (int r = 0; r < 4; ++r) {
                        const int qabs = q0 + (l4 << 2) + r;
                        const float v = silu_f(fmaf(s[r], scale, relh[qabs - kabs]));
                        Ps[(pr + r) * 72 + kf * 16 + l15] = f2bf_t(v);
                    }
                }
            }
        }
        asm volatile("s_waitcnt lgkmcnt(0)" ::: "memory");
        __builtin_amdgcn_s_barrier();                 // Kbuf free (QK^T reads done)
        if (kt + 1 < nkt) STAGE_K(kt + 1);

        // PV (active waves only)
        if (act) {
            bf16x8 ap[2];
#pragma unroll
            for (int kc = 0; kc < 2; ++kc)
                ap[kc] = *(const bf16x8*)&Ps[(prB + l15) * 72 + kc * 32 + (l4 << 3)];
            __builtin_amdgcn_s_setprio(1);
#pragma unroll
            for (int df = 0; df < 8; ++df) {
                const int vrow = df * 16 + l15;
#pragma unroll
                for (int kc = 0; kc < 2; ++kc) {
                    bf16x8 bv = *(const bf16x8*)&vb[vrow * 64 + (((kc * 4 + l4) ^ (vrow & 7)) << 3)];
                    oacc[df] = __builtin_amdgcn_mfma_f32_16x16x32_bf16(ap[kc], bv, oacc[df], 0, 0, 0);
                }
            }
            __builtin_amdgcn_s_setprio(0);
        }
        asm volatile("s_waitcnt vmcnt(0) lgkmcnt(0)" ::: "memory");  // next K,V landed
        __builtin_amdgcn_s_barrier();
        cur ^= 1;
    }
#undef STAGE_K
#undef STAGE_V

    // G = O * U (each wave its own 16 rows), row-sweep for coalescing
#pragma unroll
    for (int r = 0; r < 4; ++r) {
        const int qr = q0 + (l4 << 2) + r;
        const size_t row = (rowbase + qr) * HDIM + col0 + l15;
#pragma unroll
        for (int df = 0; df < 8; ++df)
            G[row + df * 16] = f2bf(oacc[df][r] * bf2f(Ub[row + df * 16]));
    }
}

// ---------------------------------------------------------------------------
extern "C" void kernel_launch(void* const* d_in, const int* in_sizes, int n_in,
                              void* d_out, int out_size, void* d_ws, size_t ws_size,
                              hipStream_t stream) {
    const float* query = (const float*)d_in[0];
    const float* key_  = (const float*)d_in[1];
    const float* value = (const float*)d_in[2];
    // d_in[3] attn_mask: causal by construction, handled analytically.
    const float* Wq  = (const float*)d_in[4];  const float* bq  = (const float*)d_in[5];
    const float* Wk  = (const float*)d_in[6];  const float* bk  = (const float*)d_in[7];
    const float* Wv  = (const float*)d_in[8];  const float* bv  = (const float*)d_in[9];
    const float* Wu  = (const float*)d_in[10]; const float* bu  = (const float*)d_in[11];
    const float* Wf2 = (const float*)d_in[12]; const float* bf2 = (const float*)d_in[13];
    const float* rel = (const float*)d_in[14];

    // Workspace (88 MiB): WTa 8 | Xbf 16 | Q(=G) 16 | K 16 | VTg 16 | U 16
    char* ws = (char*)d_ws;
    const size_t WBYTES = (size_t)HDIM * HDIM * 2;   // 8 MiB
    const size_t ABYTES = (size_t)4096 * HDIM * 2;   // 16 MiB
    u16* WTa  = (u16*)ws;
    u16* Xbf  = (u16*)(ws + WBYTES);
    u16* Qbuf = (u16*)(ws + WBYTES + 1 * ABYTES);
    u16* Kbuf = (u16*)(ws + WBYTES + 2 * ABYTES);
    u16* VTg  = (u16*)(ws + WBYTES + 3 * ABYTES);    // V written transposed here
    u16* Ubuf = (u16*)(ws + WBYTES + 4 * ABYTES);
    u16* WTb  = VTg;           // borrowed for Wu^T: freed before V GEMM writes VTg
    u16* Gbuf = Qbuf;          // attn reads its own Q rows, then writes them as G

    dim3 tpb(256);
    dim3 tgrid(32, 32);        // W transpose tiles
    const int n8 = 4096 * HDIM / 8;
    const size_t GLDS  = 65536;  // 64 KiB for gemm128
    const size_t G8LDS = 131072; // 128 KiB for gemm256_8p
    const size_t ALDS  = 71680;  // 70 KiB for attn_fused

    f32_to_bf16<<<2048, tpb, 0, stream>>>(query, Xbf, n8);
    transpose_w<<<tgrid, tpb, 0, stream>>>(Wq, WTa);
    transpose_w<<<tgrid, tpb, 0, stream>>>(Wu, WTb);
    gemm256_8p<<<256, 512, G8LDS, stream>>>(Xbf, WTa, WTb, bq, bu, Qbuf, Ubuf);
    transpose_w<<<tgrid, tpb, 0, stream>>>(Wk, WTa);
    f32_to_bf16<<<2048, tpb, 0, stream>>>(key_, Xbf, n8);
    gemm128<<<512, tpb, GLDS, stream>>>(Xbf, WTa, bk, Kbuf, 0);
    transpose_w<<<tgrid, tpb, 0, stream>>>(Wv, WTa);
    f32_to_bf16<<<2048, tpb, 0, stream>>>(value, Xbf, n8);
    gemm128<<<512, tpb, GLDS, stream>>>(Xbf, WTa, bv, VTg, 2);   // V -> transposed
    attn_fused<<<512, 512, ALDS, stream>>>(Qbuf, Kbuf, VTg, Ubuf, rel, Gbuf);
    transpose_w<<<tgrid, tpb, 0, stream>>>(Wf2, WTa);
    gemm128<<<512, tpb, GLDS, stream>>>(Gbuf, WTa, bf2, d_out, 1);
}

// Round 22
// 293.130 us; speedup vs baseline: 1.1401x; 1.0225x over previous
//
#include <hip/hip_runtime.h>
#include <stdint.h>

// Problem constants (B=4, S=1024, H=2048, NH=16, HD=128)
#define HDIM 2048
#define SEQLEN 1024
#define NHEADS 16
#define HEADD 128

typedef unsigned short u16;
typedef unsigned int u32;
typedef __attribute__((ext_vector_type(8))) short bf16x8;   // MFMA A/B frag
typedef __attribute__((ext_vector_type(8))) u16 u16x8;
typedef __attribute__((ext_vector_type(4))) u16 u16x4;
typedef __attribute__((ext_vector_type(4))) float f32x4;

__device__ __forceinline__ float bf2f(u16 u) {
    union { u32 i; float f; } v; v.i = ((u32)u) << 16; return v.f;
}
__device__ __forceinline__ u16 f2bf(float f) {
    union { float f; u32 i; } v; v.f = f;
    return (u16)((v.i + 0x7fffu + ((v.i >> 16) & 1u)) >> 16);  // RNE
}
__device__ __forceinline__ u16 f2bf_t(float f) {               // truncation (1 op)
    union { float f; u32 i; } v; v.f = f; return (u16)(v.i >> 16);
}
// Fast silu: x * rcp(1+exp(-x)).
__device__ __forceinline__ float silu_f(float x) {
    return x * __builtin_amdgcn_rcpf(1.f + __expf(-x));
}
// Async global->LDS, 16B per lane. LDS dest = wave-uniform base + lane*16.
__device__ __forceinline__ void glds16(const void* g, void* l) {
    __builtin_amdgcn_global_load_lds(
        (const __attribute__((address_space(1))) u32*)g,
        (__attribute__((address_space(3))) u32*)l, 16, 0, 0);
}

// ---------------------------------------------------------------------------
// f32 -> bf16 bulk convert (8 elems/thread/iter), n8 = n/8.
__global__ __launch_bounds__(256) void f32_to_bf16(const float* __restrict__ in,
                                                   u16* __restrict__ out, int n8) {
    int i = blockIdx.x * 256 + threadIdx.x;
    const int stride = gridDim.x * 256;
    for (; i < n8; i += stride) {
        f32x4 a = *(const f32x4*)&in[(size_t)i * 8];
        f32x4 b = *(const f32x4*)&in[(size_t)i * 8 + 4];
        u16x8 o;
#pragma unroll
        for (int j = 0; j < 4; ++j) { o[j] = f2bf(a[j]); o[4 + j] = f2bf(b[j]); }
        *(u16x8*)&out[(size_t)i * 8] = o;
    }
}

// ---------------------------------------------------------------------------
// Transpose + downconvert W[k][n] (2048x2048 f32) -> WT[n][k] bf16.
__global__ __launch_bounds__(256) void transpose_w(const float* __restrict__ W,
                                                   u16* __restrict__ WT) {
    __shared__ u16 T[64][76];   // 152B rows: 8B aligned, 4-way max on reads
    const int r0 = blockIdx.y * 64;   // k
    const int c0 = blockIdx.x * 64;   // n
    const int t = threadIdx.x;
#pragma unroll
    for (int c = t; c < 1024; c += 256) {
        const int r = c >> 4, cc = (c & 15) << 2;
        f32x4 v = *(const f32x4*)&W[(size_t)(r0 + r) * HDIM + c0 + cc];
        u16x4 o;
#pragma unroll
        for (int j = 0; j < 4; ++j) o[j] = f2bf(v[j]);
        *(u16x4*)&T[r][cc] = o;
    }
    __syncthreads();
#pragma unroll
    for (int c = t; c < 512; c += 256) {
        const int n = c >> 3, kc = (c & 7) << 3;   // lanes 0-7: same n, kc 0..56
        u16x8 v;
#pragma unroll
        for (int j = 0; j < 8; ++j) v[j] = T[kc + j][n];
        *(u16x8*)&WT[(size_t)(c0 + n) * HDIM + r0 + kc] = v;
    }
}

// ---------------------------------------------------------------------------
// 256x256 GEMM, QU-fused, 2-phase schedule, compiler-scheduled LDS waits:
// per K-tile {Φ1: A mf0-3 x B all (32 MFMA), Φ2: A mf4-7 x B-in-regs (32
// MFMA)}; 2 barriers/tile.  No explicit lgkmcnt/sched_barrier — plain-HIP
// ds_reads get fine-grained compiler waits interleaved with MFMA.  Counted
// vmcnt ledger unchanged: Φ1-end vmcnt(4) drains A-P3(t) (cross-wave need
// for Φ2 reads); Φ2-end vmcnt(2) drains U1(t+1) for next Φ1.
__global__ __launch_bounds__(512, 2) void gemm256_8p(
    const u16* __restrict__ X,
    const u16* __restrict__ WTq, const u16* __restrict__ WTu,
    const float* __restrict__ bq, const float* __restrict__ bu,
    u16* __restrict__ Qo, u16* __restrict__ Uo)
{
    extern __shared__ u16 lds[];   // 2 bufs x 32768 u16 (A @0, B @16384)
    const int t = threadIdx.x;
    const int lane = t & 63, wid = t >> 6;        // 8 waves
    const int l15 = lane & 15, l4 = lane >> 4;
    const int wr = wid >> 2, wn = wid & 3;        // 2M x 4N

    const int bid = blockIdx.x;                   // 256 blocks
    const int u = (bid & 7) * 32 + (bid >> 3);    // XCD-bijective
    const int tm = u & 15, tn = u >> 4;
    const int m0 = tm * 256;
    const int n0 = tn * 256;                      // 0..4095
    const u16* WT = (n0 < 2048) ? WTq : WTu;
    const float* bias = (n0 < 2048) ? bq : bu;
    u16* outp = (n0 < 2048) ? Qo : Uo;
    const int nc0 = n0 & 2047;

    const int r64 = t >> 3;                       // 0..63
    const int cse = (((t & 7) ^ (r64 & 7)) << 3);
    const u16* gA = X + (size_t)(m0 + r64) * HDIM + cse;
    const int rB0 = (r64 >> 5) * 64 + (r64 & 31);
    const u16* gB = WT + (size_t)(nc0 + rB0) * HDIM + cse;

    const int wbase = wid * 512;
    const int dstBw = (wid >> 2) * 4096 + (wid & 3) * 512;

    int offA[8][2], offB[4][2];
#pragma unroll
    for (int mf = 0; mf < 8; ++mf) {
        const int row = wr * 128 + mf * 16 + l15;
#pragma unroll
        for (int kk = 0; kk < 2; ++kk) {
            const int c = kk * 4 + l4;
            offA[mf][kk] = row * 64 + (((c) ^ (row & 7)) << 3);
        }
    }
#pragma unroll
    for (int nf = 0; nf < 4; ++nf) {
        const int row = wn * 64 + nf * 16 + l15;
#pragma unroll
        for (int kk = 0; kk < 2; ++kk) {
            const int c = kk * 4 + l4;
            offB[nf][kk] = 16384 + row * 64 + (((c) ^ (row & 7)) << 3);
        }
    }

#define SA(buf, rb, kt) glds16(gA + (size_t)(rb) * HDIM + (kt) * 64, \
                               lds + (buf) * 32768 + (rb) * 64 + wbase)
#define SB(buf, c, half, kt) glds16(gB + (size_t)((c) * 128 + (half) * 32) * HDIM + (kt) * 64, \
                               lds + (buf) * 32768 + 16384 + dstBw + (c) * 8192 + (half) * 2048)

    // Prologue: U1(0)={A-P1,B-P1}, U2(0)={B-P2,A-P3}; vmcnt(2) leaves A-P3(0).
    SA(0, 0, 0);    SA(0, 128, 0);
    SB(0, 0, 0, 0); SB(0, 1, 0, 0);
    SB(0, 0, 1, 0); SB(0, 1, 1, 0);
    SA(0, 64, 0);   SA(0, 192, 0);
    asm volatile("s_waitcnt vmcnt(2)" ::: "memory");
    __builtin_amdgcn_s_barrier();

    f32x4 acc[8][4] = {};
    int cur = 0;

#pragma unroll 1
    for (int kt = 0; kt < 32; ++kt) {
        const u16* pc = lds + cur * 32768;
        const int nb = cur ^ 1;
        const bool pf = (kt + 1 < 32);
        bf16x8 a[4][2], b[4][2];

        // ---- Φ1: read A mf0-3 + B all; issue U1(t+1); 32 MFMA ----
#pragma unroll
        for (int mf = 0; mf < 4; ++mf)
#pragma unroll
            for (int kk = 0; kk < 2; ++kk)
                a[mf][kk] = *(const bf16x8*)(pc + offA[mf][kk]);
#pragma unroll
        for (int nf = 0; nf < 4; ++nf)
#pragma unroll
            for (int kk = 0; kk < 2; ++kk)
                b[nf][kk] = *(const bf16x8*)(pc + offB[nf][kk]);
        if (pf) { SA(nb, 0, kt + 1); SA(nb, 128, kt + 1);
                  SB(nb, 0, 0, kt + 1); SB(nb, 1, 0, kt + 1); }
        __builtin_amdgcn_s_setprio(1);
#pragma unroll
        for (int mf = 0; mf < 4; ++mf)
#pragma unroll
            for (int nf = 0; nf < 4; ++nf)
#pragma unroll
                for (int kk = 0; kk < 2; ++kk)
                    acc[mf][nf] = __builtin_amdgcn_mfma_f32_16x16x32_bf16(
                        a[mf][kk], b[nf][kk], acc[mf][nf], 0, 0, 0);
        __builtin_amdgcn_s_setprio(0);
        if (pf) { asm volatile("s_waitcnt vmcnt(4)" ::: "memory"); }
        else    { asm volatile("s_waitcnt vmcnt(0)" ::: "memory"); }
        __builtin_amdgcn_s_barrier();

        // ---- Φ2: read A mf4-7 (B held in regs); issue U2(t+1); 32 MFMA ----
#pragma unroll
        for (int mf = 0; mf < 4; ++mf)
#pragma unroll
            for (int kk = 0; kk < 2; ++kk)
                a[mf][kk] = *(const bf16x8*)(pc + offA[4 + mf][kk]);
        if (pf) { SB(nb, 0, 1, kt + 1); SB(nb, 1, 1, kt + 1);
                  SA(nb, 64, kt + 1);   SA(nb, 192, kt + 1); }
        __builtin_amdgcn_s_setprio(1);
#pragma unroll
        for (int mf = 0; mf < 4; ++mf)
#pragma unroll
            for (int nf = 0; nf < 4; ++nf)
#pragma unroll
                for (int kk = 0; kk < 2; ++kk)
                    acc[4 + mf][nf] = __builtin_amdgcn_mfma_f32_16x16x32_bf16(
                        a[mf][kk], b[nf][kk], acc[4 + mf][nf], 0, 0, 0);
        __builtin_amdgcn_s_setprio(0);
        if (pf) {
            asm volatile("s_waitcnt vmcnt(2)" ::: "memory");
            __builtin_amdgcn_s_barrier();
        }
        cur ^= 1;
    }
#undef SA
#undef SB

    // Coalesced epilogue
    float bvv[4];
#pragma unroll
    for (int nf = 0; nf < 4; ++nf) bvv[nf] = bias[nc0 + wn * 64 + nf * 16 + l15];
#pragma unroll
    for (int mf = 0; mf < 8; ++mf) {
        const int mbase = m0 + wr * 128 + mf * 16 + (l4 << 2);
#pragma unroll
        for (int r = 0; r < 4; ++r) {
            u16* rowp = outp + (size_t)(mbase + r) * HDIM + nc0 + wn * 64 + l15;
#pragma unroll
            for (int nf = 0; nf < 4; ++nf)
                rowp[nf * 16] = f2bf(silu_f(acc[mf][nf][r] + bvv[nf]));
        }
    }
}

// ---------------------------------------------------------------------------
// Pipelined GEMM 128x128, compiler-scheduled LDS waits (2 barriers/tile).
// ph1-end barrier kept: guards ph2's in-place pc overwrite against ph1
// readers (reads complete before barrier via MFMA-forced waits).
// mode 0: silu->bf16; mode 1: bias->f32; mode 2: silu->bf16 transposed
// into VTg[(bh*128+d)*1024+s] via padded LDS.
__global__ __launch_bounds__(256) void gemm128(
    const u16* __restrict__ X, const u16* __restrict__ WT,
    const float* __restrict__ bias, void* __restrict__ outp, const int mode)
{
    extern __shared__ u16 lds[];   // 2 bufs x (A 8192 + B 8192) u16 = 64 KiB
    const int t = threadIdx.x;
    const int lane = t & 63, wid = t >> 6;       // 4 waves
    const int l15 = lane & 15, l4 = lane >> 4;
    const int wr = wid >> 1, wn = wid & 1;

    const int bid = blockIdx.x;                  // 512 blocks
    const int u = (bid & 7) * 64 + (bid >> 3);   // XCD-bijective
    const int tm = u & 31, tn = u >> 5;
    const int m0 = tm * 128, n0 = tn * 128;

    const int ric = t >> 3;
    const int cse = (((t & 7) ^ (ric & 7)) << 3);
    const u16* gA = X  + (size_t)(m0 + ric) * HDIM + cse;
    const u16* gB = WT + (size_t)(n0 + ric) * HDIM + cse;

    u16* buf0 = lds;
    u16* buf1 = lds + 16384;
    const int wbase = wid * 512;

    int offA[4][2], offB[4][2];
#pragma unroll
    for (int i = 0; i < 4; ++i) {
        const int row = wr * 64 + i * 16 + l15;
#pragma unroll
        for (int kk = 0; kk < 2; ++kk)
            offA[i][kk] = ((row * 128 + kk * 64 + l4 * 16) ^ ((row & 7) << 4)) >> 1;
    }
#pragma unroll
    for (int j = 0; j < 4; ++j) {
        const int row = wn * 64 + j * 16 + l15;
#pragma unroll
        for (int kk = 0; kk < 2; ++kk)
            offB[j][kk] = 8192 + ((((row * 128 + kk * 64 + l4 * 16) ^ ((row & 7) << 4))) >> 1);
    }

#define STAGE_A(buf, c, kt) glds16(gA + (size_t)(c) * 32 * HDIM + (kt) * 64, (buf) + (c) * 2048 + wbase)
#define STAGE_B(buf, c, kt) glds16(gB + (size_t)(c) * 32 * HDIM + (kt) * 64, (buf) + 8192 + (c) * 2048 + wbase)

    STAGE_B(buf0, 0, 0); STAGE_B(buf0, 1, 0); STAGE_B(buf0, 2, 0); STAGE_B(buf0, 3, 0);
    STAGE_A(buf0, 0, 0); STAGE_A(buf0, 1, 0); STAGE_A(buf0, 2, 0); STAGE_A(buf0, 3, 0);
    STAGE_B(buf1, 0, 1); STAGE_B(buf1, 1, 1); STAGE_B(buf1, 2, 1); STAGE_B(buf1, 3, 1);
    STAGE_A(buf1, 0, 1); STAGE_A(buf1, 2, 1);
    asm volatile("s_waitcnt vmcnt(6)" ::: "memory");
    __builtin_amdgcn_s_barrier();

    f32x4 acc[4][4] = {};
    u16* pc = buf0;
    u16* pn = buf1;

#pragma unroll 1
    for (int tt = 0; tt < 32; ++tt) {
        bf16x8 bfr[4][2], afr[2][2];
        // ph1: reads + prefetch(pn A1,A3) + 16 MFMA; barrier (pc-overwrite guard)
#pragma unroll
        for (int j = 0; j < 4; ++j)
#pragma unroll
            for (int kk = 0; kk < 2; ++kk)
                bfr[j][kk] = *(const bf16x8*)(pc + offB[j][kk]);
#pragma unroll
        for (int i = 0; i < 2; ++i)
#pragma unroll
            for (int kk = 0; kk < 2; ++kk)
                afr[i][kk] = *(const bf16x8*)(pc + offA[i][kk]);
        if (tt + 1 < 32) { STAGE_A(pn, 1, tt + 1); STAGE_A(pn, 3, tt + 1); }
        __builtin_amdgcn_s_setprio(1);
#pragma unroll
        for (int i = 0; i < 2; ++i)
#pragma unroll
            for (int j = 0; j < 4; ++j)
#pragma unroll
                for (int kk = 0; kk < 2; ++kk)
                    acc[i][j] = __builtin_amdgcn_mfma_f32_16x16x32_bf16(
                        afr[i][kk], bfr[j][kk], acc[i][j], 0, 0, 0);
        __builtin_amdgcn_s_setprio(0);
        __builtin_amdgcn_s_barrier();

        // ph2: reads A2-3 + prefetch(pc, tt+2) + 16 MFMA; vmcnt; barrier
#pragma unroll
        for (int i = 0; i < 2; ++i)
#pragma unroll
            for (int kk = 0; kk < 2; ++kk)
                afr[i][kk] = *(const bf16x8*)(pc + offA[2 + i][kk]);
        if (tt + 2 < 32) {
            STAGE_B(pc, 0, tt + 2); STAGE_B(pc, 1, tt + 2);
            STAGE_B(pc, 2, tt + 2); STAGE_B(pc, 3, tt + 2);
            STAGE_A(pc, 0, tt + 2); STAGE_A(pc, 2, tt + 2);
        }
        __builtin_amdgcn_s_setprio(1);
#pragma unroll
        for (int i = 0; i < 2; ++i)
#pragma unroll
            for (int j = 0; j < 4; ++j)
#pragma unroll
                for (int kk = 0; kk < 2; ++kk)
                    acc[2 + i][j] = __builtin_amdgcn_mfma_f32_16x16x32_bf16(
                        afr[i][kk], bfr[j][kk], acc[2 + i][j], 0, 0, 0);
        __builtin_amdgcn_s_setprio(0);
        if (tt + 2 < 32)      { asm volatile("s_waitcnt vmcnt(6)" ::: "memory"); }
        else if (tt + 1 < 32) { asm volatile("s_waitcnt vmcnt(0)" ::: "memory"); }
        __builtin_amdgcn_s_barrier();
        u16* tmp = pc; pc = pn; pn = tmp;
    }
#undef STAGE_A
#undef STAGE_B

    float bvv[4];
#pragma unroll
    for (int j = 0; j < 4; ++j) bvv[j] = bias[n0 + wn * 64 + j * 16 + l15];

    if (mode == 2) {
        // silu -> LDS transposed tile Tv[d][s], pad 136 (16B-aligned rows)
        u16* Tv = lds;
        __syncthreads();   // all waves done with staging buffers
#pragma unroll
        for (int i = 0; i < 4; ++i)
#pragma unroll
            for (int r = 0; r < 4; ++r) {
                const int s = wr * 64 + i * 16 + (l4 << 2) + r;
#pragma unroll
                for (int j = 0; j < 4; ++j) {
                    const int d = wn * 64 + j * 16 + l15;
                    Tv[d * 136 + s] = f2bf(silu_f(acc[i][j][r] + bvv[j]));
                }
            }
        __syncthreads();
        const int bh = (m0 >> 10) * 16 + tn;     // b*16 + h
        const int s0 = m0 & 1023;
        u16* vt = (u16*)outp;
#pragma unroll
        for (int r8 = 0; r8 < 8; ++r8) {
            const int d = (t >> 4) + r8 * 16;
            const int s = (t & 15) * 8;
            u16x8 v = *(const u16x8*)&Tv[d * 136 + s];
            *(u16x8*)&vt[((size_t)bh * HEADD + d) * SEQLEN + s0 + s] = v;
        }
        return;
    }

#pragma unroll
    for (int i = 0; i < 4; ++i) {
        const int mbase = m0 + wr * 64 + i * 16 + (l4 << 2);
#pragma unroll
        for (int r = 0; r < 4; ++r) {
            const size_t rowoff = (size_t)(mbase + r) * HDIM + n0 + wn * 64 + l15;
#pragma unroll
            for (int j = 0; j < 4; ++j) {
                const float v = acc[i][j][r] + bvv[j];
                if (mode == 0)
                    ((u16*)outp)[rowoff + j * 16] = f2bf(silu_f(v));
                else
                    ((float*)outp)[rowoff + j * 16] = v;
            }
        }
    }
}

// ---------------------------------------------------------------------------
// Fused SiLU-attention + gating, 8-wave split + diagonal-branch (round-20/21).
__global__ __launch_bounds__(512) void attn_fused(
    const u16* __restrict__ Qb, const u16* __restrict__ Kb,
    const u16* __restrict__ VTg, const u16* __restrict__ Ub,
    const float* __restrict__ rel, u16* __restrict__ G)
{
    extern __shared__ u16 alds[];
    u16* Ps = alds + 24576;
    float* relh = (float*)(alds + 33792);

    const int idx = blockIdx.x;
    const int bh8 = idx & 7;
    const int j = (idx >> 3) & 7;
    const int bhhi = idx >> 6;            // 0..7
    const int bh = bhhi * 8 + bh8;
    const int b = bh >> 4, h = bh & 15;
    const int qS0 = j * 64;               // short subtile
    const int qL0 = (15 - j) * 64;        // long subtile
    const int nkt = 16 - j;
    const int t = threadIdx.x, lane = t & 63, w = t >> 6;    // 8 waves
    const int wq = w & 3;
    const bool isL = (w < 4);
    const int l15 = lane & 15, l4 = lane >> 4, l3 = lane >> 3;
    const size_t rowbase = (size_t)b * SEQLEN;
    const int col0 = h * HEADD;
    const float scale = 0.088388347648318447f;   // 1/sqrt(128)

    for (int i = t; i < 1024; i += 512) relh[i] = rel[(size_t)(1023 + i) * NHEADS + h];

    const u16* gK0 = Kb + (rowbase + w * 8 + l4) * HDIM + col0 + ((lane & 15) ^ l4) * 8;
    const u16* gK1 = Kb + (rowbase + w * 8 + 4 + l4) * HDIM + col0 + ((lane & 15) ^ (l4 + 4)) * 8;
    const u16* gV0 = VTg + ((size_t)bh * HEADD + w * 16 + l3) * SEQLEN + ((lane & 7) ^ l3) * 8;
    const u16* gV1 = VTg + ((size_t)bh * HEADD + w * 16 + 8 + l3) * SEQLEN + ((lane & 7) ^ l3) * 8;

    const int q0 = (isL ? qL0 : qS0) + wq * 16;
    bf16x8 aq[4];
#pragma unroll
    for (int dc = 0; dc < 4; ++dc)
        aq[dc] = *(const bf16x8*)&Qb[(rowbase + q0 + l15) * HDIM + col0 + dc * 32 + (l4 << 3)];

    f32x4 oacc[8] = {};
    const int prB = (isL ? 0 : 64) + wq * 16;     // Ps row base for this wave

#define STAGE_K(kt) do {                                                        \
    const size_t ko_ = (size_t)(kt) * 64 * HDIM;                                \
    glds16(gK0 + ko_, alds + w * 1024);                                         \
    glds16(gK1 + ko_, alds + w * 1024 + 512);                                   \
} while (0)
#define STAGE_V(kt, bsel) do {                                                  \
    u16* vb_ = alds + 8192 + ((bsel) ? 8192 : 0);                               \
    const size_t ko_ = (size_t)(kt) * 64;                                       \
    glds16(gV0 + ko_, vb_ + w * 1024);                                          \
    glds16(gV1 + ko_, vb_ + w * 1024 + 512);                                    \
} while (0)

    STAGE_K(0); STAGE_V(0, 0);
    asm volatile("s_waitcnt vmcnt(0)" ::: "memory");
    __builtin_amdgcn_s_barrier();

    int cur = 0;
#pragma unroll 1
    for (int kt = 0; kt < nkt; ++kt) {
        const int k0 = kt * 64;
        const bool act = isL || (kt <= j);        // wave-uniform
        const bool diag = isL ? (kt == nkt - 1) : (kt == j);
        if (kt + 1 < nkt) STAGE_V(kt + 1, cur ^ 1);
        const u16* kb = alds;
        const u16* vb = alds + 8192 + (cur ? 8192 : 0);

        // QK^T + rel (+ mask only on diag tile) + silu -> Ps
        if (act) {
#pragma unroll
            for (int kf = 0; kf < 4; ++kf) {
                const int krow = kf * 16 + l15;
                f32x4 s = {};
                __builtin_amdgcn_s_setprio(1);
#pragma unroll
                for (int dc = 0; dc < 4; ++dc) {
                    bf16x8 bk = *(const bf16x8*)&kb[krow * 128 + (((dc * 4 + l4) ^ (krow & 7)) << 3)];
                    s = __builtin_amdgcn_mfma_f32_16x16x32_bf16(aq[dc], bk, s, 0, 0, 0);
                }
                __builtin_amdgcn_s_setprio(0);
                const int kabs = k0 + krow;
                const int pr = prB + (l4 << 2);
                if (diag) {
#pragma unroll
                    for (int r = 0; r < 4; ++r) {
                        const int qabs = q0 + (l4 << 2) + r;
                        float v = 0.f;
                        if (kabs <= qabs) v = silu_f(fmaf(s[r], scale, relh[qabs - kabs]));
                        Ps[(pr + r) * 72 + kf * 16 + l15] = f2bf_t(v);
                    }
                } else {
#pragma unroll
                    for (int r = 0; r < 4; ++r) {
                        const int qabs = q0 + (l4 << 2) + r;
                        const float v = silu_f(fmaf(s[r], scale, relh[qabs - kabs]));
                        Ps[(pr + r) * 72 + kf * 16 + l15] = f2bf_t(v);
                    }
                }
            }
        }
        asm volatile("s_waitcnt lgkmcnt(0)" ::: "memory");
        __builtin_amdgcn_s_barrier();                 // Kbuf free (QK^T reads done)
        if (kt + 1 < nkt) STAGE_K(kt + 1);

        // PV (active waves only)
        if (act) {
            bf16x8 ap[2];
#pragma unroll
            for (int kc = 0; kc < 2; ++kc)
                ap[kc] = *(const bf16x8*)&Ps[(prB + l15) * 72 + kc * 32 + (l4 << 3)];
            __builtin_amdgcn_s_setprio(1);
#pragma unroll
            for (int df = 0; df < 8; ++df) {
                const int vrow = df * 16 + l15;
#pragma unroll
                for (int kc = 0; kc < 2; ++kc) {
                    bf16x8 bv = *(const bf16x8*)&vb[vrow * 64 + (((kc * 4 + l4) ^ (vrow & 7)) << 3)];
                    oacc[df] = __builtin_amdgcn_mfma_f32_16x16x32_bf16(ap[kc], bv, oacc[df], 0, 0, 0);
                }
            }
            __builtin_amdgcn_s_setprio(0);
        }
        asm volatile("s_waitcnt vmcnt(0) lgkmcnt(0)" ::: "memory");  // next K,V landed
        __builtin_amdgcn_s_barrier();
        cur ^= 1;
    }
#undef STAGE_K
#undef STAGE_V

    // G = O * U (each wave its own 16 rows), row-sweep for coalescing
#pragma unroll
    for (int r = 0; r < 4; ++r) {
        const int qr = q0 + (l4 << 2) + r;
        const size_t row = (rowbase + qr) * HDIM + col0 + l15;
#pragma unroll
        for (int df = 0; df < 8; ++df)
            G[row + df * 16] = f2bf(oacc[df][r] * bf2f(Ub[row + df * 16]));
    }
}

// ---------------------------------------------------------------------------
extern "C" void kernel_launch(void* const* d_in, const int* in_sizes, int n_in,
                              void* d_out, int out_size, void* d_ws, size_t ws_size,
                              hipStream_t stream) {
    const float* query = (const float*)d_in[0];
    const float* key_  = (const float*)d_in[1];
    const float* value = (const float*)d_in[2];
    // d_in[3] attn_mask: causal by construction, handled analytically.
    const float* Wq  = (const float*)d_in[4];  const float* bq  = (const float*)d_in[5];
    const float* Wk  = (const float*)d_in[6];  const float* bk  = (const float*)d_in[7];
    const float* Wv  = (const float*)d_in[8];  const float* bv  = (const float*)d_in[9];
    const float* Wu  = (const float*)d_in[10]; const float* bu  = (const float*)d_in[11];
    const float* Wf2 = (const float*)d_in[12]; const float* bf2 = (const float*)d_in[13];
    const float* rel = (const float*)d_in[14];

    // Workspace (88 MiB): WTa 8 | Xbf 16 | Q(=G) 16 | K 16 | VTg 16 | U 16
    char* ws = (char*)d_ws;
    const size_t WBYTES = (size_t)HDIM * HDIM * 2;   // 8 MiB
    const size_t ABYTES = (size_t)4096 * HDIM * 2;   // 16 MiB
    u16* WTa  = (u16*)ws;
    u16* Xbf  = (u16*)(ws + WBYTES);
    u16* Qbuf = (u16*)(ws + WBYTES + 1 * ABYTES);
    u16* Kbuf = (u16*)(ws + WBYTES + 2 * ABYTES);
    u16* VTg  = (u16*)(ws + WBYTES + 3 * ABYTES);    // V written transposed here
    u16* Ubuf = (u16*)(ws + WBYTES + 4 * ABYTES);
    u16* WTb  = VTg;           // borrowed for Wu^T: freed before V GEMM writes VTg
    u16* Gbuf = Qbuf;          // attn reads its own Q rows, then writes them as G

    dim3 tpb(256);
    dim3 tgrid(32, 32);        // W transpose tiles
    const int n8 = 4096 * HDIM / 8;
    const size_t GLDS  = 65536;  // 64 KiB for gemm128
    const size_t G8LDS = 131072; // 128 KiB for gemm256_8p
    const size_t ALDS  = 71680;  // 70 KiB for attn_fused

    f32_to_bf16<<<2048, tpb, 0, stream>>>(query, Xbf, n8);
    transpose_w<<<tgrid, tpb, 0, stream>>>(Wq, WTa);
    transpose_w<<<tgrid, tpb, 0, stream>>>(Wu, WTb);
    gemm256_8p<<<256, 512, G8LDS, stream>>>(Xbf, WTa, WTb, bq, bu, Qbuf, Ubuf);
    transpose_w<<<tgrid, tpb, 0, stream>>>(Wk, WTa);
    f32_to_bf16<<<2048, tpb, 0, stream>>>(key_, Xbf, n8);
    gemm128<<<512, tpb, GLDS, stream>>>(Xbf, WTa, bk, Kbuf, 0);
    transpose_w<<<tgrid, tpb, 0, stream>>>(Wv, WTa);
    f32_to_bf16<<<2048, tpb, 0, stream>>>(value, Xbf, n8);
    gemm128<<<512, tpb, GLDS, stream>>>(Xbf, WTa, bv, VTg, 2);   // V -> transposed
    attn_fused<<<512, 512, ALDS, stream>>>(Qbuf, Kbuf, VTg, Ubuf, rel, Gbuf);
    transpose_w<<<tgrid, tpb, 0, stream>>>(Wf2, WTa);
    gemm128<<<512, tpb, GLDS, stream>>>(Gbuf, WTa, bf2, d_out, 1);
}

// Round 23
// 290.570 us; speedup vs baseline: 1.1501x; 1.0088x over previous
//
#include <hip/hip_runtime.h>
#include <stdint.h>

// Problem constants (B=4, S=1024, H=2048, NH=16, HD=128)
#define HDIM 2048
#define SEQLEN 1024
#define NHEADS 16
#define HEADD 128

typedef unsigned short u16;
typedef unsigned int u32;
typedef __attribute__((ext_vector_type(8))) short bf16x8;   // MFMA A/B frag
typedef __attribute__((ext_vector_type(8))) u16 u16x8;
typedef __attribute__((ext_vector_type(4))) u16 u16x4;
typedef __attribute__((ext_vector_type(4))) float f32x4;

__device__ __forceinline__ float bf2f(u16 u) {
    union { u32 i; float f; } v; v.i = ((u32)u) << 16; return v.f;
}
__device__ __forceinline__ u16 f2bf(float f) {
    union { float f; u32 i; } v; v.f = f;
    return (u16)((v.i + 0x7fffu + ((v.i >> 16) & 1u)) >> 16);  // RNE
}
__device__ __forceinline__ u16 f2bf_t(float f) {               // truncation (1 op)
    union { float f; u32 i; } v; v.f = f; return (u16)(v.i >> 16);
}
// Fast silu: x * rcp(1+exp(-x)).
__device__ __forceinline__ float silu_f(float x) {
    return x * __builtin_amdgcn_rcpf(1.f + __expf(-x));
}
// Async global->LDS, 16B per lane. LDS dest = wave-uniform base + lane*16.
__device__ __forceinline__ void glds16(const void* g, void* l) {
    __builtin_amdgcn_global_load_lds(
        (const __attribute__((address_space(1))) u32*)g,
        (__attribute__((address_space(3))) u32*)l, 16, 0, 0);
}

// ---------------------------------------------------------------------------
// f32 -> bf16 bulk convert (8 elems/thread/iter), n8 = n/8.
__global__ __launch_bounds__(256) void f32_to_bf16(const float* __restrict__ in,
                                                   u16* __restrict__ out, int n8) {
    int i = blockIdx.x * 256 + threadIdx.x;
    const int stride = gridDim.x * 256;
    for (; i < n8; i += stride) {
        f32x4 a = *(const f32x4*)&in[(size_t)i * 8];
        f32x4 b = *(const f32x4*)&in[(size_t)i * 8 + 4];
        u16x8 o;
#pragma unroll
        for (int j = 0; j < 4; ++j) { o[j] = f2bf(a[j]); o[4 + j] = f2bf(b[j]); }
        *(u16x8*)&out[(size_t)i * 8] = o;
    }
}

// ---------------------------------------------------------------------------
// Transpose + downconvert W[k][n] (2048x2048 f32) -> WT[n][k] bf16.
__global__ __launch_bounds__(256) void transpose_w(const float* __restrict__ W,
                                                   u16* __restrict__ WT) {
    __shared__ u16 T[64][76];   // 152B rows: 8B aligned, 4-way max on reads
    const int r0 = blockIdx.y * 64;   // k
    const int c0 = blockIdx.x * 64;   // n
    const int t = threadIdx.x;
#pragma unroll
    for (int c = t; c < 1024; c += 256) {
        const int r = c >> 4, cc = (c & 15) << 2;
        f32x4 v = *(const f32x4*)&W[(size_t)(r0 + r) * HDIM + c0 + cc];
        u16x4 o;
#pragma unroll
        for (int j = 0; j < 4; ++j) o[j] = f2bf(v[j]);
        *(u16x4*)&T[r][cc] = o;
    }
    __syncthreads();
#pragma unroll
    for (int c = t; c < 512; c += 256) {
        const int n = c >> 3, kc = (c & 7) << 3;   // lanes 0-7: same n, kc 0..56
        u16x8 v;
#pragma unroll
        for (int j = 0; j < 8; ++j) v[j] = T[kc + j][n];
        *(u16x8*)&WT[(size_t)(c0 + n) * HDIM + r0 + kc] = v;
    }
}

// ---------------------------------------------------------------------------
// 256x256 GEMM, QU-fused, 1-barrier-per-K-tile: all 8 loads of tile t+1
// issued during Φ1 of tile t; tile-entry vmcnt(0)+barrier guarantees Φ2's
// A-P3 reads are resident -> no mid barrier.  Two 32-MFMA setprio clusters.
__global__ __launch_bounds__(512, 2) void gemm256_8p(
    const u16* __restrict__ X,
    const u16* __restrict__ WTq, const u16* __restrict__ WTu,
    const float* __restrict__ bq, const float* __restrict__ bu,
    u16* __restrict__ Qo, u16* __restrict__ Uo)
{
    extern __shared__ u16 lds[];   // 2 bufs x 32768 u16 (A @0, B @16384)
    const int t = threadIdx.x;
    const int lane = t & 63, wid = t >> 6;        // 8 waves
    const int l15 = lane & 15, l4 = lane >> 4;
    const int wr = wid >> 2, wn = wid & 3;        // 2M x 4N

    const int bid = blockIdx.x;                   // 256 blocks
    const int u = (bid & 7) * 32 + (bid >> 3);    // XCD-bijective
    const int tm = u & 15, tn = u >> 4;
    const int m0 = tm * 256;
    const int n0 = tn * 256;                      // 0..4095
    const u16* WT = (n0 < 2048) ? WTq : WTu;
    const float* bias = (n0 < 2048) ? bq : bu;
    u16* outp = (n0 < 2048) ? Qo : Uo;
    const int nc0 = n0 & 2047;

    const int r64 = t >> 3;                       // 0..63
    const int cse = (((t & 7) ^ (r64 & 7)) << 3);
    const u16* gA = X + (size_t)(m0 + r64) * HDIM + cse;
    const int rB0 = (r64 >> 5) * 64 + (r64 & 31);
    const u16* gB = WT + (size_t)(nc0 + rB0) * HDIM + cse;

    const int wbase = wid * 512;
    const int dstBw = (wid >> 2) * 4096 + (wid & 3) * 512;

    int offA[8][2], offB[4][2];
#pragma unroll
    for (int mf = 0; mf < 8; ++mf) {
        const int row = wr * 128 + mf * 16 + l15;
#pragma unroll
        for (int kk = 0; kk < 2; ++kk) {
            const int c = kk * 4 + l4;
            offA[mf][kk] = row * 64 + (((c) ^ (row & 7)) << 3);
        }
    }
#pragma unroll
    for (int nf = 0; nf < 4; ++nf) {
        const int row = wn * 64 + nf * 16 + l15;
#pragma unroll
        for (int kk = 0; kk < 2; ++kk) {
            const int c = kk * 4 + l4;
            offB[nf][kk] = 16384 + row * 64 + (((c) ^ (row & 7)) << 3);
        }
    }

#define SA(buf, rb, kt) glds16(gA + (size_t)(rb) * HDIM + (kt) * 64, \
                               lds + (buf) * 32768 + (rb) * 64 + wbase)
#define SB(buf, c, half, kt) glds16(gB + (size_t)((c) * 128 + (half) * 32) * HDIM + (kt) * 64, \
                               lds + (buf) * 32768 + 16384 + dstBw + (c) * 8192 + (half) * 2048)
#define SALL(buf, kt) do {                                                     \
    SA(buf, 0, kt); SA(buf, 64, kt); SA(buf, 128, kt); SA(buf, 192, kt);       \
    SB(buf, 0, 0, kt); SB(buf, 1, 0, kt); SB(buf, 0, 1, kt); SB(buf, 1, 1, kt);\
} while (0)

    SALL(0, 0);
    asm volatile("s_waitcnt vmcnt(0)" ::: "memory");
    __builtin_amdgcn_s_barrier();

    f32x4 acc[8][4] = {};
    int cur = 0;

#pragma unroll 1
    for (int kt = 0; kt < 32; ++kt) {
        const u16* pc = lds + cur * 32768;
        const int nb = cur ^ 1;
        const bool pf = (kt + 1 < 32);
        bf16x8 a[4][2], b[4][2];

        // Issue all of tile t+1; then Φ1 reads + 32 MFMA.
        if (pf) SALL(nb, kt + 1);
#pragma unroll
        for (int mf = 0; mf < 4; ++mf)
#pragma unroll
            for (int kk = 0; kk < 2; ++kk)
                a[mf][kk] = *(const bf16x8*)(pc + offA[mf][kk]);
#pragma unroll
        for (int nf = 0; nf < 4; ++nf)
#pragma unroll
            for (int kk = 0; kk < 2; ++kk)
                b[nf][kk] = *(const bf16x8*)(pc + offB[nf][kk]);
        __builtin_amdgcn_s_setprio(1);
#pragma unroll
        for (int mf = 0; mf < 4; ++mf)
#pragma unroll
            for (int nf = 0; nf < 4; ++nf)
#pragma unroll
                for (int kk = 0; kk < 2; ++kk)
                    acc[mf][nf] = __builtin_amdgcn_mfma_f32_16x16x32_bf16(
                        a[mf][kk], b[nf][kk], acc[mf][nf], 0, 0, 0);
        __builtin_amdgcn_s_setprio(0);

        // Φ2: A mf4-7 (resident since tile entry), B held in regs; 32 MFMA.
#pragma unroll
        for (int mf = 0; mf < 4; ++mf)
#pragma unroll
            for (int kk = 0; kk < 2; ++kk)
                a[mf][kk] = *(const bf16x8*)(pc + offA[4 + mf][kk]);
        __builtin_amdgcn_s_setprio(1);
#pragma unroll
        for (int mf = 0; mf < 4; ++mf)
#pragma unroll
            for (int nf = 0; nf < 4; ++nf)
#pragma unroll
                for (int kk = 0; kk < 2; ++kk)
                    acc[4 + mf][nf] = __builtin_amdgcn_mfma_f32_16x16x32_bf16(
                        a[mf][kk], b[nf][kk], acc[4 + mf][nf], 0, 0, 0);
        __builtin_amdgcn_s_setprio(0);
        if (pf) { asm volatile("s_waitcnt vmcnt(0)" ::: "memory"); }
        __builtin_amdgcn_s_barrier();
        cur ^= 1;
    }
#undef SALL
#undef SA
#undef SB

    // Coalesced epilogue
    float bvv[4];
#pragma unroll
    for (int nf = 0; nf < 4; ++nf) bvv[nf] = bias[nc0 + wn * 64 + nf * 16 + l15];
#pragma unroll
    for (int mf = 0; mf < 8; ++mf) {
        const int mbase = m0 + wr * 128 + mf * 16 + (l4 << 2);
#pragma unroll
        for (int r = 0; r < 4; ++r) {
            u16* rowp = outp + (size_t)(mbase + r) * HDIM + nc0 + wn * 64 + l15;
#pragma unroll
            for (int nf = 0; nf < 4; ++nf)
                rowp[nf * 16] = f2bf(silu_f(acc[mf][nf][r] + bvv[nf]));
        }
    }
}

// ---------------------------------------------------------------------------
// 128x128 GEMM body, clean double-buffer, 1 barrier per K-tile: all 8
// chunks of tt+1 staged into pn at iteration top; one 32-MFMA cluster.
// mode 0: silu->bf16; mode 1: bias->f32; mode 2: silu->bf16 transposed
// into VTg[(bh*128+d)*1024+s] via padded LDS.
__device__ __forceinline__ void gemm128_body(
    const u16* __restrict__ X, const u16* __restrict__ WT,
    const float* __restrict__ bias, void* __restrict__ outp,
    const int mode, const int bid, u16* lds)
{
    const int t = threadIdx.x;
    const int lane = t & 63, wid = t >> 6;       // 4 waves
    const int l15 = lane & 15, l4 = lane >> 4;
    const int wr = wid >> 1, wn = wid & 1;

    const int u = (bid & 7) * 64 + (bid >> 3);   // XCD-bijective over 512
    const int tm = u & 31, tn = u >> 5;
    const int m0 = tm * 128, n0 = tn * 128;

    const int ric = t >> 3;
    const int cse = (((t & 7) ^ (ric & 7)) << 3);
    const u16* gA = X  + (size_t)(m0 + ric) * HDIM + cse;
    const u16* gB = WT + (size_t)(n0 + ric) * HDIM + cse;

    u16* buf0 = lds;
    u16* buf1 = lds + 16384;
    const int wbase = wid * 512;

    int offA[4][2], offB[4][2];
#pragma unroll
    for (int i = 0; i < 4; ++i) {
        const int row = wr * 64 + i * 16 + l15;
#pragma unroll
        for (int kk = 0; kk < 2; ++kk)
            offA[i][kk] = ((row * 128 + kk * 64 + l4 * 16) ^ ((row & 7) << 4)) >> 1;
    }
#pragma unroll
    for (int j = 0; j < 4; ++j) {
        const int row = wn * 64 + j * 16 + l15;
#pragma unroll
        for (int kk = 0; kk < 2; ++kk)
            offB[j][kk] = 8192 + ((((row * 128 + kk * 64 + l4 * 16) ^ ((row & 7) << 4))) >> 1);
    }

#define STAGE_ALL(buf, kt) do {                                                 \
    glds16(gB + (size_t)0 * 32 * HDIM + (kt) * 64, (buf) + 8192 + 0 * 2048 + wbase); \
    glds16(gB + (size_t)1 * 32 * HDIM + (kt) * 64, (buf) + 8192 + 1 * 2048 + wbase); \
    glds16(gB + (size_t)2 * 32 * HDIM + (kt) * 64, (buf) + 8192 + 2 * 2048 + wbase); \
    glds16(gB + (size_t)3 * 32 * HDIM + (kt) * 64, (buf) + 8192 + 3 * 2048 + wbase); \
    glds16(gA + (size_t)0 * 32 * HDIM + (kt) * 64, (buf) + 0 * 2048 + wbase);   \
    glds16(gA + (size_t)1 * 32 * HDIM + (kt) * 64, (buf) + 1 * 2048 + wbase);   \
    glds16(gA + (size_t)2 * 32 * HDIM + (kt) * 64, (buf) + 2 * 2048 + wbase);   \
    glds16(gA + (size_t)3 * 32 * HDIM + (kt) * 64, (buf) + 3 * 2048 + wbase);   \
} while (0)

    STAGE_ALL(buf0, 0);
    asm volatile("s_waitcnt vmcnt(0)" ::: "memory");
    __builtin_amdgcn_s_barrier();

    f32x4 acc[4][4] = {};
    u16* pc = buf0;
    u16* pn = buf1;

#pragma unroll 1
    for (int tt = 0; tt < 32; ++tt) {
        if (tt + 1 < 32) STAGE_ALL(pn, tt + 1);
        bf16x8 bfr[4][2], afr[4][2];
#pragma unroll
        for (int j = 0; j < 4; ++j)
#pragma unroll
            for (int kk = 0; kk < 2; ++kk)
                bfr[j][kk] = *(const bf16x8*)(pc + offB[j][kk]);
#pragma unroll
        for (int i = 0; i < 4; ++i)
#pragma unroll
            for (int kk = 0; kk < 2; ++kk)
                afr[i][kk] = *(const bf16x8*)(pc + offA[i][kk]);
        __builtin_amdgcn_s_setprio(1);
#pragma unroll
        for (int i = 0; i < 4; ++i)
#pragma unroll
            for (int j = 0; j < 4; ++j)
#pragma unroll
                for (int kk = 0; kk < 2; ++kk)
                    acc[i][j] = __builtin_amdgcn_mfma_f32_16x16x32_bf16(
                        afr[i][kk], bfr[j][kk], acc[i][j], 0, 0, 0);
        __builtin_amdgcn_s_setprio(0);
        if (tt + 1 < 32) { asm volatile("s_waitcnt vmcnt(0)" ::: "memory"); }
        __builtin_amdgcn_s_barrier();
        u16* tmp = pc; pc = pn; pn = tmp;
    }
#undef STAGE_ALL

    float bvv[4];
#pragma unroll
    for (int j = 0; j < 4; ++j) bvv[j] = bias[n0 + wn * 64 + j * 16 + l15];

    if (mode == 2) {
        // silu -> LDS transposed tile Tv[d][s], pad 136 (16B-aligned rows)
        u16* Tv = lds;
        __syncthreads();
#pragma unroll
        for (int i = 0; i < 4; ++i)
#pragma unroll
            for (int r = 0; r < 4; ++r) {
                const int s = wr * 64 + i * 16 + (l4 << 2) + r;
#pragma unroll
                for (int j = 0; j < 4; ++j) {
                    const int d = wn * 64 + j * 16 + l15;
                    Tv[d * 136 + s] = f2bf(silu_f(acc[i][j][r] + bvv[j]));
                }
            }
        __syncthreads();
        const int bh = (m0 >> 10) * 16 + tn;     // b*16 + h
        const int s0 = m0 & 1023;
        u16* vt = (u16*)outp;
#pragma unroll
        for (int r8 = 0; r8 < 8; ++r8) {
            const int d = (t >> 4) + r8 * 16;
            const int s = (t & 15) * 8;
            u16x8 v = *(const u16x8*)&Tv[d * 136 + s];
            *(u16x8*)&vt[((size_t)bh * HEADD + d) * SEQLEN + s0 + s] = v;
        }
        return;
    }

#pragma unroll
    for (int i = 0; i < 4; ++i) {
        const int mbase = m0 + wr * 64 + i * 16 + (l4 << 2);
#pragma unroll
        for (int r = 0; r < 4; ++r) {
            const size_t rowoff = (size_t)(mbase + r) * HDIM + n0 + wn * 64 + l15;
#pragma unroll
            for (int j = 0; j < 4; ++j) {
                const float v = acc[i][j][r] + bvv[j];
                if (mode == 0)
                    ((u16*)outp)[rowoff + j * 16] = f2bf(silu_f(v));
                else
                    ((float*)outp)[rowoff + j * 16] = v;
            }
        }
    }
}

__global__ __launch_bounds__(256) void gemm128(
    const u16* __restrict__ X, const u16* __restrict__ WT,
    const float* __restrict__ bias, void* __restrict__ outp, const int mode)
{
    extern __shared__ u16 lds[];
    gemm128_body(X, WT, bias, outp, mode, blockIdx.x, lds);
}

// Fused K+V projection: blocks 0-511 compute K (mode 0), 512-1023 compute V
// (mode 2, transposed out).  Doubles resident blocks/CU vs serial dispatches.
__global__ __launch_bounds__(256) void gemm128_kv(
    const u16* __restrict__ Kx, const u16* __restrict__ WTk,
    const float* __restrict__ bk, u16* __restrict__ Ko,
    const u16* __restrict__ Vx, const u16* __restrict__ WTv,
    const float* __restrict__ bv, u16* __restrict__ Vo)
{
    extern __shared__ u16 lds[];
    const int bid = blockIdx.x;
    if (bid < 512) gemm128_body(Kx, WTk, bk, Ko, 0, bid, lds);
    else           gemm128_body(Vx, WTv, bv, Vo, 2, bid - 512, lds);
}

// ---------------------------------------------------------------------------
// Fused SiLU-attention + gating, 8-wave split + diagonal-branch; explicit
// lgkmcnt drains removed (register deps + compiler waits order ds ops).
__global__ __launch_bounds__(512) void attn_fused(
    const u16* __restrict__ Qb, const u16* __restrict__ Kb,
    const u16* __restrict__ VTg, const u16* __restrict__ Ub,
    const float* __restrict__ rel, u16* __restrict__ G)
{
    extern __shared__ u16 alds[];
    u16* Ps = alds + 24576;
    float* relh = (float*)(alds + 33792);

    const int idx = blockIdx.x;
    const int bh8 = idx & 7;
    const int j = (idx >> 3) & 7;
    const int bhhi = idx >> 6;            // 0..7
    const int bh = bhhi * 8 + bh8;
    const int b = bh >> 4, h = bh & 15;
    const int qS0 = j * 64;               // short subtile
    const int qL0 = (15 - j) * 64;        // long subtile
    const int nkt = 16 - j;
    const int t = threadIdx.x, lane = t & 63, w = t >> 6;    // 8 waves
    const int wq = w & 3;
    const bool isL = (w < 4);
    const int l15 = lane & 15, l4 = lane >> 4, l3 = lane >> 3;
    const size_t rowbase = (size_t)b * SEQLEN;
    const int col0 = h * HEADD;
    const float scale = 0.088388347648318447f;   // 1/sqrt(128)

    for (int i = t; i < 1024; i += 512) relh[i] = rel[(size_t)(1023 + i) * NHEADS + h];

    const u16* gK0 = Kb + (rowbase + w * 8 + l4) * HDIM + col0 + ((lane & 15) ^ l4) * 8;
    const u16* gK1 = Kb + (rowbase + w * 8 + 4 + l4) * HDIM + col0 + ((lane & 15) ^ (l4 + 4)) * 8;
    const u16* gV0 = VTg + ((size_t)bh * HEADD + w * 16 + l3) * SEQLEN + ((lane & 7) ^ l3) * 8;
    const u16* gV1 = VTg + ((size_t)bh * HEADD + w * 16 + 8 + l3) * SEQLEN + ((lane & 7) ^ l3) * 8;

    const int q0 = (isL ? qL0 : qS0) + wq * 16;
    bf16x8 aq[4];
#pragma unroll
    for (int dc = 0; dc < 4; ++dc)
        aq[dc] = *(const bf16x8*)&Qb[(rowbase + q0 + l15) * HDIM + col0 + dc * 32 + (l4 << 3)];

    f32x4 oacc[8] = {};
    const int prB = (isL ? 0 : 64) + wq * 16;     // Ps row base for this wave

#define STAGE_K(kt) do {                                                        \
    const size_t ko_ = (size_t)(kt) * 64 * HDIM;                                \
    glds16(gK0 + ko_, alds + w * 1024);                                         \
    glds16(gK1 + ko_, alds + w * 1024 + 512);                                   \
} while (0)
#define STAGE_V(kt, bsel) do {                                                  \
    u16* vb_ = alds + 8192 + ((bsel) ? 8192 : 0);                               \
    const size_t ko_ = (size_t)(kt) * 64;                                       \
    glds16(gV0 + ko_, vb_ + w * 1024);                                          \
    glds16(gV1 + ko_, vb_ + w * 1024 + 512);                                    \
} while (0)

    STAGE_K(0); STAGE_V(0, 0);
    asm volatile("s_waitcnt vmcnt(0)" ::: "memory");
    __builtin_amdgcn_s_barrier();

    int cur = 0;
#pragma unroll 1
    for (int kt = 0; kt < nkt; ++kt) {
        const int k0 = kt * 64;
        const bool act = isL || (kt <= j);        // wave-uniform
        const bool diag = isL ? (kt == nkt - 1) : (kt == j);
        if (kt + 1 < nkt) STAGE_V(kt + 1, cur ^ 1);
        const u16* kb = alds;
        const u16* vb = alds + 8192 + (cur ? 8192 : 0);

        // QK^T + rel (+ mask only on diag tile) + silu -> Ps
        if (act) {
#pragma unroll
            for (int kf = 0; kf < 4; ++kf) {
                const int krow = kf * 16 + l15;
                f32x4 s = {};
                __builtin_amdgcn_s_setprio(1);
#pragma unroll
                for (int dc = 0; dc < 4; ++dc) {
                    bf16x8 bk = *(const bf16x8*)&kb[krow * 128 + (((dc * 4 + l4) ^ (krow & 7)) << 3)];
                    s = __builtin_amdgcn_mfma_f32_16x16x32_bf16(aq[dc], bk, s, 0, 0, 0);
                }
                __builtin_amdgcn_s_setprio(0);
                const int kabs = k0 + krow;
                const int pr = prB + (l4 << 2);
                if (diag) {
#pragma unroll
                    for (int r = 0; r < 4; ++r) {
                        const int qabs = q0 + (l4 << 2) + r;
                        float v = 0.f;
                        if (kabs <= qabs) v = silu_f(fmaf(s[r], scale, relh[qabs - kabs]));
                        Ps[(pr + r) * 72 + kf * 16 + l15] = f2bf_t(v);
                    }
                } else {
#pragma unroll
                    for (int r = 0; r < 4; ++r) {
                        const int qabs = q0 + (l4 << 2) + r;
                        const float v = silu_f(fmaf(s[r], scale, relh[qabs - kabs]));
                        Ps[(pr + r) * 72 + kf * 16 + l15] = f2bf_t(v);
                    }
                }
            }
        }
        __builtin_amdgcn_s_barrier();                 // Kbuf free (QK^T reads done)
        if (kt + 1 < nkt) STAGE_K(kt + 1);

        // PV (active waves only)
        if (act) {
            bf16x8 ap[2];
#pragma unroll
            for (int kc = 0; kc < 2; ++kc)
                ap[kc] = *(const bf16x8*)&Ps[(prB + l15) * 72 + kc * 32 + (l4 << 3)];
            __builtin_amdgcn_s_setprio(1);
#pragma unroll
            for (int df = 0; df < 8; ++df) {
                const int vrow = df * 16 + l15;
#pragma unroll
                for (int kc = 0; kc < 2; ++kc) {
                    bf16x8 bv = *(const bf16x8*)&vb[vrow * 64 + (((kc * 4 + l4) ^ (vrow & 7)) << 3)];
                    oacc[df] = __builtin_amdgcn_mfma_f32_16x16x32_bf16(ap[kc], bv, oacc[df], 0, 0, 0);
                }
            }
            __builtin_amdgcn_s_setprio(0);
        }
        asm volatile("s_waitcnt vmcnt(0)" ::: "memory");  // next K,V landed
        __builtin_amdgcn_s_barrier();
        cur ^= 1;
    }
#undef STAGE_K
#undef STAGE_V

    // G = O * U (each wave its own 16 rows), row-sweep for coalescing
#pragma unroll
    for (int r = 0; r < 4; ++r) {
        const int qr = q0 + (l4 << 2) + r;
        const size_t row = (rowbase + qr) * HDIM + col0 + l15;
#pragma unroll
        for (int df = 0; df < 8; ++df)
            G[row + df * 16] = f2bf(oacc[df][r] * bf2f(Ub[row + df * 16]));
    }
}

// ---------------------------------------------------------------------------
extern "C" void kernel_launch(void* const* d_in, const int* in_sizes, int n_in,
                              void* d_out, int out_size, void* d_ws, size_t ws_size,
                              hipStream_t stream) {
    const float* query = (const float*)d_in[0];
    const float* key_  = (const float*)d_in[1];
    const float* value = (const float*)d_in[2];
    // d_in[3] attn_mask: causal by construction, handled analytically.
    const float* Wq  = (const float*)d_in[4];  const float* bq  = (const float*)d_in[5];
    const float* Wk  = (const float*)d_in[6];  const float* bk  = (const float*)d_in[7];
    const float* Wv  = (const float*)d_in[8];  const float* bv  = (const float*)d_in[9];
    const float* Wu  = (const float*)d_in[10]; const float* bu  = (const float*)d_in[11];
    const float* Wf2 = (const float*)d_in[12]; const float* bf2 = (const float*)d_in[13];
    const float* rel = (const float*)d_in[14];

    // Workspace (88 MiB): WTa 8 | Xbf 16 | Q(=G) 16 | K 16 | VTg 16 | U 16.
    // d_out (32 MiB, fully rewritten by final GEMM) used as scratch for
    // key_bf (16 MiB) + Wv^T (8 MiB) during the fused KV projection.
    char* ws = (char*)d_ws;
    const size_t WBYTES = (size_t)HDIM * HDIM * 2;   // 8 MiB
    const size_t ABYTES = (size_t)4096 * HDIM * 2;   // 16 MiB
    u16* WTa  = (u16*)ws;
    u16* Xbf  = (u16*)(ws + WBYTES);
    u16* Qbuf = (u16*)(ws + WBYTES + 1 * ABYTES);
    u16* Kbuf = (u16*)(ws + WBYTES + 2 * ABYTES);
    u16* VTg  = (u16*)(ws + WBYTES + 3 * ABYTES);    // V written transposed here
    u16* Ubuf = (u16*)(ws + WBYTES + 4 * ABYTES);
    u16* WTb  = VTg;           // borrowed for Wu^T: freed before KV GEMM writes VTg
    u16* Gbuf = Qbuf;          // attn reads its own Q rows, then writes them as G
    u16* KXbf = (u16*)d_out;                 // scratch in d_out
    u16* WTv  = (u16*)((char*)d_out + ABYTES);

    dim3 tpb(256);
    dim3 tgrid(32, 32);        // W transpose tiles
    const int n8 = 4096 * HDIM / 8;
    const size_t GLDS  = 65536;  // 64 KiB for gemm128
    const size_t G8LDS = 131072; // 128 KiB for gemm256_8p
    const size_t ALDS  = 71680;  // 70 KiB for attn_fused

    f32_to_bf16<<<2048, tpb, 0, stream>>>(query, Xbf, n8);
    transpose_w<<<tgrid, tpb, 0, stream>>>(Wq, WTa);
    transpose_w<<<tgrid, tpb, 0, stream>>>(Wu, WTb);
    gemm256_8p<<<256, 512, G8LDS, stream>>>(Xbf, WTa, WTb, bq, bu, Qbuf, Ubuf);
    f32_to_bf16<<<2048, tpb, 0, stream>>>(key_, KXbf, n8);
    f32_to_bf16<<<2048, tpb, 0, stream>>>(value, Xbf, n8);
    transpose_w<<<tgrid, tpb, 0, stream>>>(Wk, WTa);
    transpose_w<<<tgrid, tpb, 0, stream>>>(Wv, WTv);
    gemm128_kv<<<1024, tpb, GLDS, stream>>>(KXbf, WTa, bk, Kbuf,
                                            Xbf, WTv, bv, VTg);
    attn_fused<<<512, 512, ALDS, stream>>>(Qbuf, Kbuf, VTg, Ubuf, rel, Gbuf);
    transpose_w<<<tgrid, tpb, 0, stream>>>(Wf2, WTa);
    gemm128<<<512, tpb, GLDS, stream>>>(Gbuf, WTa, bf2, d_out, 1);
}

// Round 24
// 287.378 us; speedup vs baseline: 1.1629x; 1.0111x over previous
//
#include <hip/hip_runtime.h>
#include <stdint.h>

// Problem constants (B=4, S=1024, H=2048, NH=16, HD=128)
#define HDIM 2048
#define SEQLEN 1024
#define NHEADS 16
#define HEADD 128

typedef unsigned short u16;
typedef unsigned int u32;
typedef __attribute__((ext_vector_type(8))) short bf16x8;   // MFMA A/B frag
typedef __attribute__((ext_vector_type(8))) u16 u16x8;
typedef __attribute__((ext_vector_type(4))) u16 u16x4;
typedef __attribute__((ext_vector_type(4))) float f32x4;

__device__ __forceinline__ float bf2f(u16 u) {
    union { u32 i; float f; } v; v.i = ((u32)u) << 16; return v.f;
}
__device__ __forceinline__ u16 f2bf(float f) {
    union { float f; u32 i; } v; v.f = f;
    return (u16)((v.i + 0x7fffu + ((v.i >> 16) & 1u)) >> 16);  // RNE
}
__device__ __forceinline__ u16 f2bf_t(float f) {               // truncation (1 op)
    union { float f; u32 i; } v; v.f = f; return (u16)(v.i >> 16);
}
// Fast silu: x * rcp(1+exp(-x)).
__device__ __forceinline__ float silu_f(float x) {
    return x * __builtin_amdgcn_rcpf(1.f + __expf(-x));
}
// Async global->LDS, 16B per lane. LDS dest = wave-uniform base + lane*16.
__device__ __forceinline__ void glds16(const void* g, void* l) {
    __builtin_amdgcn_global_load_lds(
        (const __attribute__((address_space(1))) u32*)g,
        (__attribute__((address_space(3))) u32*)l, 16, 0, 0);
}

// ---------------------------------------------------------------------------
// f32 -> bf16 bulk convert (8 elems/thread/iter), n8 = n/8.
__global__ __launch_bounds__(256) void f32_to_bf16(const float* __restrict__ in,
                                                   u16* __restrict__ out, int n8) {
    int i = blockIdx.x * 256 + threadIdx.x;
    const int stride = gridDim.x * 256;
    for (; i < n8; i += stride) {
        f32x4 a = *(const f32x4*)&in[(size_t)i * 8];
        f32x4 b = *(const f32x4*)&in[(size_t)i * 8 + 4];
        u16x8 o;
#pragma unroll
        for (int j = 0; j < 4; ++j) { o[j] = f2bf(a[j]); o[4 + j] = f2bf(b[j]); }
        *(u16x8*)&out[(size_t)i * 8] = o;
    }
}

// Two-tensor variant: blocks [0,n8/256) do in0->out0, rest do in1->out1.
__global__ __launch_bounds__(256) void f32_to_bf16_2(
    const float* __restrict__ in0, u16* __restrict__ out0,
    const float* __restrict__ in1, u16* __restrict__ out1, int n8) {
    const int half = (int)(blockIdx.x >= (unsigned)(n8 >> 8));
    const float* in = half ? in1 : in0;
    u16* out = half ? out1 : out0;
    const int i = (blockIdx.x - half * (n8 >> 8)) * 256 + threadIdx.x;
    if (i < n8) {
        f32x4 a = *(const f32x4*)&in[(size_t)i * 8];
        f32x4 b = *(const f32x4*)&in[(size_t)i * 8 + 4];
        u16x8 o;
#pragma unroll
        for (int j = 0; j < 4; ++j) { o[j] = f2bf(a[j]); o[4 + j] = f2bf(b[j]); }
        *(u16x8*)&out[(size_t)i * 8] = o;
    }
}

// ---------------------------------------------------------------------------
// Transpose + downconvert W[k][n] (2048x2048 f32) -> WT[n][k] bf16.
__device__ __forceinline__ void transpose_w_body(const float* __restrict__ W,
                                                 u16* __restrict__ WT) {
    __shared__ u16 T[64][76];   // 152B rows: 8B aligned, 4-way max on reads
    const int r0 = blockIdx.y * 64;   // k
    const int c0 = blockIdx.x * 64;   // n
    const int t = threadIdx.x;
#pragma unroll
    for (int c = t; c < 1024; c += 256) {
        const int r = c >> 4, cc = (c & 15) << 2;
        f32x4 v = *(const f32x4*)&W[(size_t)(r0 + r) * HDIM + c0 + cc];
        u16x4 o;
#pragma unroll
        for (int j = 0; j < 4; ++j) o[j] = f2bf(v[j]);
        *(u16x4*)&T[r][cc] = o;
    }
    __syncthreads();
#pragma unroll
    for (int c = t; c < 512; c += 256) {
        const int n = c >> 3, kc = (c & 7) << 3;   // lanes 0-7: same n, kc 0..56
        u16x8 v;
#pragma unroll
        for (int j = 0; j < 8; ++j) v[j] = T[kc + j][n];
        *(u16x8*)&WT[(size_t)(c0 + n) * HDIM + r0 + kc] = v;
    }
}

__global__ __launch_bounds__(256) void transpose_w(const float* __restrict__ W,
                                                   u16* __restrict__ WT) {
    transpose_w_body(W, WT);
}

// Two matrices in one dispatch (z selects pair).
__global__ __launch_bounds__(256) void transpose_w2(
    const float* __restrict__ W0, u16* __restrict__ WT0,
    const float* __restrict__ W1, u16* __restrict__ WT1) {
    if (blockIdx.z == 0) transpose_w_body(W0, WT0);
    else                 transpose_w_body(W1, WT1);
}

// ---------------------------------------------------------------------------
// 256x256 GEMM, QU-fused, 1-barrier-per-K-tile (round-23, unchanged).
__global__ __launch_bounds__(512, 2) void gemm256_8p(
    const u16* __restrict__ X,
    const u16* __restrict__ WTq, const u16* __restrict__ WTu,
    const float* __restrict__ bq, const float* __restrict__ bu,
    u16* __restrict__ Qo, u16* __restrict__ Uo)
{
    extern __shared__ u16 lds[];   // 2 bufs x 32768 u16 (A @0, B @16384)
    const int t = threadIdx.x;
    const int lane = t & 63, wid = t >> 6;        // 8 waves
    const int l15 = lane & 15, l4 = lane >> 4;
    const int wr = wid >> 2, wn = wid & 3;        // 2M x 4N

    const int bid = blockIdx.x;                   // 256 blocks
    const int u = (bid & 7) * 32 + (bid >> 3);    // XCD-bijective
    const int tm = u & 15, tn = u >> 4;
    const int m0 = tm * 256;
    const int n0 = tn * 256;                      // 0..4095
    const u16* WT = (n0 < 2048) ? WTq : WTu;
    const float* bias = (n0 < 2048) ? bq : bu;
    u16* outp = (n0 < 2048) ? Qo : Uo;
    const int nc0 = n0 & 2047;

    const int r64 = t >> 3;                       // 0..63
    const int cse = (((t & 7) ^ (r64 & 7)) << 3);
    const u16* gA = X + (size_t)(m0 + r64) * HDIM + cse;
    const int rB0 = (r64 >> 5) * 64 + (r64 & 31);
    const u16* gB = WT + (size_t)(nc0 + rB0) * HDIM + cse;

    const int wbase = wid * 512;
    const int dstBw = (wid >> 2) * 4096 + (wid & 3) * 512;

    int offA[8][2], offB[4][2];
#pragma unroll
    for (int mf = 0; mf < 8; ++mf) {
        const int row = wr * 128 + mf * 16 + l15;
#pragma unroll
        for (int kk = 0; kk < 2; ++kk) {
            const int c = kk * 4 + l4;
            offA[mf][kk] = row * 64 + (((c) ^ (row & 7)) << 3);
        }
    }
#pragma unroll
    for (int nf = 0; nf < 4; ++nf) {
        const int row = wn * 64 + nf * 16 + l15;
#pragma unroll
        for (int kk = 0; kk < 2; ++kk) {
            const int c = kk * 4 + l4;
            offB[nf][kk] = 16384 + row * 64 + (((c) ^ (row & 7)) << 3);
        }
    }

#define SA(buf, rb, kt) glds16(gA + (size_t)(rb) * HDIM + (kt) * 64, \
                               lds + (buf) * 32768 + (rb) * 64 + wbase)
#define SB(buf, c, half, kt) glds16(gB + (size_t)((c) * 128 + (half) * 32) * HDIM + (kt) * 64, \
                               lds + (buf) * 32768 + 16384 + dstBw + (c) * 8192 + (half) * 2048)
#define SALL(buf, kt) do {                                                     \
    SA(buf, 0, kt); SA(buf, 64, kt); SA(buf, 128, kt); SA(buf, 192, kt);       \
    SB(buf, 0, 0, kt); SB(buf, 1, 0, kt); SB(buf, 0, 1, kt); SB(buf, 1, 1, kt);\
} while (0)

    SALL(0, 0);
    asm volatile("s_waitcnt vmcnt(0)" ::: "memory");
    __builtin_amdgcn_s_barrier();

    f32x4 acc[8][4] = {};
    int cur = 0;

#pragma unroll 1
    for (int kt = 0; kt < 32; ++kt) {
        const u16* pc = lds + cur * 32768;
        const int nb = cur ^ 1;
        const bool pf = (kt + 1 < 32);
        bf16x8 a[4][2], b[4][2];

        if (pf) SALL(nb, kt + 1);
#pragma unroll
        for (int mf = 0; mf < 4; ++mf)
#pragma unroll
            for (int kk = 0; kk < 2; ++kk)
                a[mf][kk] = *(const bf16x8*)(pc + offA[mf][kk]);
#pragma unroll
        for (int nf = 0; nf < 4; ++nf)
#pragma unroll
            for (int kk = 0; kk < 2; ++kk)
                b[nf][kk] = *(const bf16x8*)(pc + offB[nf][kk]);
        __builtin_amdgcn_s_setprio(1);
#pragma unroll
        for (int mf = 0; mf < 4; ++mf)
#pragma unroll
            for (int nf = 0; nf < 4; ++nf)
#pragma unroll
                for (int kk = 0; kk < 2; ++kk)
                    acc[mf][nf] = __builtin_amdgcn_mfma_f32_16x16x32_bf16(
                        a[mf][kk], b[nf][kk], acc[mf][nf], 0, 0, 0);
        __builtin_amdgcn_s_setprio(0);

#pragma unroll
        for (int mf = 0; mf < 4; ++mf)
#pragma unroll
            for (int kk = 0; kk < 2; ++kk)
                a[mf][kk] = *(const bf16x8*)(pc + offA[4 + mf][kk]);
        __builtin_amdgcn_s_setprio(1);
#pragma unroll
        for (int mf = 0; mf < 4; ++mf)
#pragma unroll
            for (int nf = 0; nf < 4; ++nf)
#pragma unroll
                for (int kk = 0; kk < 2; ++kk)
                    acc[4 + mf][nf] = __builtin_amdgcn_mfma_f32_16x16x32_bf16(
                        a[mf][kk], b[nf][kk], acc[4 + mf][nf], 0, 0, 0);
        __builtin_amdgcn_s_setprio(0);
        if (pf) { asm volatile("s_waitcnt vmcnt(0)" ::: "memory"); }
        __builtin_amdgcn_s_barrier();
        cur ^= 1;
    }
#undef SALL
#undef SA
#undef SB

    float bvv[4];
#pragma unroll
    for (int nf = 0; nf < 4; ++nf) bvv[nf] = bias[nc0 + wn * 64 + nf * 16 + l15];
#pragma unroll
    for (int mf = 0; mf < 8; ++mf) {
        const int mbase = m0 + wr * 128 + mf * 16 + (l4 << 2);
#pragma unroll
        for (int r = 0; r < 4; ++r) {
            u16* rowp = outp + (size_t)(mbase + r) * HDIM + nc0 + wn * 64 + l15;
#pragma unroll
            for (int nf = 0; nf < 4; ++nf)
                rowp[nf * 16] = f2bf(silu_f(acc[mf][nf][r] + bvv[nf]));
        }
    }
}

// ---------------------------------------------------------------------------
// 128x128 GEMM, clean double-buffer, 1 barrier/K-tile (round-23 body).
// mode 0: silu->bf16; mode 1: bias->f32; mode 2: silu->bf16 transposed
// into VTg[(bh*128+d)*1024+s] via padded LDS.
__global__ __launch_bounds__(256) void gemm128(
    const u16* __restrict__ X, const u16* __restrict__ WT,
    const float* __restrict__ bias, void* __restrict__ outp, const int mode)
{
    extern __shared__ u16 lds[];
    const int t = threadIdx.x;
    const int lane = t & 63, wid = t >> 6;       // 4 waves
    const int l15 = lane & 15, l4 = lane >> 4;
    const int wr = wid >> 1, wn = wid & 1;

    const int bid = blockIdx.x;                  // 512 blocks
    const int u = (bid & 7) * 64 + (bid >> 3);   // XCD-bijective
    const int tm = u & 31, tn = u >> 5;
    const int m0 = tm * 128, n0 = tn * 128;

    const int ric = t >> 3;
    const int cse = (((t & 7) ^ (ric & 7)) << 3);
    const u16* gA = X  + (size_t)(m0 + ric) * HDIM + cse;
    const u16* gB = WT + (size_t)(n0 + ric) * HDIM + cse;

    u16* buf0 = lds;
    u16* buf1 = lds + 16384;
    const int wbase = wid * 512;

    int offA[4][2], offB[4][2];
#pragma unroll
    for (int i = 0; i < 4; ++i) {
        const int row = wr * 64 + i * 16 + l15;
#pragma unroll
        for (int kk = 0; kk < 2; ++kk)
            offA[i][kk] = ((row * 128 + kk * 64 + l4 * 16) ^ ((row & 7) << 4)) >> 1;
    }
#pragma unroll
    for (int j = 0; j < 4; ++j) {
        const int row = wn * 64 + j * 16 + l15;
#pragma unroll
        for (int kk = 0; kk < 2; ++kk)
            offB[j][kk] = 8192 + ((((row * 128 + kk * 64 + l4 * 16) ^ ((row & 7) << 4))) >> 1);
    }

#define STAGE_ALL(buf, kt) do {                                                 \
    glds16(gB + (size_t)0 * 32 * HDIM + (kt) * 64, (buf) + 8192 + 0 * 2048 + wbase); \
    glds16(gB + (size_t)1 * 32 * HDIM + (kt) * 64, (buf) + 8192 + 1 * 2048 + wbase); \
    glds16(gB + (size_t)2 * 32 * HDIM + (kt) * 64, (buf) + 8192 + 2 * 2048 + wbase); \
    glds16(gB + (size_t)3 * 32 * HDIM + (kt) * 64, (buf) + 8192 + 3 * 2048 + wbase); \
    glds16(gA + (size_t)0 * 32 * HDIM + (kt) * 64, (buf) + 0 * 2048 + wbase);   \
    glds16(gA + (size_t)1 * 32 * HDIM + (kt) * 64, (buf) + 1 * 2048 + wbase);   \
    glds16(gA + (size_t)2 * 32 * HDIM + (kt) * 64, (buf) + 2 * 2048 + wbase);   \
    glds16(gA + (size_t)3 * 32 * HDIM + (kt) * 64, (buf) + 3 * 2048 + wbase);   \
} while (0)

    STAGE_ALL(buf0, 0);
    asm volatile("s_waitcnt vmcnt(0)" ::: "memory");
    __builtin_amdgcn_s_barrier();

    f32x4 acc[4][4] = {};
    u16* pc = buf0;
    u16* pn = buf1;

#pragma unroll 1
    for (int tt = 0; tt < 32; ++tt) {
        if (tt + 1 < 32) STAGE_ALL(pn, tt + 1);
        bf16x8 bfr[4][2], afr[4][2];
#pragma unroll
        for (int j = 0; j < 4; ++j)
#pragma unroll
            for (int kk = 0; kk < 2; ++kk)
                bfr[j][kk] = *(const bf16x8*)(pc + offB[j][kk]);
#pragma unroll
        for (int i = 0; i < 4; ++i)
#pragma unroll
            for (int kk = 0; kk < 2; ++kk)
                afr[i][kk] = *(const bf16x8*)(pc + offA[i][kk]);
        __builtin_amdgcn_s_setprio(1);
#pragma unroll
        for (int i = 0; i < 4; ++i)
#pragma unroll
            for (int j = 0; j < 4; ++j)
#pragma unroll
                for (int kk = 0; kk < 2; ++kk)
                    acc[i][j] = __builtin_amdgcn_mfma_f32_16x16x32_bf16(
                        afr[i][kk], bfr[j][kk], acc[i][j], 0, 0, 0);
        __builtin_amdgcn_s_setprio(0);
        if (tt + 1 < 32) { asm volatile("s_waitcnt vmcnt(0)" ::: "memory"); }
        __builtin_amdgcn_s_barrier();
        u16* tmp = pc; pc = pn; pn = tmp;
    }
#undef STAGE_ALL

    float bvv[4];
#pragma unroll
    for (int j = 0; j < 4; ++j) bvv[j] = bias[n0 + wn * 64 + j * 16 + l15];

    if (mode == 2) {
        u16* Tv = lds;
        __syncthreads();
#pragma unroll
        for (int i = 0; i < 4; ++i)
#pragma unroll
            for (int r = 0; r < 4; ++r) {
                const int s = wr * 64 + i * 16 + (l4 << 2) + r;
#pragma unroll
                for (int j = 0; j < 4; ++j) {
                    const int d = wn * 64 + j * 16 + l15;
                    Tv[d * 136 + s] = f2bf(silu_f(acc[i][j][r] + bvv[j]));
                }
            }
        __syncthreads();
        const int bh = (m0 >> 10) * 16 + tn;     // b*16 + h
        const int s0 = m0 & 1023;
        u16* vt = (u16*)outp;
#pragma unroll
        for (int r8 = 0; r8 < 8; ++r8) {
            const int d = (t >> 4) + r8 * 16;
            const int s = (t & 15) * 8;
            u16x8 v = *(const u16x8*)&Tv[d * 136 + s];
            *(u16x8*)&vt[((size_t)bh * HEADD + d) * SEQLEN + s0 + s] = v;
        }
        return;
    }

#pragma unroll
    for (int i = 0; i < 4; ++i) {
        const int mbase = m0 + wr * 64 + i * 16 + (l4 << 2);
#pragma unroll
        for (int r = 0; r < 4; ++r) {
            const size_t rowoff = (size_t)(mbase + r) * HDIM + n0 + wn * 64 + l15;
#pragma unroll
            for (int j = 0; j < 4; ++j) {
                const float v = acc[i][j][r] + bvv[j];
                if (mode == 0)
                    ((u16*)outp)[rowoff + j * 16] = f2bf(silu_f(v));
                else
                    ((float*)outp)[rowoff + j * 16] = v;
            }
        }
    }
}

// ---------------------------------------------------------------------------
// Fused SiLU-attention + gating, 8-wave split + diagonal-branch (round-23).
__global__ __launch_bounds__(512) void attn_fused(
    const u16* __restrict__ Qb, const u16* __restrict__ Kb,
    const u16* __restrict__ VTg, const u16* __restrict__ Ub,
    const float* __restrict__ rel, u16* __restrict__ G)
{
    extern __shared__ u16 alds[];
    u16* Ps = alds + 24576;
    float* relh = (float*)(alds + 33792);

    const int idx = blockIdx.x;
    const int bh8 = idx & 7;
    const int j = (idx >> 3) & 7;
    const int bhhi = idx >> 6;            // 0..7
    const int bh = bhhi * 8 + bh8;
    const int b = bh >> 4, h = bh & 15;
    const int qS0 = j * 64;               // short subtile
    const int qL0 = (15 - j) * 64;        // long subtile
    const int nkt = 16 - j;
    const int t = threadIdx.x, lane = t & 63, w = t >> 6;    // 8 waves
    const int wq = w & 3;
    const bool isL = (w < 4);
    const int l15 = lane & 15, l4 = lane >> 4, l3 = lane >> 3;
    const size_t rowbase = (size_t)b * SEQLEN;
    const int col0 = h * HEADD;
    const float scale = 0.088388347648318447f;   // 1/sqrt(128)

    for (int i = t; i < 1024; i += 512) relh[i] = rel[(size_t)(1023 + i) * NHEADS + h];

    const u16* gK0 = Kb + (rowbase + w * 8 + l4) * HDIM + col0 + ((lane & 15) ^ l4) * 8;
    const u16* gK1 = Kb + (rowbase + w * 8 + 4 + l4) * HDIM + col0 + ((lane & 15) ^ (l4 + 4)) * 8;
    const u16* gV0 = VTg + ((size_t)bh * HEADD + w * 16 + l3) * SEQLEN + ((lane & 7) ^ l3) * 8;
    const u16* gV1 = VTg + ((size_t)bh * HEADD + w * 16 + 8 + l3) * SEQLEN + ((lane & 7) ^ l3) * 8;

    const int q0 = (isL ? qL0 : qS0) + wq * 16;
    bf16x8 aq[4];
#pragma unroll
    for (int dc = 0; dc < 4; ++dc)
        aq[dc] = *(const bf16x8*)&Qb[(rowbase + q0 + l15) * HDIM + col0 + dc * 32 + (l4 << 3)];

    f32x4 oacc[8] = {};
    const int prB = (isL ? 0 : 64) + wq * 16;     // Ps row base for this wave

#define STAGE_K(kt) do {                                                        \
    const size_t ko_ = (size_t)(kt) * 64 * HDIM;                                \
    glds16(gK0 + ko_, alds + w * 1024);                                         \
    glds16(gK1 + ko_, alds + w * 1024 + 512);                                   \
} while (0)
#define STAGE_V(kt, bsel) do {                                                  \
    u16* vb_ = alds + 8192 + ((bsel) ? 8192 : 0);                               \
    const size_t ko_ = (size_t)(kt) * 64;                                       \
    glds16(gV0 + ko_, vb_ + w * 1024);                                          \
    glds16(gV1 + ko_, vb_ + w * 1024 + 512);                                    \
} while (0)

    STAGE_K(0); STAGE_V(0, 0);
    asm volatile("s_waitcnt vmcnt(0)" ::: "memory");
    __builtin_amdgcn_s_barrier();

    int cur = 0;
#pragma unroll 1
    for (int kt = 0; kt < nkt; ++kt) {
        const int k0 = kt * 64;
        const bool act = isL || (kt <= j);        // wave-uniform
        const bool diag = isL ? (kt == nkt - 1) : (kt == j);
        if (kt + 1 < nkt) STAGE_V(kt + 1, cur ^ 1);
        const u16* kb = alds;
        const u16* vb = alds + 8192 + (cur ? 8192 : 0);

        // QK^T + rel (+ mask only on diag tile) + silu -> Ps
        if (act) {
#pragma unroll
            for (int kf = 0; kf < 4; ++kf) {
                const int krow = kf * 16 + l15;
                f32x4 s = {};
                __builtin_amdgcn_s_setprio(1);
#pragma unroll
                for (int dc = 0; dc < 4; ++dc) {
                    bf16x8 bk = *(const bf16x8*)&kb[krow * 128 + (((dc * 4 + l4) ^ (krow & 7)) << 3)];
                    s = __builtin_amdgcn_mfma_f32_16x16x32_bf16(aq[dc], bk, s, 0, 0, 0);
                }
                __builtin_amdgcn_s_setprio(0);
                const int kabs = k0 + krow;
                const int pr = prB + (l4 << 2);
                if (diag) {
#pragma unroll
                    for (int r = 0; r < 4; ++r) {
                        const int qabs = q0 + (l4 << 2) + r;
                        float v = 0.f;
                        if (kabs <= qabs) v = silu_f(fmaf(s[r], scale, relh[qabs - kabs]));
                        Ps[(pr + r) * 72 + kf * 16 + l15] = f2bf_t(v);
                    }
                } else {
#pragma unroll
                    for (int r = 0; r < 4; ++r) {
                        const int qabs = q0 + (l4 << 2) + r;
                        const float v = silu_f(fmaf(s[r], scale, relh[qabs - kabs]));
                        Ps[(pr + r) * 72 + kf * 16 + l15] = f2bf_t(v);
                    }
                }
            }
        }
        __builtin_amdgcn_s_barrier();                 // Kbuf free (QK^T reads done)
        if (kt + 1 < nkt) STAGE_K(kt + 1);

        // PV (active waves only)
        if (act) {
            bf16x8 ap[2];
#pragma unroll
            for (int kc = 0; kc < 2; ++kc)
                ap[kc] = *(const bf16x8*)&Ps[(prB + l15) * 72 + kc * 32 + (l4 << 3)];
            __builtin_amdgcn_s_setprio(1);
#pragma unroll
            for (int df = 0; df < 8; ++df) {
                const int vrow = df * 16 + l15;
#pragma unroll
                for (int kc = 0; kc < 2; ++kc) {
                    bf16x8 bv = *(const bf16x8*)&vb[vrow * 64 + (((kc * 4 + l4) ^ (vrow & 7)) << 3)];
                    oacc[df] = __builtin_amdgcn_mfma_f32_16x16x32_bf16(ap[kc], bv, oacc[df], 0, 0, 0);
                }
            }
            __builtin_amdgcn_s_setprio(0);
        }
        asm volatile("s_waitcnt vmcnt(0)" ::: "memory");  // next K,V landed
        __builtin_amdgcn_s_barrier();
        cur ^= 1;
    }
#undef STAGE_K
#undef STAGE_V

    // G = O * U (each wave its own 16 rows), row-sweep for coalescing
#pragma unroll
    for (int r = 0; r < 4; ++r) {
        const int qr = q0 + (l4 << 2) + r;
        const size_t row = (rowbase + qr) * HDIM + col0 + l15;
#pragma unroll
        for (int df = 0; df < 8; ++df)
            G[row + df * 16] = f2bf(oacc[df][r] * bf2f(Ub[row + df * 16]));
    }
}

// ---------------------------------------------------------------------------
extern "C" void kernel_launch(void* const* d_in, const int* in_sizes, int n_in,
                              void* d_out, int out_size, void* d_ws, size_t ws_size,
                              hipStream_t stream) {
    const float* query = (const float*)d_in[0];
    const float* key_  = (const float*)d_in[1];
    const float* value = (const float*)d_in[2];
    // d_in[3] attn_mask: causal by construction, handled analytically.
    const float* Wq  = (const float*)d_in[4];  const float* bq  = (const float*)d_in[5];
    const float* Wk  = (const float*)d_in[6];  const float* bk  = (const float*)d_in[7];
    const float* Wv  = (const float*)d_in[8];  const float* bv  = (const float*)d_in[9];
    const float* Wu  = (const float*)d_in[10]; const float* bu  = (const float*)d_in[11];
    const float* Wf2 = (const float*)d_in[12]; const float* bf2 = (const float*)d_in[13];
    const float* rel = (const float*)d_in[14];

    // Workspace (88 MiB): WTa 8 | Xbf 16 | Q(=G) 16 | K 16 | VTg 16 | U 16.
    // d_out (32 MiB, fully rewritten by the final GEMM) used as scratch for
    // key_bf (16 MiB) + Wv^T (8 MiB).
    char* ws = (char*)d_ws;
    const size_t WBYTES = (size_t)HDIM * HDIM * 2;   // 8 MiB
    const size_t ABYTES = (size_t)4096 * HDIM * 2;   // 16 MiB
    u16* WTa  = (u16*)ws;
    u16* Xbf  = (u16*)(ws + WBYTES);
    u16* Qbuf = (u16*)(ws + WBYTES + 1 * ABYTES);
    u16* Kbuf = (u16*)(ws + WBYTES + 2 * ABYTES);
    u16* VTg  = (u16*)(ws + WBYTES + 3 * ABYTES);    // V written transposed here
    u16* Ubuf = (u16*)(ws + WBYTES + 4 * ABYTES);
    u16* WTb  = VTg;           // borrowed for Wu^T: freed before V GEMM writes VTg
    u16* Gbuf = Qbuf;          // attn reads its own Q rows, then writes them as G
    u16* KXbf = (u16*)d_out;                 // scratch in d_out
    u16* WTv  = (u16*)((char*)d_out + ABYTES);

    dim3 tpb(256);
    dim3 tgrid(32, 32);        // W transpose tiles
    dim3 tgrid2(32, 32, 2);    // dual transpose
    const int n8 = 4096 * HDIM / 8;
    const size_t GLDS  = 65536;  // 64 KiB for gemm128
    const size_t G8LDS = 131072; // 128 KiB for gemm256_8p
    const size_t ALDS  = 71680;  // 70 KiB for attn_fused

    f32_to_bf16<<<2048, tpb, 0, stream>>>(query, Xbf, n8);
    transpose_w2<<<tgrid2, tpb, 0, stream>>>(Wq, WTa, Wu, WTb);
    gemm256_8p<<<256, 512, G8LDS, stream>>>(Xbf, WTa, WTb, bq, bu, Qbuf, Ubuf);
    f32_to_bf16_2<<<2 * (n8 >> 8), tpb, 0, stream>>>(key_, KXbf, value, Xbf, n8);
    transpose_w2<<<tgrid2, tpb, 0, stream>>>(Wk, WTa, Wv, WTv);
    gemm128<<<512, tpb, GLDS, stream>>>(KXbf, WTa, bk, Kbuf, 0);
    gemm128<<<512, tpb, GLDS, stream>>>(Xbf, WTv, bv, VTg, 2);
    attn_fused<<<512, 512, ALDS, stream>>>(Qbuf, Kbuf, VTg, Ubuf, rel, Gbuf);
    transpose_w<<<tgrid, tpb, 0, stream>>>(Wf2, WTa);
    gemm128<<<512, tpb, GLDS, stream>>>(Gbuf, WTa, bf2, d_out, 1);
}